// Round 4
// baseline (17979.172 us; speedup 1.0000x reference)
//
#include <hip/hip_runtime.h>
#include <stdint.h>

// LSTM_34359738368754: 2-layer LSTM, T=180 B=512 H=1024 I=V=108.
// R4: persistent cooperative kernel for the whole 180-step loop.
//  - Previous structure (R3) paid ~2 launch boundaries per step (360 total);
//    per-step measured 42us vs ~16-18us compute floor -> launch/dispatch
//    overhead dominated. Now: ONE hipLaunchCooperativeKernel, 2 device-side
//    grid barriers per step (sense-reversal, agent-scope atomics + fences).
//  - Phase B (gates2 = c1@Wcomb^T) retiled 128x64 over 256 blocks (was
//    128x128 over 128 blocks = half chip idle). Weight traffic unchanged;
//    duplicated stream is the 1MB C1b activation (L2-resident per XCD).
//  - Phase A unchanged: b<128 gates1(K=128+1024)->cell1; b>=128 U2(K=1024).
//  - Old multi-launch path kept as fallback (coop launch failure / small ws).

typedef unsigned short u16;
typedef __attribute__((ext_vector_type(4))) float f32x4;
typedef __attribute__((ext_vector_type(8))) short bf16x8;

#define HDIM 1024
#define BSZ  512
#define TSTEPS 180
#define IIN  108
#define VOUT 108
#define NBLK 256

__device__ __forceinline__ u16 f2bf(float x) {
  union { float f; unsigned u; } v; v.f = x;
  unsigned r = (v.u + 0x7fffu + ((v.u >> 16) & 1u)) >> 16;  // RNE
  return (u16)r;
}
__device__ __forceinline__ float bf2f(u16 b) {
  union { unsigned u; float f; } v; v.u = ((unsigned)b) << 16; return v.f;
}
__device__ __forceinline__ float sigm(float x) { return 1.f / (1.f + __expf(-x)); }
__device__ __forceinline__ float tanh_(float x) {
  float a = fabsf(x), t = __expf(-2.f * a);
  float r = (1.f - t) / (1.f + t);
  return x < 0.f ? -r : r;
}
__device__ __forceinline__ int permrow(int n) { return ((n & 1023) << 2) | (n >> 10); }

__device__ __forceinline__ void load16_lds(const void* g, void* l) {
  __builtin_amdgcn_global_load_lds(
      (const __attribute__((address_space(1))) unsigned int*)g,
      (__attribute__((address_space(3))) unsigned int*)l, 16, 0, 0);
}

// ---------------- grid-wide barrier (cooperative launch) ----------------
// bar[0] = arrival count, bar[1] = generation. Sense-reversal; agent scope.
// __threadfence() both sides handles cross-XCD L2 writeback/invalidate.
__device__ __forceinline__ void grid_sync(unsigned* bar) {
  __syncthreads();
  if (threadIdx.x == 0) {
    __threadfence();
    unsigned g = __hip_atomic_load(bar + 1, __ATOMIC_RELAXED, __HIP_MEMORY_SCOPE_AGENT);
    unsigned a = __hip_atomic_fetch_add(bar, 1u, __ATOMIC_ACQ_REL, __HIP_MEMORY_SCOPE_AGENT);
    if (a == (unsigned)(NBLK - 1)) {
      __hip_atomic_store(bar, 0u, __ATOMIC_RELAXED, __HIP_MEMORY_SCOPE_AGENT);
      __hip_atomic_store(bar + 1, g + 1u, __ATOMIC_RELEASE, __HIP_MEMORY_SCOPE_AGENT);
    } else {
      while (__hip_atomic_load(bar + 1, __ATOMIC_RELAXED, __HIP_MEMORY_SCOPE_AGENT) == g)
        __builtin_amdgcn_s_sleep(1);
    }
    __threadfence();
  }
  __syncthreads();
}

// ================= 128x128 double-buffered GEMM =================
// smem: buf b at smem + b*32768; As 16KB then Bs 16KB. BK=64.
// LDS chunk swizzle: physical chunk pc holds logical chunk pc^(row&7).
__device__ __forceinline__ void stage128(const u16* A, const u16* B, int K,
                                         int k0, int m0, int n0,
                                         char* smem, int buf, int wave, int lane) {
  u16* As = (u16*)(smem + buf * 32768);
  u16* Bs = (u16*)(smem + buf * 32768 + 16384);
#pragma unroll
  for (int i = 0; i < 4; ++i) {
    int c = (wave * 4 + i) * 64 + lane;
    int row = c >> 3, lc = (c & 7) ^ (row & 7);     // swizzled source chunk
    const u16* g = A + (size_t)(m0 + row) * K + k0 + (lc << 3);
    load16_lds(g, As + c * 8);
  }
#pragma unroll
  for (int i = 0; i < 4; ++i) {
    int c = (wave * 4 + i) * 64 + lane;
    int row = c >> 3, lc = (c & 7) ^ (row & 7);
    const u16* g = B + (size_t)(n0 + row) * K + k0 + (lc << 3);
    load16_lds(g, Bs + c * 8);
  }
}

__device__ __forceinline__ void compute128(f32x4 acc[4][4], char* smem, int buf,
                                           int wm, int wn, int l16, int quad) {
  const bf16x8* Av = (const bf16x8*)(smem + buf * 32768);
  const bf16x8* Bv = (const bf16x8*)(smem + buf * 32768 + 16384);
  const int sw = l16 & 7;
#pragma unroll
  for (int kk = 0; kk < 2; ++kk) {
    const int pc = (kk * 4 + quad) ^ sw;            // swizzled chunk
    bf16x8 a[4], b[4];
#pragma unroll
    for (int mt = 0; mt < 4; ++mt)
      a[mt] = Av[(wm * 64 + mt * 16 + l16) * 8 + pc];
#pragma unroll
    for (int nt = 0; nt < 4; ++nt)
      b[nt] = Bv[(wn * 64 + nt * 16 + l16) * 8 + pc];
#pragma unroll
    for (int mt = 0; mt < 4; ++mt)
#pragma unroll
      for (int nt = 0; nt < 4; ++nt)
        acc[mt][nt] = __builtin_amdgcn_mfma_f32_16x16x32_bf16(
            a[mt], b[nt], acc[mt][nt], 0, 0, 0);
  }
}

// acc(128x128) at (m0,n0) = A0@B0^T (K0, optional) + A1@B1^T (K1).
template <bool HAS0>
__device__ __forceinline__ void gemm128(f32x4 acc[4][4],
    const u16* A0, const u16* B0, int K0,
    const u16* A1, const u16* B1, int K1,
    int m0, int n0, char* smem) {
  const int tid = threadIdx.x;
  const int lane = tid & 63, wave = tid >> 6;
  const int quad = lane >> 4, l16 = lane & 15;
  const int wm = wave >> 1, wn = wave & 1;

#pragma unroll
  for (int mt = 0; mt < 4; ++mt)
#pragma unroll
    for (int nt = 0; nt < 4; ++nt) {
      f32x4 z = {0.f, 0.f, 0.f, 0.f};
      acc[mt][nt] = z;
    }

  const int n0i = HAS0 ? (K0 >> 6) : 0;
  const int nIter = n0i + (K1 >> 6);

  // prologue: stage iter 0 into buf 0
  if (HAS0 && n0i > 0)
    stage128(A0, B0, K0, 0, m0, n0, smem, 0, wave, lane);
  else
    stage128(A1, B1, K1, 0, m0, n0, smem, 0, wave, lane);

  for (int it = 0; it < nIter; ++it) {
    if (it + 1 < nIter) {
      int nx = it + 1;
      if (HAS0 && nx < n0i)
        stage128(A0, B0, K0, nx * 64, m0, n0, smem, nx & 1, wave, lane);
      else
        stage128(A1, B1, K1, (nx - n0i) * 64, m0, n0, smem, nx & 1, wave, lane);
      __builtin_amdgcn_s_waitcnt(0xF78);  // vmcnt(8): prev stage landed
    } else {
      __builtin_amdgcn_s_waitcnt(0xF70);  // vmcnt(0)
    }
    __builtin_amdgcn_s_barrier();
    asm volatile("" ::: "memory");
    compute128(acc, smem, it & 1, wm, wn, l16, quad);
    asm volatile("" ::: "memory");
    __builtin_amdgcn_s_barrier();  // all waves done reading buf before overwrite
  }
}

// ============ phase-B 128x64 double-buffered GEMM (persistent kernel) ============
// buf b at smem + b*24576; As (128 rows) 16KB then Bs (64 rows) 8KB. BK=64.
__device__ __forceinline__ void stage_pb(const u16* A, const u16* B, int k0,
                                         int m0, int n0, char* smem, int buf,
                                         int wave, int lane) {
  u16* As = (u16*)(smem + buf * 24576);
  u16* Bs = (u16*)(smem + buf * 24576 + 16384);
#pragma unroll
  for (int i = 0; i < 4; ++i) {
    int c = (wave * 4 + i) * 64 + lane;               // 1024 chunks = 128 rows
    int row = c >> 3, lc = (c & 7) ^ (row & 7);
    load16_lds(A + (size_t)(m0 + row) * 1024 + k0 + (lc << 3), As + c * 8);
  }
#pragma unroll
  for (int i = 0; i < 2; ++i) {
    int c = (wave * 2 + i) * 64 + lane;               // 512 chunks = 64 rows
    int row = c >> 3, lc = (c & 7) ^ (row & 7);
    load16_lds(B + (size_t)(n0 + row) * 1024 + k0 + (lc << 3), Bs + c * 8);
  }
}

__device__ __forceinline__ void compute_pb(f32x4 acc[4][2], char* smem, int buf,
                                           int wm, int wn, int l16, int quad) {
  const bf16x8* Av = (const bf16x8*)(smem + buf * 24576);
  const bf16x8* Bv = (const bf16x8*)(smem + buf * 24576 + 16384);
  const int sw = l16 & 7;
#pragma unroll
  for (int kk = 0; kk < 2; ++kk) {
    const int pc = (kk * 4 + quad) ^ sw;
    bf16x8 a[4], b[2];
#pragma unroll
    for (int mt = 0; mt < 4; ++mt)
      a[mt] = Av[(wm * 64 + mt * 16 + l16) * 8 + pc];
#pragma unroll
    for (int nt = 0; nt < 2; ++nt)
      b[nt] = Bv[(wn * 32 + nt * 16 + l16) * 8 + pc];
#pragma unroll
    for (int mt = 0; mt < 4; ++mt)
#pragma unroll
      for (int nt = 0; nt < 2; ++nt)
        acc[mt][nt] = __builtin_amdgcn_mfma_f32_16x16x32_bf16(
            a[mt], b[nt], acc[mt][nt], 0, 0, 0);
  }
}

// ================= persistent whole-sequence kernel =================
__global__ __launch_bounds__(256, 1) void lstm_persistent(
    const u16* __restrict__ Xbf, const u16* __restrict__ W1a,
    const u16* __restrict__ Whh1b, const float* __restrict__ b1s,
    float* __restrict__ C1f, u16* __restrict__ C1b,
    const u16* __restrict__ Whh2b, const float* __restrict__ b2s,
    u16* __restrict__ U2, const u16* __restrict__ Wcombb,
    float* __restrict__ C2f, u16* __restrict__ C2seq,
    u16* __restrict__ H1x, u16* __restrict__ H1y,
    u16* __restrict__ H2x, u16* __restrict__ H2y,
    unsigned* __restrict__ bar)
{
  __shared__ __align__(16) char smem[65536];
  const int tid = threadIdx.x;
  const int lane = tid & 63, wave = tid >> 6;
  const int quad = lane >> 4, l16 = lane & 15;
  const int wm = wave >> 1, wn = wave & 1;
  const int b = blockIdx.x;

  for (int t = 0; t < TSTEPS; ++t) {
    const int p = t & 1;
    const u16* H1in = p ? H1y : H1x;  u16* H1o = p ? H1x : H1y;
    const u16* H2in = p ? H2y : H2x;  u16* H2o = p ? H2x : H2y;
    const u16* Xt = Xbf + (size_t)t * BSZ * 128;

    // ---------------- phase A ----------------
    if (b < 128) {
      f32x4 acc[4][4];
      const int m0 = (b >> 5) * 128, n0 = (b & 31) * 128;
      gemm128<true>(acc, Xt, W1a, 128, H1in, Whh1b, 1024, m0, n0, smem);

      float* gl = (float*)smem;  // [64][132]
      const int jbase = (b & 31) * 32;
#pragma unroll
      for (int h = 0; h < 2; ++h) {
        __syncthreads();
        if (wm == h) {
#pragma unroll
          for (int nt = 0; nt < 4; ++nt) {
            int col = wn * 64 + nt * 16 + l16;
#pragma unroll
            for (int mt = 0; mt < 4; ++mt) {
              int rowb = mt * 16 + quad * 4;
#pragma unroll
              for (int r = 0; r < 4; ++r)
                gl[(rowb + r) * 132 + col] = acc[mt][nt][r];
            }
          }
        }
        __syncthreads();
#pragma unroll
        for (int itr = 0; itr < 8; ++itr) {
          int idx = itr * 256 + tid;
          int mr = idx >> 5, jl = idx & 31;
          f32x4 g4 = *(const f32x4*)(gl + mr * 132 + jl * 4);
          f32x4 b4 = *(const f32x4*)(b1s + jbase * 4 + jl * 4);
          g4 += b4;
          float ii = sigm(g4[0]), ff = sigm(g4[1]);
          float gg = tanh_(g4[2]), oo = sigm(g4[3]);
          size_t off = (size_t)(m0 + h * 64 + mr) * HDIM + jbase + jl;
          float cp = C1f[off];
          float cn = ff * cp + ii * gg;
          float hh = oo * tanh_(cn);
          C1f[off] = cn;
          H1o[off] = f2bf(hh);
          C1b[off] = f2bf(cn);
        }
      }
    } else {
      f32x4 acc[4][4];
      const int bb = b - 128;
      const int m0 = (bb >> 5) * 128, n0 = (bb & 31) * 128;
      gemm128<false>(acc, nullptr, nullptr, 0, H2in, Whh2b, 1024, m0, n0, smem);
#pragma unroll
      for (int nt = 0; nt < 4; ++nt) {
        int col = n0 + wn * 64 + nt * 16 + l16;
        float bias = b2s[col];
#pragma unroll
        for (int mt = 0; mt < 4; ++mt) {
          int row = m0 + wm * 64 + mt * 16 + quad * 4;
#pragma unroll
          for (int r = 0; r < 4; ++r)
            U2[(size_t)(row + r) * 4096 + col] = f2bf(acc[mt][nt][r] + bias);
        }
      }
    }
    grid_sync(bar);

    // ---------------- phase B: gates2 = c1@Wcomb^T + U2, 128x64 tiles ----------------
    {
      f32x4 acc[4][2];
#pragma unroll
      for (int mt = 0; mt < 4; ++mt)
#pragma unroll
        for (int nt = 0; nt < 2; ++nt) {
          f32x4 z = {0.f, 0.f, 0.f, 0.f};
          acc[mt][nt] = z;
        }
      const int m0 = (b >> 6) * 128;        // 4 m-tiles
      const int n0 = (b & 63) * 64;         // 64 n-tiles
      const int jbase = (b & 63) * 16;

      stage_pb(C1b, Wcombb, 0, m0, n0, smem, 0, wave, lane);
      for (int it = 0; it < 16; ++it) {
        if (it + 1 < 16) {
          stage_pb(C1b, Wcombb, (it + 1) * 64, m0, n0, smem, (it + 1) & 1, wave, lane);
          __builtin_amdgcn_s_waitcnt(0xF76);  // vmcnt(6): prev stage landed
        } else {
          __builtin_amdgcn_s_waitcnt(0xF70);  // vmcnt(0)
        }
        __builtin_amdgcn_s_barrier();
        asm volatile("" ::: "memory");
        compute_pb(acc, smem, it & 1, wm, wn, l16, quad);
        asm volatile("" ::: "memory");
        __builtin_amdgcn_s_barrier();
      }

      float* gl = (float*)smem;  // [128][68]
      __syncthreads();
#pragma unroll
      for (int nt = 0; nt < 2; ++nt) {
        int col = wn * 32 + nt * 16 + l16;
#pragma unroll
        for (int mt = 0; mt < 4; ++mt) {
          int rowb = wm * 64 + mt * 16 + quad * 4;
#pragma unroll
          for (int r = 0; r < 4; ++r)
            gl[(rowb + r) * 68 + col] = acc[mt][nt][r];
        }
      }
      __syncthreads();
      u16* C2dst = C2seq + (size_t)t * BSZ * HDIM;
#pragma unroll
      for (int itr = 0; itr < 8; ++itr) {
        int idx = itr * 256 + tid;
        int mr = idx >> 4, jl = idx & 15;
        int grow = m0 + mr;
        f32x4 g4 = *(const f32x4*)(gl + mr * 68 + jl * 4);
        const u16* u2p = U2 + (size_t)grow * 4096 + (jbase + jl) * 4;
        g4[0] += bf2f(u2p[0]); g4[1] += bf2f(u2p[1]);
        g4[2] += bf2f(u2p[2]); g4[3] += bf2f(u2p[3]);
        float ii = sigm(g4[0]), ff = sigm(g4[1]);
        float gg = tanh_(g4[2]), oo = sigm(g4[3]);
        size_t off = (size_t)grow * HDIM + jbase + jl;
        float cp = C2f[off];
        float cn = ff * cp + ii * gg;
        float hh = oo * tanh_(cn);
        C2f[off] = cn;
        H2o[off] = f2bf(hh);
        C2dst[off] = f2bf(cn);
      }
    }
    grid_sync(bar);
  }
}

// ============ fallback per-step kernels (old path) ============
__global__ __launch_bounds__(256, 1) void k1_fused(
    const u16* __restrict__ Xt, const u16* __restrict__ W1a,
    const u16* __restrict__ H1in, const u16* __restrict__ Whh1,
    const float* __restrict__ b1s, float* __restrict__ c1State,
    u16* __restrict__ H1out, u16* __restrict__ C1out,
    const u16* __restrict__ H2in, const u16* __restrict__ Whh2,
    const float* __restrict__ b2s, u16* __restrict__ U2)
{
  __shared__ __align__(16) char smem[65536];
  const int tid = threadIdx.x;
  const int lane = tid & 63, wave = tid >> 6;
  const int quad = lane >> 4, l16 = lane & 15;
  const int wm = wave >> 1, wn = wave & 1;
  const int b = blockIdx.x;
  f32x4 acc[4][4];

  if (b < 128) {
    const int m0 = (b >> 5) * 128, n0 = (b & 31) * 128;
    gemm128<true>(acc, Xt, W1a, 128, H1in, Whh1, 1024, m0, n0, smem);

    float* gl = (float*)smem;  // [64][132]
    const int jbase = (b & 31) * 32;
#pragma unroll
    for (int h = 0; h < 2; ++h) {
      __syncthreads();
      if (wm == h) {
#pragma unroll
        for (int nt = 0; nt < 4; ++nt) {
          int col = wn * 64 + nt * 16 + l16;
#pragma unroll
          for (int mt = 0; mt < 4; ++mt) {
            int rowb = mt * 16 + quad * 4;
#pragma unroll
            for (int r = 0; r < 4; ++r)
              gl[(rowb + r) * 132 + col] = acc[mt][nt][r];
          }
        }
      }
      __syncthreads();
#pragma unroll
      for (int itr = 0; itr < 8; ++itr) {
        int idx = itr * 256 + tid;
        int mr = idx >> 5, jl = idx & 31;
        f32x4 g4 = *(const f32x4*)(gl + mr * 132 + jl * 4);
        f32x4 b4 = *(const f32x4*)(b1s + jbase * 4 + jl * 4);
        g4 += b4;
        float ii = sigm(g4[0]), ff = sigm(g4[1]);
        float gg = tanh_(g4[2]), oo = sigm(g4[3]);
        size_t off = (size_t)(m0 + h * 64 + mr) * HDIM + jbase + jl;
        float cp = c1State[off];
        float cn = ff * cp + ii * gg;
        float hh = oo * tanh_(cn);
        c1State[off] = cn;
        H1out[off] = f2bf(hh);
        C1out[off] = f2bf(cn);
      }
    }
  } else {
    const int bb = b - 128;
    const int m0 = (bb >> 5) * 128, n0 = (bb & 31) * 128;
    gemm128<false>(acc, nullptr, nullptr, 0, H2in, Whh2, 1024, m0, n0, smem);
#pragma unroll
    for (int nt = 0; nt < 4; ++nt) {
      int col = n0 + wn * 64 + nt * 16 + l16;
      float bias = b2s[col];
#pragma unroll
      for (int mt = 0; mt < 4; ++mt) {
        int row = m0 + wm * 64 + mt * 16 + quad * 4;
#pragma unroll
        for (int r = 0; r < 4; ++r)
          U2[(size_t)(row + r) * 4096 + col] = f2bf(acc[mt][nt][r] + bias);
      }
    }
  }
}

__global__ __launch_bounds__(256, 1) void k2_cell2(
    const u16* __restrict__ C1b, const u16* __restrict__ Wcomb,
    const u16* __restrict__ U2, float* __restrict__ c2State,
    u16* __restrict__ H2out, u16* __restrict__ C2out)
{
  __shared__ __align__(16) char smem[65536];
  const int tid = threadIdx.x;
  const int lane = tid & 63, wave = tid >> 6;
  const int quad = lane >> 4, l16 = lane & 15;
  const int wm = wave >> 1, wn = wave & 1;
  const int b = blockIdx.x;
  const int m0 = (b >> 5) * 128, n0 = (b & 31) * 128;
  f32x4 acc[4][4];
  gemm128<false>(acc, nullptr, nullptr, 0, C1b, Wcomb, 1024, m0, n0, smem);

  float* gl = (float*)smem;
  const int jbase = (b & 31) * 32;
#pragma unroll
  for (int h = 0; h < 2; ++h) {
    __syncthreads();
    if (wm == h) {
#pragma unroll
      for (int nt = 0; nt < 4; ++nt) {
        int col = wn * 64 + nt * 16 + l16;
#pragma unroll
        for (int mt = 0; mt < 4; ++mt) {
          int rowb = mt * 16 + quad * 4;
#pragma unroll
          for (int r = 0; r < 4; ++r)
            gl[(rowb + r) * 132 + col] = acc[mt][nt][r];
        }
      }
    }
    __syncthreads();
#pragma unroll
    for (int itr = 0; itr < 8; ++itr) {
      int idx = itr * 256 + tid;
      int mr = idx >> 5, jl = idx & 31;
      int grow = m0 + h * 64 + mr;
      f32x4 g4 = *(const f32x4*)(gl + mr * 132 + jl * 4);
      const u16* u2p = U2 + (size_t)grow * 4096 + jbase * 4 + jl * 4;
      g4[0] += bf2f(u2p[0]); g4[1] += bf2f(u2p[1]);
      g4[2] += bf2f(u2p[2]); g4[3] += bf2f(u2p[3]);
      float ii = sigm(g4[0]), ff = sigm(g4[1]);
      float gg = tanh_(g4[2]), oo = sigm(g4[3]);
      size_t off = (size_t)grow * HDIM + jbase + jl;
      float cp = c2State[off];
      float cn = ff * cp + ii * gg;
      float hh = oo * tanh_(cn);
      c2State[off] = cn;
      H2out[off] = f2bf(hh);
      C2out[off] = f2bf(cn);
    }
  }
}

// ================= 64x128 single-buffered GEMM (wcomb / final) =================
__device__ __forceinline__ void gemm_tile_64x128(
    f32x4 acc[2][4],
    const u16* A0, const u16* B0, int K0,
    const u16* A1, const u16* B1, int K1,
    int m0, int n0, u16* As, u16* Bs)
{
  const int tid  = threadIdx.x;
  const int lane = tid & 63;
  const int wave = tid >> 6;
  const int quad = lane >> 4;
  const int l16  = lane & 15;
  const int wm   = wave >> 1;
  const int wn   = wave & 1;
  const int sw   = l16 & 7;

#pragma unroll
  for (int mt = 0; mt < 2; ++mt)
#pragma unroll
    for (int nt = 0; nt < 4; ++nt) {
      f32x4 z = {0.f, 0.f, 0.f, 0.f};
      acc[mt][nt] = z;
    }

  for (int s = 0; s < 2; ++s) {
    const u16* A = s ? A1 : A0;
    const u16* B = s ? B1 : B0;
    const int  K = s ? K1 : K0;
    for (int k0 = 0; k0 < K; k0 += 64) {
      __syncthreads();
#pragma unroll
      for (int i = 0; i < 2; ++i) {
        int c = (wave * 2 + i) * 64 + lane;
        int row = c >> 3, lc = (c & 7) ^ (row & 7);
        const u16* g = A + (size_t)(m0 + row) * K + k0 + (lc << 3);
        load16_lds(g, As + c * 8);
      }
#pragma unroll
      for (int i = 0; i < 4; ++i) {
        int c = (wave * 4 + i) * 64 + lane;
        int row = c >> 3, lc = (c & 7) ^ (row & 7);
        const u16* g = B + (size_t)(n0 + row) * K + k0 + (lc << 3);
        load16_lds(g, Bs + c * 8);
      }
      __syncthreads();
      const bf16x8* Av = (const bf16x8*)As;
      const bf16x8* Bv = (const bf16x8*)Bs;
#pragma unroll
      for (int kk = 0; kk < 2; ++kk) {
        const int pc = (kk * 4 + quad) ^ sw;
        bf16x8 a[2], b[4];
#pragma unroll
        for (int mt = 0; mt < 2; ++mt)
          a[mt] = Av[(wm * 32 + mt * 16 + l16) * 8 + pc];
#pragma unroll
        for (int nt = 0; nt < 4; ++nt)
          b[nt] = Bv[(wn * 64 + nt * 16 + l16) * 8 + pc];
#pragma unroll
        for (int mt = 0; mt < 2; ++mt)
#pragma unroll
          for (int nt = 0; nt < 4; ++nt)
            acc[mt][nt] = __builtin_amdgcn_mfma_f32_16x16x32_bf16(
                a[mt], b[nt], acc[mt][nt], 0, 0, 0);
      }
    }
  }
  __syncthreads();
}

__global__ __launch_bounds__(256, 2) void wcomb_gemm(
    const u16* __restrict__ A, const u16* __restrict__ Bt, u16* __restrict__ outp)
{
  __shared__ __align__(16) char smem[24576];
  u16* As = (u16*)smem;
  u16* Bs = (u16*)(smem + 8192);
  const int m0 = blockIdx.y * 64;
  const int n0 = blockIdx.x * 128;
  f32x4 acc[2][4];
  gemm_tile_64x128(acc, A, Bt, 1024, nullptr, nullptr, 0, m0, n0, As, Bs);
  const int lane = threadIdx.x & 63;
  const int wave = threadIdx.x >> 6;
  const int quad = lane >> 4, l16 = lane & 15;
  const int wm = wave >> 1, wn = wave & 1;
#pragma unroll
  for (int mt = 0; mt < 2; ++mt)
#pragma unroll
    for (int nt = 0; nt < 4; ++nt)
#pragma unroll
      for (int r = 0; r < 4; ++r) {
        int mr = m0 + wm * 32 + mt * 16 + quad * 4 + r;
        int c  = n0 + wn * 64 + nt * 16 + l16;
        outp[(size_t)permrow(mr) * 1024 + c] = f2bf(acc[mt][nt][r]);
      }
}

__global__ __launch_bounds__(256, 2) void final_logsoftmax(
    const u16* __restrict__ C2, const u16* __restrict__ Wf,
    const float* __restrict__ bfin, float* __restrict__ out)
{
  __shared__ __align__(16) char smem[64 * 132 * 4 + 256];
  u16* As = (u16*)smem;
  u16* Bs = (u16*)(smem + 8192);
  float* gl  = (float*)smem;
  float* lse = (float*)(smem + 64 * 132 * 4);

  const int m0 = blockIdx.y * 64;
  f32x4 acc[2][4];
  gemm_tile_64x128(acc, C2, Wf, 1024, nullptr, nullptr, 0, m0, 0, As, Bs);

  const int tid = threadIdx.x;
  const int lane = tid & 63;
  const int wave = tid >> 6;
  const int quad = lane >> 4, l16 = lane & 15;
  const int wm = wave >> 1, wn = wave & 1;
#pragma unroll
  for (int nt = 0; nt < 4; ++nt) {
    int coll = wn * 64 + nt * 16 + l16;
    float bias = (coll < VOUT) ? bfin[coll] : 0.f;
#pragma unroll
    for (int mt = 0; mt < 2; ++mt) {
      int rowb = wm * 32 + mt * 16 + quad * 4;
#pragma unroll
      for (int r = 0; r < 4; ++r)
        gl[(rowb + r) * 132 + coll] = acc[mt][nt][r] + bias;
    }
  }
  __syncthreads();
  if (tid < 64) {
    const float* row = gl + tid * 132;
    float mx = -1e30f;
    for (int c = 0; c < VOUT; ++c) mx = fmaxf(mx, row[c]);
    float s = 0.f;
    for (int c = 0; c < VOUT; ++c) s += __expf(row[c] - mx);
    lse[tid] = mx + __logf(s);
  }
  __syncthreads();
  for (int idx = tid; idx < 64 * VOUT; idx += 256) {
    int m = idx / VOUT, c = idx - m * VOUT;
    out[(size_t)(m0 + m) * VOUT + c] = gl[m * 132 + c] - lse[m];
  }
}

// ---------------- setup kernels ----------------
__global__ void k_build_w1a(const float* __restrict__ w, u16* __restrict__ d) {
  int idx = blockIdx.x * 256 + threadIdx.x;
  int n = idx >> 7, k = idx & 127;
  float v = (k < IIN) ? w[n * IIN + k] : 0.f;
  d[permrow(n) * 128 + k] = f2bf(v);
}
__global__ void k_conv_perm1024(const float* __restrict__ w, u16* __restrict__ d) {
  int idx = blockIdx.x * 256 + threadIdx.x;
  int n = idx >> 10, k = idx & 1023;
  d[(size_t)permrow(n) * 1024 + k] = f2bf(w[idx]);
}
__global__ void k_conv(const float* __restrict__ s, u16* __restrict__ d) {
  int idx = blockIdx.x * 256 + threadIdx.x;
  d[idx] = f2bf(s[idx]);
}
__global__ void k_transpose1024(const float* __restrict__ s, u16* __restrict__ d) {
  int idx = blockIdx.x * 256 + threadIdx.x;
  int r = idx >> 10, c = idx & 1023;
  d[c * 1024 + r] = f2bf(s[idx]);
}
__global__ void k_build_wfin(const float* __restrict__ w, u16* __restrict__ d) {
  int idx = blockIdx.x * 256 + threadIdx.x;
  int r = idx >> 10, c = idx & 1023;
  d[idx] = (r < VOUT) ? f2bf(w[r * 1024 + c]) : (u16)0;
}
__global__ void k_build_xpad(const float* __restrict__ x, u16* __restrict__ d) {
  int idx = blockIdx.x * 256 + threadIdx.x;
  int row = idx >> 7, k = idx & 127;
  d[idx] = (k < IIN) ? f2bf(x[row * IIN + k]) : (u16)0;
}
__global__ void k_b1sum(const float* __restrict__ a, const float* __restrict__ b,
                        float* __restrict__ d) {
  int n = blockIdx.x * 256 + threadIdx.x;
  d[permrow(n)] = a[n] + b[n];
}
__global__ void k_b2sum(const float* __restrict__ Wih2, const float* __restrict__ bmid,
                        const float* __restrict__ bih2, const float* __restrict__ bhh2,
                        float* __restrict__ d) {
  int row = blockIdx.x * 4 + (threadIdx.x >> 6);
  int lane = threadIdx.x & 63;
  const float* wr = Wih2 + (size_t)row * 1024;
  float s = 0.f;
  for (int k = lane; k < 1024; k += 64) s += wr[k] * bmid[k];
#pragma unroll
  for (int o = 32; o > 0; o >>= 1) s += __shfl_down(s, o);
  if (lane == 0) d[permrow(row)] = s + bih2[row] + bhh2[row];
}

extern "C" void kernel_launch(void* const* d_in, const int* in_sizes, int n_in,
                              void* d_out, int out_size, void* d_ws, size_t ws_size,
                              hipStream_t stream) {
  const float* x    = (const float*)d_in[0];
  const float* Wih1 = (const float*)d_in[1];
  const float* Whh1 = (const float*)d_in[2];
  const float* bih1 = (const float*)d_in[3];
  const float* bhh1 = (const float*)d_in[4];
  const float* Wmid = (const float*)d_in[5];
  const float* bmid = (const float*)d_in[6];
  const float* Wih2 = (const float*)d_in[7];
  const float* Whh2 = (const float*)d_in[8];
  const float* bih2 = (const float*)d_in[9];
  const float* bhh2 = (const float*)d_in[10];
  const float* Wfin = (const float*)d_in[11];
  const float* bfin = (const float*)d_in[12];

  const size_t SZ_XBF = (size_t)TSTEPS * BSZ * 128 * 2;
  const size_t SZ_W1A = (size_t)4096 * 128 * 2;
  const size_t SZ_W1K = (size_t)4096 * 1024 * 2;
  const size_t SZ_WMT = (size_t)1024 * 1024 * 2;
  const size_t SZ_WFB = (size_t)128 * 1024 * 2;
  const size_t SZ_BSM = (size_t)4096 * 4;
  const size_t SZ_HB  = (size_t)BSZ * HDIM * 2;
  const size_t SZ_CF  = (size_t)BSZ * HDIM * 4;
  const size_t SZ_U2  = (size_t)BSZ * 4096 * 2;
  const size_t SZ_C2S = (size_t)TSTEPS * BSZ * HDIM * 2;

  char* base = (char*)d_ws;
  size_t off = 0;
  auto alloc = [&](size_t b) { char* p = base + off; off += (b + 255) & ~(size_t)255; return p; };

  u16*   Xbf    = (u16*)alloc(SZ_XBF);
  u16*   W1a    = (u16*)alloc(SZ_W1A);
  u16*   Whh1b  = (u16*)alloc(SZ_W1K);
  u16*   Wcombb = (u16*)alloc(SZ_W1K);
  u16*   Whh2b  = (u16*)alloc(SZ_W1K);
  u16*   Wih2b  = (u16*)alloc(SZ_W1K);
  u16*   WmidT  = (u16*)alloc(SZ_WMT);
  u16*   Wfinb  = (u16*)alloc(SZ_WFB);
  float* b1s    = (float*)alloc(SZ_BSM);
  float* b2s    = (float*)alloc(SZ_BSM);
  u16*   H1p[2]; H1p[0] = (u16*)alloc(SZ_HB); H1p[1] = (u16*)alloc(SZ_HB);
  u16*   H2p[2]; H2p[0] = (u16*)alloc(SZ_HB); H2p[1] = (u16*)alloc(SZ_HB);
  float* C1f    = (float*)alloc(SZ_CF);
  float* C2f    = (float*)alloc(SZ_CF);
  u16*   C1b    = (u16*)alloc(SZ_HB);
  u16*   C2b    = (u16*)alloc(SZ_HB);
  u16*   U2     = (u16*)alloc(SZ_U2);
  unsigned* barp = (unsigned*)alloc(256);
  u16*   C2seq  = (u16*)(base + off);
  bool batched  = (off + SZ_C2S) <= ws_size;

  // zero states: H1p0,H1p1,H2p0,H2p1,C1f,C2f contiguous (256-aligned sizes)
  size_t zbytes = 4 * SZ_HB + 2 * SZ_CF;
  hipMemsetAsync((void*)H1p[0], 0, zbytes, stream);
  hipMemsetAsync((void*)barp, 0, 256, stream);

  k_build_w1a<<<2048, 256, 0, stream>>>(Wih1, W1a);
  k_conv_perm1024<<<16384, 256, 0, stream>>>(Whh1, Whh1b);
  k_conv_perm1024<<<16384, 256, 0, stream>>>(Whh2, Whh2b);
  k_conv<<<16384, 256, 0, stream>>>(Wih2, Wih2b);
  k_transpose1024<<<4096, 256, 0, stream>>>(Wmid, WmidT);
  k_build_wfin<<<512, 256, 0, stream>>>(Wfin, Wfinb);
  k_build_xpad<<<46080, 256, 0, stream>>>(x, Xbf);
  k_b1sum<<<16, 256, 0, stream>>>(bih1, bhh1, b1s);
  k_b2sum<<<1024, 256, 0, stream>>>(Wih2, bmid, bih2, bhh2, b2s);
  wcomb_gemm<<<dim3(8, 64), 256, 0, stream>>>(Wih2b, WmidT, Wcombb);

  bool usedPersistent = false;
  if (batched) {
    u16* H1x = H1p[0]; u16* H1y = H1p[1];
    u16* H2x = H2p[0]; u16* H2y = H2p[1];
    void* kargs[] = {
        (void*)&Xbf, (void*)&W1a, (void*)&Whh1b, (void*)&b1s,
        (void*)&C1f, (void*)&C1b, (void*)&Whh2b, (void*)&b2s,
        (void*)&U2, (void*)&Wcombb, (void*)&C2f, (void*)&C2seq,
        (void*)&H1x, (void*)&H1y, (void*)&H2x, (void*)&H2y,
        (void*)&barp};
    hipError_t ce = hipLaunchCooperativeKernel(
        (const void*)lstm_persistent, dim3(NBLK), dim3(256), kargs, 0, stream);
    usedPersistent = (ce == hipSuccess);
    if (!usedPersistent) (void)hipGetLastError();  // clear sticky error for fallback
  }

  if (usedPersistent) {
    final_logsoftmax<<<dim3(1, (TSTEPS * BSZ) / 64), 256, 0, stream>>>(
        C2seq, Wfinb, bfin, (float*)d_out);
  } else {
    for (int t = 0; t < TSTEPS; ++t) {
      int p = t & 1;
      k1_fused<<<256, 256, 0, stream>>>(
          Xbf + (size_t)t * BSZ * 128, W1a, H1p[p], Whh1b, b1s, C1f,
          H1p[p ^ 1], C1b, H2p[p], Whh2b, b2s, U2);
      u16* c2dst = batched ? (C2seq + (size_t)t * BSZ * HDIM) : C2b;
      k2_cell2<<<128, 256, 0, stream>>>(C1b, Wcombb, U2, C2f, H2p[p ^ 1], c2dst);
      if (!batched)
        final_logsoftmax<<<dim3(1, 8), 256, 0, stream>>>(
            C2b, Wfinb, bfin, (float*)d_out + (size_t)t * BSZ * VOUT);
    }
    if (batched)
      final_logsoftmax<<<dim3(1, (TSTEPS * BSZ) / 64), 256, 0, stream>>>(
          C2seq, Wfinb, bfin, (float*)d_out);
  }
}

// Round 5
// 11952.359 us; speedup vs baseline: 1.5042x; 1.5042x over previous
//
#include <hip/hip_runtime.h>
#include <stdint.h>

// LSTM_34359738368754: 2-layer LSTM, T=180 B=512 H=1024 I=V=108.
// R5: persistent cooperative kernel + XCD-leader-fenced grid barrier.
//  - R4 measured 17.98ms (2.4x WORSE than R3 7.58ms): MfmaUtil 5.5%,
//    ~98us/step vs ~15us compute -> ~40us per grid_sync. Cause: every one
//    of 256 blocks ran __threadfence() = buffer_wbl2+buffer_inv sc1, a full
//    4MB L2 tag-walk; 32 serialized walks per XCD per barrier.
//  - R5: only the LAST-arriving block per XCD fences (1 wbl2+inv per XCD,
//    parallel across 8 XCDs). All blocks' stores are already drained to L2
//    by __syncthreads (compiler emits s_waitcnt vmcnt(0) before s_barrier);
//    leader's cache-wide wbl2/inv covers the whole XCD. Per-CU L1 staleness
//    handled by a cheap per-block "buffer_inv sc0" after the gen flip.
//  - XCD id via s_getreg(HW_REG_XCC_ID) (HW-verified, learn_hip m09);
//    per-XCD populations counted once in a prologue full barrier.
//  - Everything else identical to R4 (phase A gates1/U2, phase B 128x64).

typedef unsigned short u16;
typedef __attribute__((ext_vector_type(4))) float f32x4;
typedef __attribute__((ext_vector_type(8))) short bf16x8;

#define HDIM 1024
#define BSZ  512
#define TSTEPS 180
#define IIN  108
#define VOUT 108
#define NBLK 256

__device__ __forceinline__ u16 f2bf(float x) {
  union { float f; unsigned u; } v; v.f = x;
  unsigned r = (v.u + 0x7fffu + ((v.u >> 16) & 1u)) >> 16;  // RNE
  return (u16)r;
}
__device__ __forceinline__ float bf2f(u16 b) {
  union { unsigned u; float f; } v; v.u = ((unsigned)b) << 16; return v.f;
}
__device__ __forceinline__ float sigm(float x) { return 1.f / (1.f + __expf(-x)); }
__device__ __forceinline__ float tanh_(float x) {
  float a = fabsf(x), t = __expf(-2.f * a);
  float r = (1.f - t) / (1.f + t);
  return x < 0.f ? -r : r;
}
__device__ __forceinline__ int permrow(int n) { return ((n & 1023) << 2) | (n >> 10); }

__device__ __forceinline__ void load16_lds(const void* g, void* l) {
  __builtin_amdgcn_global_load_lds(
      (const __attribute__((address_space(1))) unsigned int*)g,
      (__attribute__((address_space(3))) unsigned int*)l, 16, 0, 0);
}

// ---------------- grid barriers (cooperative launch) ----------------
// bar layout (u32): [0]=leader/arrival cnt, [1]=generation, [2]=nxcd,
//                   [4..11]=per-XCD arrival cnt, [12..19]=per-XCD population.

// Full barrier: every block fences. Slow (~40us) — used ONCE in prologue.
__device__ __forceinline__ void grid_sync_full(unsigned* bar) {
  __syncthreads();
  if (threadIdx.x == 0) {
    __threadfence();
    unsigned g = __hip_atomic_load(bar + 1, __ATOMIC_RELAXED, __HIP_MEMORY_SCOPE_AGENT);
    unsigned a = __hip_atomic_fetch_add(bar, 1u, __ATOMIC_ACQ_REL, __HIP_MEMORY_SCOPE_AGENT);
    if (a == (unsigned)(NBLK - 1)) {
      __hip_atomic_store(bar, 0u, __ATOMIC_RELAXED, __HIP_MEMORY_SCOPE_AGENT);
      __hip_atomic_store(bar + 1, g + 1u, __ATOMIC_RELEASE, __HIP_MEMORY_SCOPE_AGENT);
    } else {
      while (__hip_atomic_load(bar + 1, __ATOMIC_RELAXED, __HIP_MEMORY_SCOPE_AGENT) == g)
        __builtin_amdgcn_s_sleep(1);
    }
    __threadfence();
  }
  __syncthreads();
}

// Leader barrier: last arriver per XCD runs the (cache-wide) fence; others
// only do a cheap L1 invalidate after the generation flips.
__device__ __forceinline__ void grid_sync_x(unsigned* bar, int xcd,
                                            unsigned xpop, unsigned nxcd) {
  __syncthreads();  // drains all waves' stores to L2 (vmcnt(0) before s_barrier)
  if (threadIdx.x == 0) {
    unsigned g = __hip_atomic_load(bar + 1, __ATOMIC_RELAXED, __HIP_MEMORY_SCOPE_AGENT);
    asm volatile("" ::: "memory");  // keep gen-read before arrival
    unsigned a = __hip_atomic_fetch_add(bar + 4 + xcd, 1u, __ATOMIC_RELAXED,
                                        __HIP_MEMORY_SCOPE_AGENT);
    if (a + 1u == xpop) {  // last block on this XCD
      __hip_atomic_store(bar + 4 + xcd, 0u, __ATOMIC_RELAXED, __HIP_MEMORY_SCOPE_AGENT);
      __threadfence();     // wbl2+inv sc1: flush+inv THIS XCD's L2 (covers all 32 blocks)
      unsigned c = __hip_atomic_fetch_add(bar, 1u, __ATOMIC_RELAXED,
                                          __HIP_MEMORY_SCOPE_AGENT);
      if (c + 1u == nxcd) {  // last XCD leader: release the grid
        __hip_atomic_store(bar, 0u, __ATOMIC_RELAXED, __HIP_MEMORY_SCOPE_AGENT);
        asm volatile("s_waitcnt vmcnt(0)" ::: "memory");  // cnt reset lands first
        __hip_atomic_store(bar + 1, g + 1u, __ATOMIC_RELAXED, __HIP_MEMORY_SCOPE_AGENT);
      }
    }
    while (__hip_atomic_load(bar + 1, __ATOMIC_RELAXED, __HIP_MEMORY_SCOPE_AGENT) == g)
      __builtin_amdgcn_s_sleep(1);
    asm volatile("buffer_inv sc0" ::: "memory");  // drop stale L1 lines (this CU)
  }
  __syncthreads();
}

// ================= 128x128 double-buffered GEMM =================
// smem: buf b at smem + b*32768; As 16KB then Bs 16KB. BK=64.
// LDS chunk swizzle: physical chunk pc holds logical chunk pc^(row&7).
__device__ __forceinline__ void stage128(const u16* A, const u16* B, int K,
                                         int k0, int m0, int n0,
                                         char* smem, int buf, int wave, int lane) {
  u16* As = (u16*)(smem + buf * 32768);
  u16* Bs = (u16*)(smem + buf * 32768 + 16384);
#pragma unroll
  for (int i = 0; i < 4; ++i) {
    int c = (wave * 4 + i) * 64 + lane;
    int row = c >> 3, lc = (c & 7) ^ (row & 7);     // swizzled source chunk
    const u16* g = A + (size_t)(m0 + row) * K + k0 + (lc << 3);
    load16_lds(g, As + c * 8);
  }
#pragma unroll
  for (int i = 0; i < 4; ++i) {
    int c = (wave * 4 + i) * 64 + lane;
    int row = c >> 3, lc = (c & 7) ^ (row & 7);
    const u16* g = B + (size_t)(n0 + row) * K + k0 + (lc << 3);
    load16_lds(g, Bs + c * 8);
  }
}

__device__ __forceinline__ void compute128(f32x4 acc[4][4], char* smem, int buf,
                                           int wm, int wn, int l16, int quad) {
  const bf16x8* Av = (const bf16x8*)(smem + buf * 32768);
  const bf16x8* Bv = (const bf16x8*)(smem + buf * 32768 + 16384);
  const int sw = l16 & 7;
#pragma unroll
  for (int kk = 0; kk < 2; ++kk) {
    const int pc = (kk * 4 + quad) ^ sw;            // swizzled chunk
    bf16x8 a[4], b[4];
#pragma unroll
    for (int mt = 0; mt < 4; ++mt)
      a[mt] = Av[(wm * 64 + mt * 16 + l16) * 8 + pc];
#pragma unroll
    for (int nt = 0; nt < 4; ++nt)
      b[nt] = Bv[(wn * 64 + nt * 16 + l16) * 8 + pc];
#pragma unroll
    for (int mt = 0; mt < 4; ++mt)
#pragma unroll
      for (int nt = 0; nt < 4; ++nt)
        acc[mt][nt] = __builtin_amdgcn_mfma_f32_16x16x32_bf16(
            a[mt], b[nt], acc[mt][nt], 0, 0, 0);
  }
}

// acc(128x128) at (m0,n0) = A0@B0^T (K0, optional) + A1@B1^T (K1).
template <bool HAS0>
__device__ __forceinline__ void gemm128(f32x4 acc[4][4],
    const u16* A0, const u16* B0, int K0,
    const u16* A1, const u16* B1, int K1,
    int m0, int n0, char* smem) {
  const int tid = threadIdx.x;
  const int lane = tid & 63, wave = tid >> 6;
  const int quad = lane >> 4, l16 = lane & 15;
  const int wm = wave >> 1, wn = wave & 1;

#pragma unroll
  for (int mt = 0; mt < 4; ++mt)
#pragma unroll
    for (int nt = 0; nt < 4; ++nt) {
      f32x4 z = {0.f, 0.f, 0.f, 0.f};
      acc[mt][nt] = z;
    }

  const int n0i = HAS0 ? (K0 >> 6) : 0;
  const int nIter = n0i + (K1 >> 6);

  // prologue: stage iter 0 into buf 0
  if (HAS0 && n0i > 0)
    stage128(A0, B0, K0, 0, m0, n0, smem, 0, wave, lane);
  else
    stage128(A1, B1, K1, 0, m0, n0, smem, 0, wave, lane);

  for (int it = 0; it < nIter; ++it) {
    if (it + 1 < nIter) {
      int nx = it + 1;
      if (HAS0 && nx < n0i)
        stage128(A0, B0, K0, nx * 64, m0, n0, smem, nx & 1, wave, lane);
      else
        stage128(A1, B1, K1, (nx - n0i) * 64, m0, n0, smem, nx & 1, wave, lane);
      __builtin_amdgcn_s_waitcnt(0xF78);  // vmcnt(8): prev stage landed
    } else {
      __builtin_amdgcn_s_waitcnt(0xF70);  // vmcnt(0)
    }
    __builtin_amdgcn_s_barrier();
    asm volatile("" ::: "memory");
    compute128(acc, smem, it & 1, wm, wn, l16, quad);
    asm volatile("" ::: "memory");
    __builtin_amdgcn_s_barrier();  // all waves done reading buf before overwrite
  }
}

// ============ phase-B 128x64 double-buffered GEMM (persistent kernel) ============
// buf b at smem + b*24576; As (128 rows) 16KB then Bs (64 rows) 8KB. BK=64.
__device__ __forceinline__ void stage_pb(const u16* A, const u16* B, int k0,
                                         int m0, int n0, char* smem, int buf,
                                         int wave, int lane) {
  u16* As = (u16*)(smem + buf * 24576);
  u16* Bs = (u16*)(smem + buf * 24576 + 16384);
#pragma unroll
  for (int i = 0; i < 4; ++i) {
    int c = (wave * 4 + i) * 64 + lane;               // 1024 chunks = 128 rows
    int row = c >> 3, lc = (c & 7) ^ (row & 7);
    load16_lds(A + (size_t)(m0 + row) * 1024 + k0 + (lc << 3), As + c * 8);
  }
#pragma unroll
  for (int i = 0; i < 2; ++i) {
    int c = (wave * 2 + i) * 64 + lane;               // 512 chunks = 64 rows
    int row = c >> 3, lc = (c & 7) ^ (row & 7);
    load16_lds(B + (size_t)(n0 + row) * 1024 + k0 + (lc << 3), Bs + c * 8);
  }
}

__device__ __forceinline__ void compute_pb(f32x4 acc[4][2], char* smem, int buf,
                                           int wm, int wn, int l16, int quad) {
  const bf16x8* Av = (const bf16x8*)(smem + buf * 24576);
  const bf16x8* Bv = (const bf16x8*)(smem + buf * 24576 + 16384);
  const int sw = l16 & 7;
#pragma unroll
  for (int kk = 0; kk < 2; ++kk) {
    const int pc = (kk * 4 + quad) ^ sw;
    bf16x8 a[4], b[2];
#pragma unroll
    for (int mt = 0; mt < 4; ++mt)
      a[mt] = Av[(wm * 64 + mt * 16 + l16) * 8 + pc];
#pragma unroll
    for (int nt = 0; nt < 2; ++nt)
      b[nt] = Bv[(wn * 32 + nt * 16 + l16) * 8 + pc];
#pragma unroll
    for (int mt = 0; mt < 4; ++mt)
#pragma unroll
      for (int nt = 0; nt < 2; ++nt)
        acc[mt][nt] = __builtin_amdgcn_mfma_f32_16x16x32_bf16(
            a[mt], b[nt], acc[mt][nt], 0, 0, 0);
  }
}

// ================= persistent whole-sequence kernel =================
__global__ __launch_bounds__(256, 1) void lstm_persistent(
    const u16* __restrict__ Xbf, const u16* __restrict__ W1a,
    const u16* __restrict__ Whh1b, const float* __restrict__ b1s,
    float* __restrict__ C1f, u16* __restrict__ C1b,
    const u16* __restrict__ Whh2b, const float* __restrict__ b2s,
    u16* __restrict__ U2, const u16* __restrict__ Wcombb,
    float* __restrict__ C2f, u16* __restrict__ C2seq,
    u16* __restrict__ H1x, u16* __restrict__ H1y,
    u16* __restrict__ H2x, u16* __restrict__ H2y,
    unsigned* __restrict__ bar)
{
  __shared__ __align__(16) char smem[65536];
  const int tid = threadIdx.x;
  const int lane = tid & 63, wave = tid >> 6;
  const int quad = lane >> 4, l16 = lane & 15;
  const int wm = wave >> 1, wn = wave & 1;
  const int b = blockIdx.x;

  // ---- prologue: XCD census (populations + #XCDs), one full barrier ----
  int xcd = 0;
  unsigned xpop = 0, nxcd = 0;
  if (tid == 0) {
    asm volatile("s_getreg_b32 %0, hwreg(HW_REG_XCC_ID)" : "=s"(xcd));
    xcd &= 7;
    unsigned old = __hip_atomic_fetch_add(bar + 12 + xcd, 1u, __ATOMIC_RELAXED,
                                          __HIP_MEMORY_SCOPE_AGENT);
    if (old == 0u)
      __hip_atomic_fetch_add(bar + 2, 1u, __ATOMIC_RELAXED, __HIP_MEMORY_SCOPE_AGENT);
  }
  grid_sync_full(bar);
  if (tid == 0) {
    xpop = __hip_atomic_load(bar + 12 + xcd, __ATOMIC_RELAXED, __HIP_MEMORY_SCOPE_AGENT);
    nxcd = __hip_atomic_load(bar + 2, __ATOMIC_RELAXED, __HIP_MEMORY_SCOPE_AGENT);
  }

  for (int t = 0; t < TSTEPS; ++t) {
    const int p = t & 1;
    const u16* H1in = p ? H1y : H1x;  u16* H1o = p ? H1x : H1y;
    const u16* H2in = p ? H2y : H2x;  u16* H2o = p ? H2x : H2y;
    const u16* Xt = Xbf + (size_t)t * BSZ * 128;

    // ---------------- phase A ----------------
    if (b < 128) {
      f32x4 acc[4][4];
      const int m0 = (b >> 5) * 128, n0 = (b & 31) * 128;
      gemm128<true>(acc, Xt, W1a, 128, H1in, Whh1b, 1024, m0, n0, smem);

      float* gl = (float*)smem;  // [64][132]
      const int jbase = (b & 31) * 32;
#pragma unroll
      for (int h = 0; h < 2; ++h) {
        __syncthreads();
        if (wm == h) {
#pragma unroll
          for (int nt = 0; nt < 4; ++nt) {
            int col = wn * 64 + nt * 16 + l16;
#pragma unroll
            for (int mt = 0; mt < 4; ++mt) {
              int rowb = mt * 16 + quad * 4;
#pragma unroll
              for (int r = 0; r < 4; ++r)
                gl[(rowb + r) * 132 + col] = acc[mt][nt][r];
            }
          }
        }
        __syncthreads();
#pragma unroll
        for (int itr = 0; itr < 8; ++itr) {
          int idx = itr * 256 + tid;
          int mr = idx >> 5, jl = idx & 31;
          f32x4 g4 = *(const f32x4*)(gl + mr * 132 + jl * 4);
          f32x4 b4 = *(const f32x4*)(b1s + jbase * 4 + jl * 4);
          g4 += b4;
          float ii = sigm(g4[0]), ff = sigm(g4[1]);
          float gg = tanh_(g4[2]), oo = sigm(g4[3]);
          size_t off = (size_t)(m0 + h * 64 + mr) * HDIM + jbase + jl;
          float cp = C1f[off];
          float cn = ff * cp + ii * gg;
          float hh = oo * tanh_(cn);
          C1f[off] = cn;
          H1o[off] = f2bf(hh);
          C1b[off] = f2bf(cn);
        }
      }
    } else {
      f32x4 acc[4][4];
      const int bb = b - 128;
      const int m0 = (bb >> 5) * 128, n0 = (bb & 31) * 128;
      gemm128<false>(acc, nullptr, nullptr, 0, H2in, Whh2b, 1024, m0, n0, smem);
#pragma unroll
      for (int nt = 0; nt < 4; ++nt) {
        int col = n0 + wn * 64 + nt * 16 + l16;
        float bias = b2s[col];
#pragma unroll
        for (int mt = 0; mt < 4; ++mt) {
          int row = m0 + wm * 64 + mt * 16 + quad * 4;
#pragma unroll
          for (int r = 0; r < 4; ++r)
            U2[(size_t)(row + r) * 4096 + col] = f2bf(acc[mt][nt][r] + bias);
        }
      }
    }
    grid_sync_x(bar, xcd, xpop, nxcd);

    // ---------------- phase B: gates2 = c1@Wcomb^T + U2, 128x64 tiles ----------------
    {
      f32x4 acc[4][2];
#pragma unroll
      for (int mt = 0; mt < 4; ++mt)
#pragma unroll
        for (int nt = 0; nt < 2; ++nt) {
          f32x4 z = {0.f, 0.f, 0.f, 0.f};
          acc[mt][nt] = z;
        }
      const int m0 = (b >> 6) * 128;        // 4 m-tiles
      const int n0 = (b & 63) * 64;         // 64 n-tiles
      const int jbase = (b & 63) * 16;

      stage_pb(C1b, Wcombb, 0, m0, n0, smem, 0, wave, lane);
      for (int it = 0; it < 16; ++it) {
        if (it + 1 < 16) {
          stage_pb(C1b, Wcombb, (it + 1) * 64, m0, n0, smem, (it + 1) & 1, wave, lane);
          __builtin_amdgcn_s_waitcnt(0xF76);  // vmcnt(6): prev stage landed
        } else {
          __builtin_amdgcn_s_waitcnt(0xF70);  // vmcnt(0)
        }
        __builtin_amdgcn_s_barrier();
        asm volatile("" ::: "memory");
        compute_pb(acc, smem, it & 1, wm, wn, l16, quad);
        asm volatile("" ::: "memory");
        __builtin_amdgcn_s_barrier();
      }

      float* gl = (float*)smem;  // [128][68]
      __syncthreads();
#pragma unroll
      for (int nt = 0; nt < 2; ++nt) {
        int col = wn * 32 + nt * 16 + l16;
#pragma unroll
        for (int mt = 0; mt < 4; ++mt) {
          int rowb = wm * 64 + mt * 16 + quad * 4;
#pragma unroll
          for (int r = 0; r < 4; ++r)
            gl[(rowb + r) * 68 + col] = acc[mt][nt][r];
        }
      }
      __syncthreads();
      u16* C2dst = C2seq + (size_t)t * BSZ * HDIM;
#pragma unroll
      for (int itr = 0; itr < 8; ++itr) {
        int idx = itr * 256 + tid;
        int mr = idx >> 4, jl = idx & 15;
        int grow = m0 + mr;
        f32x4 g4 = *(const f32x4*)(gl + mr * 68 + jl * 4);
        const u16* u2p = U2 + (size_t)grow * 4096 + (jbase + jl) * 4;
        g4[0] += bf2f(u2p[0]); g4[1] += bf2f(u2p[1]);
        g4[2] += bf2f(u2p[2]); g4[3] += bf2f(u2p[3]);
        float ii = sigm(g4[0]), ff = sigm(g4[1]);
        float gg = tanh_(g4[2]), oo = sigm(g4[3]);
        size_t off = (size_t)grow * HDIM + jbase + jl;
        float cp = C2f[off];
        float cn = ff * cp + ii * gg;
        float hh = oo * tanh_(cn);
        C2f[off] = cn;
        H2o[off] = f2bf(hh);
        C2dst[off] = f2bf(cn);
      }
    }
    grid_sync_x(bar, xcd, xpop, nxcd);
  }
}

// ============ fallback per-step kernels (old path) ============
__global__ __launch_bounds__(256, 1) void k1_fused(
    const u16* __restrict__ Xt, const u16* __restrict__ W1a,
    const u16* __restrict__ H1in, const u16* __restrict__ Whh1,
    const float* __restrict__ b1s, float* __restrict__ c1State,
    u16* __restrict__ H1out, u16* __restrict__ C1out,
    const u16* __restrict__ H2in, const u16* __restrict__ Whh2,
    const float* __restrict__ b2s, u16* __restrict__ U2)
{
  __shared__ __align__(16) char smem[65536];
  const int tid = threadIdx.x;
  const int lane = tid & 63, wave = tid >> 6;
  const int quad = lane >> 4, l16 = lane & 15;
  const int wm = wave >> 1, wn = wave & 1;
  const int b = blockIdx.x;
  f32x4 acc[4][4];

  if (b < 128) {
    const int m0 = (b >> 5) * 128, n0 = (b & 31) * 128;
    gemm128<true>(acc, Xt, W1a, 128, H1in, Whh1, 1024, m0, n0, smem);

    float* gl = (float*)smem;  // [64][132]
    const int jbase = (b & 31) * 32;
#pragma unroll
    for (int h = 0; h < 2; ++h) {
      __syncthreads();
      if (wm == h) {
#pragma unroll
        for (int nt = 0; nt < 4; ++nt) {
          int col = wn * 64 + nt * 16 + l16;
#pragma unroll
          for (int mt = 0; mt < 4; ++mt) {
            int rowb = mt * 16 + quad * 4;
#pragma unroll
            for (int r = 0; r < 4; ++r)
              gl[(rowb + r) * 132 + col] = acc[mt][nt][r];
          }
        }
      }
      __syncthreads();
#pragma unroll
      for (int itr = 0; itr < 8; ++itr) {
        int idx = itr * 256 + tid;
        int mr = idx >> 5, jl = idx & 31;
        f32x4 g4 = *(const f32x4*)(gl + mr * 132 + jl * 4);
        f32x4 b4 = *(const f32x4*)(b1s + jbase * 4 + jl * 4);
        g4 += b4;
        float ii = sigm(g4[0]), ff = sigm(g4[1]);
        float gg = tanh_(g4[2]), oo = sigm(g4[3]);
        size_t off = (size_t)(m0 + h * 64 + mr) * HDIM + jbase + jl;
        float cp = c1State[off];
        float cn = ff * cp + ii * gg;
        float hh = oo * tanh_(cn);
        c1State[off] = cn;
        H1out[off] = f2bf(hh);
        C1out[off] = f2bf(cn);
      }
    }
  } else {
    const int bb = b - 128;
    const int m0 = (bb >> 5) * 128, n0 = (bb & 31) * 128;
    gemm128<false>(acc, nullptr, nullptr, 0, H2in, Whh2, 1024, m0, n0, smem);
#pragma unroll
    for (int nt = 0; nt < 4; ++nt) {
      int col = n0 + wn * 64 + nt * 16 + l16;
      float bias = b2s[col];
#pragma unroll
      for (int mt = 0; mt < 4; ++mt) {
        int row = m0 + wm * 64 + mt * 16 + quad * 4;
#pragma unroll
        for (int r = 0; r < 4; ++r)
          U2[(size_t)(row + r) * 4096 + col] = f2bf(acc[mt][nt][r] + bias);
      }
    }
  }
}

__global__ __launch_bounds__(256, 1) void k2_cell2(
    const u16* __restrict__ C1b, const u16* __restrict__ Wcomb,
    const u16* __restrict__ U2, float* __restrict__ c2State,
    u16* __restrict__ H2out, u16* __restrict__ C2out)
{
  __shared__ __align__(16) char smem[65536];
  const int tid = threadIdx.x;
  const int lane = tid & 63, wave = tid >> 6;
  const int quad = lane >> 4, l16 = lane & 15;
  const int wm = wave >> 1, wn = wave & 1;
  const int b = blockIdx.x;
  const int m0 = (b >> 5) * 128, n0 = (b & 31) * 128;
  f32x4 acc[4][4];
  gemm128<false>(acc, nullptr, nullptr, 0, C1b, Wcomb, 1024, m0, n0, smem);

  float* gl = (float*)smem;
  const int jbase = (b & 31) * 32;
#pragma unroll
  for (int h = 0; h < 2; ++h) {
    __syncthreads();
    if (wm == h) {
#pragma unroll
      for (int nt = 0; nt < 4; ++nt) {
        int col = wn * 64 + nt * 16 + l16;
#pragma unroll
        for (int mt = 0; mt < 4; ++mt) {
          int rowb = mt * 16 + quad * 4;
#pragma unroll
          for (int r = 0; r < 4; ++r)
            gl[(rowb + r) * 132 + col] = acc[mt][nt][r];
        }
      }
    }
    __syncthreads();
#pragma unroll
    for (int itr = 0; itr < 8; ++itr) {
      int idx = itr * 256 + tid;
      int mr = idx >> 5, jl = idx & 31;
      int grow = m0 + h * 64 + mr;
      f32x4 g4 = *(const f32x4*)(gl + mr * 132 + jl * 4);
      const u16* u2p = U2 + (size_t)grow * 4096 + jbase * 4 + jl * 4;
      g4[0] += bf2f(u2p[0]); g4[1] += bf2f(u2p[1]);
      g4[2] += bf2f(u2p[2]); g4[3] += bf2f(u2p[3]);
      float ii = sigm(g4[0]), ff = sigm(g4[1]);
      float gg = tanh_(g4[2]), oo = sigm(g4[3]);
      size_t off = (size_t)grow * HDIM + jbase + jl;
      float cp = c2State[off];
      float cn = ff * cp + ii * gg;
      float hh = oo * tanh_(cn);
      c2State[off] = cn;
      H2out[off] = f2bf(hh);
      C2out[off] = f2bf(cn);
    }
  }
}

// ================= 64x128 single-buffered GEMM (wcomb / final) =================
__device__ __forceinline__ void gemm_tile_64x128(
    f32x4 acc[2][4],
    const u16* A0, const u16* B0, int K0,
    const u16* A1, const u16* B1, int K1,
    int m0, int n0, u16* As, u16* Bs)
{
  const int tid  = threadIdx.x;
  const int lane = tid & 63;
  const int wave = tid >> 6;
  const int quad = lane >> 4;
  const int l16  = lane & 15;
  const int wm   = wave >> 1;
  const int wn   = wave & 1;
  const int sw   = l16 & 7;

#pragma unroll
  for (int mt = 0; mt < 2; ++mt)
#pragma unroll
    for (int nt = 0; nt < 4; ++nt) {
      f32x4 z = {0.f, 0.f, 0.f, 0.f};
      acc[mt][nt] = z;
    }

  for (int s = 0; s < 2; ++s) {
    const u16* A = s ? A1 : A0;
    const u16* B = s ? B1 : B0;
    const int  K = s ? K1 : K0;
    for (int k0 = 0; k0 < K; k0 += 64) {
      __syncthreads();
#pragma unroll
      for (int i = 0; i < 2; ++i) {
        int c = (wave * 2 + i) * 64 + lane;
        int row = c >> 3, lc = (c & 7) ^ (row & 7);
        const u16* g = A + (size_t)(m0 + row) * K + k0 + (lc << 3);
        load16_lds(g, As + c * 8);
      }
#pragma unroll
      for (int i = 0; i < 4; ++i) {
        int c = (wave * 4 + i) * 64 + lane;
        int row = c >> 3, lc = (c & 7) ^ (row & 7);
        const u16* g = B + (size_t)(n0 + row) * K + k0 + (lc << 3);
        load16_lds(g, Bs + c * 8);
      }
      __syncthreads();
      const bf16x8* Av = (const bf16x8*)As;
      const bf16x8* Bv = (const bf16x8*)Bs;
#pragma unroll
      for (int kk = 0; kk < 2; ++kk) {
        const int pc = (kk * 4 + quad) ^ sw;
        bf16x8 a[2], b[4];
#pragma unroll
        for (int mt = 0; mt < 2; ++mt)
          a[mt] = Av[(wm * 32 + mt * 16 + l16) * 8 + pc];
#pragma unroll
        for (int nt = 0; nt < 4; ++nt)
          b[nt] = Bv[(wn * 64 + nt * 16 + l16) * 8 + pc];
#pragma unroll
        for (int mt = 0; mt < 2; ++mt)
#pragma unroll
          for (int nt = 0; nt < 4; ++nt)
            acc[mt][nt] = __builtin_amdgcn_mfma_f32_16x16x32_bf16(
                a[mt], b[nt], acc[mt][nt], 0, 0, 0);
      }
    }
  }
  __syncthreads();
}

__global__ __launch_bounds__(256, 2) void wcomb_gemm(
    const u16* __restrict__ A, const u16* __restrict__ Bt, u16* __restrict__ outp)
{
  __shared__ __align__(16) char smem[24576];
  u16* As = (u16*)smem;
  u16* Bs = (u16*)(smem + 8192);
  const int m0 = blockIdx.y * 64;
  const int n0 = blockIdx.x * 128;
  f32x4 acc[2][4];
  gemm_tile_64x128(acc, A, Bt, 1024, nullptr, nullptr, 0, m0, n0, As, Bs);
  const int lane = threadIdx.x & 63;
  const int wave = threadIdx.x >> 6;
  const int quad = lane >> 4, l16 = lane & 15;
  const int wm = wave >> 1, wn = wave & 1;
#pragma unroll
  for (int mt = 0; mt < 2; ++mt)
#pragma unroll
    for (int nt = 0; nt < 4; ++nt)
#pragma unroll
      for (int r = 0; r < 4; ++r) {
        int mr = m0 + wm * 32 + mt * 16 + quad * 4 + r;
        int c  = n0 + wn * 64 + nt * 16 + l16;
        outp[(size_t)permrow(mr) * 1024 + c] = f2bf(acc[mt][nt][r]);
      }
}

__global__ __launch_bounds__(256, 2) void final_logsoftmax(
    const u16* __restrict__ C2, const u16* __restrict__ Wf,
    const float* __restrict__ bfin, float* __restrict__ out)
{
  __shared__ __align__(16) char smem[64 * 132 * 4 + 256];
  u16* As = (u16*)smem;
  u16* Bs = (u16*)(smem + 8192);
  float* gl  = (float*)smem;
  float* lse = (float*)(smem + 64 * 132 * 4);

  const int m0 = blockIdx.y * 64;
  f32x4 acc[2][4];
  gemm_tile_64x128(acc, C2, Wf, 1024, nullptr, nullptr, 0, m0, 0, As, Bs);

  const int tid = threadIdx.x;
  const int lane = tid & 63;
  const int wave = tid >> 6;
  const int quad = lane >> 4, l16 = lane & 15;
  const int wm = wave >> 1, wn = wave & 1;
#pragma unroll
  for (int nt = 0; nt < 4; ++nt) {
    int coll = wn * 64 + nt * 16 + l16;
    float bias = (coll < VOUT) ? bfin[coll] : 0.f;
#pragma unroll
    for (int mt = 0; mt < 2; ++mt) {
      int rowb = wm * 32 + mt * 16 + quad * 4;
#pragma unroll
      for (int r = 0; r < 4; ++r)
        gl[(rowb + r) * 132 + coll] = acc[mt][nt][r] + bias;
    }
  }
  __syncthreads();
  if (tid < 64) {
    const float* row = gl + tid * 132;
    float mx = -1e30f;
    for (int c = 0; c < VOUT; ++c) mx = fmaxf(mx, row[c]);
    float s = 0.f;
    for (int c = 0; c < VOUT; ++c) s += __expf(row[c] - mx);
    lse[tid] = mx + __logf(s);
  }
  __syncthreads();
  for (int idx = tid; idx < 64 * VOUT; idx += 256) {
    int m = idx / VOUT, c = idx - m * VOUT;
    out[(size_t)(m0 + m) * VOUT + c] = gl[m * 132 + c] - lse[m];
  }
}

// ---------------- setup kernels ----------------
__global__ void k_build_w1a(const float* __restrict__ w, u16* __restrict__ d) {
  int idx = blockIdx.x * 256 + threadIdx.x;
  int n = idx >> 7, k = idx & 127;
  float v = (k < IIN) ? w[n * IIN + k] : 0.f;
  d[permrow(n) * 128 + k] = f2bf(v);
}
__global__ void k_conv_perm1024(const float* __restrict__ w, u16* __restrict__ d) {
  int idx = blockIdx.x * 256 + threadIdx.x;
  int n = idx >> 10, k = idx & 1023;
  d[(size_t)permrow(n) * 1024 + k] = f2bf(w[idx]);
}
__global__ void k_conv(const float* __restrict__ s, u16* __restrict__ d) {
  int idx = blockIdx.x * 256 + threadIdx.x;
  d[idx] = f2bf(s[idx]);
}
__global__ void k_transpose1024(const float* __restrict__ s, u16* __restrict__ d) {
  int idx = blockIdx.x * 256 + threadIdx.x;
  int r = idx >> 10, c = idx & 1023;
  d[c * 1024 + r] = f2bf(s[idx]);
}
__global__ void k_build_wfin(const float* __restrict__ w, u16* __restrict__ d) {
  int idx = blockIdx.x * 256 + threadIdx.x;
  int r = idx >> 10, c = idx & 1023;
  d[idx] = (r < VOUT) ? f2bf(w[r * 1024 + c]) : (u16)0;
}
__global__ void k_build_xpad(const float* __restrict__ x, u16* __restrict__ d) {
  int idx = blockIdx.x * 256 + threadIdx.x;
  int row = idx >> 7, k = idx & 127;
  d[idx] = (k < IIN) ? f2bf(x[row * IIN + k]) : (u16)0;
}
__global__ void k_b1sum(const float* __restrict__ a, const float* __restrict__ b,
                        float* __restrict__ d) {
  int n = blockIdx.x * 256 + threadIdx.x;
  d[permrow(n)] = a[n] + b[n];
}
__global__ void k_b2sum(const float* __restrict__ Wih2, const float* __restrict__ bmid,
                        const float* __restrict__ bih2, const float* __restrict__ bhh2,
                        float* __restrict__ d) {
  int row = blockIdx.x * 4 + (threadIdx.x >> 6);
  int lane = threadIdx.x & 63;
  const float* wr = Wih2 + (size_t)row * 1024;
  float s = 0.f;
  for (int k = lane; k < 1024; k += 64) s += wr[k] * bmid[k];
#pragma unroll
  for (int o = 32; o > 0; o >>= 1) s += __shfl_down(s, o);
  if (lane == 0) d[permrow(row)] = s + bih2[row] + bhh2[row];
}

extern "C" void kernel_launch(void* const* d_in, const int* in_sizes, int n_in,
                              void* d_out, int out_size, void* d_ws, size_t ws_size,
                              hipStream_t stream) {
  const float* x    = (const float*)d_in[0];
  const float* Wih1 = (const float*)d_in[1];
  const float* Whh1 = (const float*)d_in[2];
  const float* bih1 = (const float*)d_in[3];
  const float* bhh1 = (const float*)d_in[4];
  const float* Wmid = (const float*)d_in[5];
  const float* bmid = (const float*)d_in[6];
  const float* Wih2 = (const float*)d_in[7];
  const float* Whh2 = (const float*)d_in[8];
  const float* bih2 = (const float*)d_in[9];
  const float* bhh2 = (const float*)d_in[10];
  const float* Wfin = (const float*)d_in[11];
  const float* bfin = (const float*)d_in[12];

  const size_t SZ_XBF = (size_t)TSTEPS * BSZ * 128 * 2;
  const size_t SZ_W1A = (size_t)4096 * 128 * 2;
  const size_t SZ_W1K = (size_t)4096 * 1024 * 2;
  const size_t SZ_WMT = (size_t)1024 * 1024 * 2;
  const size_t SZ_WFB = (size_t)128 * 1024 * 2;
  const size_t SZ_BSM = (size_t)4096 * 4;
  const size_t SZ_HB  = (size_t)BSZ * HDIM * 2;
  const size_t SZ_CF  = (size_t)BSZ * HDIM * 4;
  const size_t SZ_U2  = (size_t)BSZ * 4096 * 2;
  const size_t SZ_C2S = (size_t)TSTEPS * BSZ * HDIM * 2;

  char* base = (char*)d_ws;
  size_t off = 0;
  auto alloc = [&](size_t b) { char* p = base + off; off += (b + 255) & ~(size_t)255; return p; };

  u16*   Xbf    = (u16*)alloc(SZ_XBF);
  u16*   W1a    = (u16*)alloc(SZ_W1A);
  u16*   Whh1b  = (u16*)alloc(SZ_W1K);
  u16*   Wcombb = (u16*)alloc(SZ_W1K);
  u16*   Whh2b  = (u16*)alloc(SZ_W1K);
  u16*   Wih2b  = (u16*)alloc(SZ_W1K);
  u16*   WmidT  = (u16*)alloc(SZ_WMT);
  u16*   Wfinb  = (u16*)alloc(SZ_WFB);
  float* b1s    = (float*)alloc(SZ_BSM);
  float* b2s    = (float*)alloc(SZ_BSM);
  u16*   H1p[2]; H1p[0] = (u16*)alloc(SZ_HB); H1p[1] = (u16*)alloc(SZ_HB);
  u16*   H2p[2]; H2p[0] = (u16*)alloc(SZ_HB); H2p[1] = (u16*)alloc(SZ_HB);
  float* C1f    = (float*)alloc(SZ_CF);
  float* C2f    = (float*)alloc(SZ_CF);
  u16*   C1b    = (u16*)alloc(SZ_HB);
  u16*   C2b    = (u16*)alloc(SZ_HB);
  u16*   U2     = (u16*)alloc(SZ_U2);
  unsigned* barp = (unsigned*)alloc(256);
  u16*   C2seq  = (u16*)(base + off);
  bool batched  = (off + SZ_C2S) <= ws_size;

  // zero states: H1p0,H1p1,H2p0,H2p1,C1f,C2f contiguous (256-aligned sizes)
  size_t zbytes = 4 * SZ_HB + 2 * SZ_CF;
  hipMemsetAsync((void*)H1p[0], 0, zbytes, stream);
  hipMemsetAsync((void*)barp, 0, 256, stream);

  k_build_w1a<<<2048, 256, 0, stream>>>(Wih1, W1a);
  k_conv_perm1024<<<16384, 256, 0, stream>>>(Whh1, Whh1b);
  k_conv_perm1024<<<16384, 256, 0, stream>>>(Whh2, Whh2b);
  k_conv<<<16384, 256, 0, stream>>>(Wih2, Wih2b);
  k_transpose1024<<<4096, 256, 0, stream>>>(Wmid, WmidT);
  k_build_wfin<<<512, 256, 0, stream>>>(Wfin, Wfinb);
  k_build_xpad<<<46080, 256, 0, stream>>>(x, Xbf);
  k_b1sum<<<16, 256, 0, stream>>>(bih1, bhh1, b1s);
  k_b2sum<<<1024, 256, 0, stream>>>(Wih2, bmid, bih2, bhh2, b2s);
  wcomb_gemm<<<dim3(8, 64), 256, 0, stream>>>(Wih2b, WmidT, Wcombb);

  bool usedPersistent = false;
  if (batched) {
    u16* H1x = H1p[0]; u16* H1y = H1p[1];
    u16* H2x = H2p[0]; u16* H2y = H2p[1];
    void* kargs[] = {
        (void*)&Xbf, (void*)&W1a, (void*)&Whh1b, (void*)&b1s,
        (void*)&C1f, (void*)&C1b, (void*)&Whh2b, (void*)&b2s,
        (void*)&U2, (void*)&Wcombb, (void*)&C2f, (void*)&C2seq,
        (void*)&H1x, (void*)&H1y, (void*)&H2x, (void*)&H2y,
        (void*)&barp};
    hipError_t ce = hipLaunchCooperativeKernel(
        (const void*)lstm_persistent, dim3(NBLK), dim3(256), kargs, 0, stream);
    usedPersistent = (ce == hipSuccess);
    if (!usedPersistent) (void)hipGetLastError();  // clear sticky error for fallback
  }

  if (usedPersistent) {
    final_logsoftmax<<<dim3(1, (TSTEPS * BSZ) / 64), 256, 0, stream>>>(
        C2seq, Wfinb, bfin, (float*)d_out);
  } else {
    for (int t = 0; t < TSTEPS; ++t) {
      int p = t & 1;
      k1_fused<<<256, 256, 0, stream>>>(
          Xbf + (size_t)t * BSZ * 128, W1a, H1p[p], Whh1b, b1s, C1f,
          H1p[p ^ 1], C1b, H2p[p], Whh2b, b2s, U2);
      u16* c2dst = batched ? (C2seq + (size_t)t * BSZ * HDIM) : C2b;
      k2_cell2<<<128, 256, 0, stream>>>(C1b, Wcombb, U2, C2f, H2p[p ^ 1], c2dst);
      if (!batched)
        final_logsoftmax<<<dim3(1, 8), 256, 0, stream>>>(
            C2b, Wfinb, bfin, (float*)d_out + (size_t)t * BSZ * VOUT);
    }
    if (batched)
      final_logsoftmax<<<dim3(1, (TSTEPS * BSZ) / 64), 256, 0, stream>>>(
          C2seq, Wfinb, bfin, (float*)d_out);
  }
}

// Round 7
// 7428.623 us; speedup vs baseline: 2.4203x; 1.6090x over previous
//
#include <hip/hip_runtime.h>
#include <stdint.h>

// LSTM_34359738368754: 2-layer LSTM, T=180 B=512 H=1024 I=V=108.
// R6: persistent kernel, FENCE-FREE grid barrier + coherent data paths.
//  - R4: 256 fences/barrier = 40us. R5: 1 fence/XCD = 12.5us/barrier — the
//    floor of ANY cache-wide op is the 4MB L2 tag walk (32768 lines ~ 13.6us).
//  - R6 removes cache maintenance entirely:
//    * cross-block buffers (H1,H2,C1b,U2,C2f,C2seq) use agent-scope stores
//      (sc1 write-through to LLC) and agent-scope / sc1-bypass loads.
//      GEMM A-operand staging uses global_load_lds aux=0x11 (SC0|SC1).
//    * weights/X/biases stay normally cached -> L2-resident ALL 180 steps
//      (R4/R5 re-fetched ~24MB of weights per step after each inv).
//    * grid_sync = pure 2-level counter tree (8 groups x 32, 128B-spread
//      lines, explicit vmcnt(0) ordering, s_sleep spin). No threadfence.
//  - Epilogues restructured to 2-col pairs for 32/64-bit coherent accesses;
//    U2 scatter packs lane pairs via __shfl_xor.

typedef unsigned short u16;
typedef __attribute__((ext_vector_type(2))) float f32x2;
typedef __attribute__((ext_vector_type(4))) float f32x4;
typedef __attribute__((ext_vector_type(8))) short bf16x8;
typedef unsigned long long u64;

#define HDIM 1024
#define BSZ  512
#define TSTEPS 180
#define IIN  108
#define VOUT 108
#define NBLK 256

#define AGENT __HIP_MEMORY_SCOPE_AGENT
#define RLX   __ATOMIC_RELAXED

__device__ __forceinline__ u16 f2bf(float x) {
  union { float f; unsigned u; } v; v.f = x;
  unsigned r = (v.u + 0x7fffu + ((v.u >> 16) & 1u)) >> 16;  // RNE
  return (u16)r;
}
__device__ __forceinline__ float bf2f(unsigned b) {
  union { unsigned u; float f; } v; v.u = (b & 0xffffu) << 16; return v.f;
}
__device__ __forceinline__ float sigm(float x) { return 1.f / (1.f + __expf(-x)); }
__device__ __forceinline__ float tanh_(float x) {
  float a = fabsf(x), t = __expf(-2.f * a);
  float r = (1.f - t) / (1.f + t);
  return x < 0.f ? -r : r;
}
__device__ __forceinline__ int permrow(int n) { return ((n & 1023) << 2) | (n >> 10); }

// aux = CPol: 0 = cached; 0x11 = SC0|SC1 (agent-coherent: bypass L1+L2, hit LLC)
template <int AUX>
__device__ __forceinline__ void load16_lds(const void* g, void* l) {
  __builtin_amdgcn_global_load_lds(
      (const __attribute__((address_space(1))) unsigned int*)g,
      (__attribute__((address_space(3))) unsigned int*)l, 16, 0, AUX);
}

__device__ __forceinline__ void st32(void* p, unsigned v) {
  __hip_atomic_store((unsigned*)p, v, RLX, AGENT);
}
__device__ __forceinline__ void st64(void* p, u64 v) {
  __hip_atomic_store((u64*)p, v, RLX, AGENT);
}
__device__ __forceinline__ u64 ld64(const void* p) {
  return __hip_atomic_load((u64*)p, RLX, AGENT);
}

// ---------------- fence-free grid barrier ----------------
// bar[0]=gen; bar[32]=root; bar[64+g*32]=group-g arrival (128B-separated).
// Release = write-through stores already at LLC when arrival add lands
// (syncthreads drains vmcnt; explicit vmcnt(0) orders protocol steps).
__device__ __forceinline__ void grid_sync(unsigned* bar, int grp) {
  __syncthreads();
  if (threadIdx.x == 0) {
    unsigned* gen  = bar;
    unsigned* root = bar + 32;
    unsigned* gcnt = bar + 64 + grp * 32;
    unsigned g = __hip_atomic_load(gen, RLX, AGENT);
    asm volatile("s_waitcnt vmcnt(0)" ::: "memory");
    unsigned a = __hip_atomic_fetch_add(gcnt, 1u, RLX, AGENT);
    if (a == 31u) {                       // last of this group of 32
      __hip_atomic_store(gcnt, 0u, RLX, AGENT);
      asm volatile("s_waitcnt vmcnt(0)" ::: "memory");
      unsigned c = __hip_atomic_fetch_add(root, 1u, RLX, AGENT);
      if (c == 7u) {                      // last group: release the grid
        __hip_atomic_store(root, 0u, RLX, AGENT);
        asm volatile("s_waitcnt vmcnt(0)" ::: "memory");
        __hip_atomic_store(gen, g + 1u, RLX, AGENT);
      }
    }
    while (__hip_atomic_load(gen, RLX, AGENT) == g)
      __builtin_amdgcn_s_sleep(2);
  }
  __syncthreads();
}

// ================= 128x128 double-buffered GEMM =================
// smem: buf b at smem + b*32768; As 16KB then Bs 16KB. BK=64.
// LDS chunk swizzle: physical chunk pc holds logical chunk pc^(row&7).
// AUXA: cache policy for the A-operand staging loads (B always cached).
template <int AUXA>
__device__ __forceinline__ void stage128(const u16* A, const u16* B, int K,
                                         int k0, int m0, int n0,
                                         char* smem, int buf, int wave, int lane) {
  u16* As = (u16*)(smem + buf * 32768);
  u16* Bs = (u16*)(smem + buf * 32768 + 16384);
#pragma unroll
  for (int i = 0; i < 4; ++i) {
    int c = (wave * 4 + i) * 64 + lane;
    int row = c >> 3, lc = (c & 7) ^ (row & 7);     // swizzled source chunk
    const u16* g = A + (size_t)(m0 + row) * K + k0 + (lc << 3);
    load16_lds<AUXA>(g, As + c * 8);
  }
#pragma unroll
  for (int i = 0; i < 4; ++i) {
    int c = (wave * 4 + i) * 64 + lane;
    int row = c >> 3, lc = (c & 7) ^ (row & 7);
    const u16* g = B + (size_t)(n0 + row) * K + k0 + (lc << 3);
    load16_lds<0>(g, Bs + c * 8);
  }
}

__device__ __forceinline__ void compute128(f32x4 acc[4][4], char* smem, int buf,
                                           int wm, int wn, int l16, int quad) {
  const bf16x8* Av = (const bf16x8*)(smem + buf * 32768);
  const bf16x8* Bv = (const bf16x8*)(smem + buf * 32768 + 16384);
  const int sw = l16 & 7;
#pragma unroll
  for (int kk = 0; kk < 2; ++kk) {
    const int pc = (kk * 4 + quad) ^ sw;            // swizzled chunk
    bf16x8 a[4], b[4];
#pragma unroll
    for (int mt = 0; mt < 4; ++mt)
      a[mt] = Av[(wm * 64 + mt * 16 + l16) * 8 + pc];
#pragma unroll
    for (int nt = 0; nt < 4; ++nt)
      b[nt] = Bv[(wn * 64 + nt * 16 + l16) * 8 + pc];
#pragma unroll
    for (int mt = 0; mt < 4; ++mt)
#pragma unroll
      for (int nt = 0; nt < 4; ++nt)
        acc[mt][nt] = __builtin_amdgcn_mfma_f32_16x16x32_bf16(
            a[mt], b[nt], acc[mt][nt], 0, 0, 0);
  }
}

// acc(128x128) at (m0,n0) = A0@B0^T (K0, optional, cached A) + A1@B1^T (K1,
// coherent A). B operands always cached (weights).
template <bool HAS0>
__device__ __forceinline__ void gemm128(f32x4 acc[4][4],
    const u16* A0, const u16* B0, int K0,
    const u16* A1, const u16* B1, int K1,
    int m0, int n0, char* smem) {
  const int tid = threadIdx.x;
  const int lane = tid & 63, wave = tid >> 6;
  const int quad = lane >> 4, l16 = lane & 15;
  const int wm = wave >> 1, wn = wave & 1;

#pragma unroll
  for (int mt = 0; mt < 4; ++mt)
#pragma unroll
    for (int nt = 0; nt < 4; ++nt) {
      f32x4 z = {0.f, 0.f, 0.f, 0.f};
      acc[mt][nt] = z;
    }

  const int n0i = HAS0 ? (K0 >> 6) : 0;
  const int nIter = n0i + (K1 >> 6);

  // prologue: stage iter 0 into buf 0
  if (HAS0 && n0i > 0)
    stage128<0>(A0, B0, K0, 0, m0, n0, smem, 0, wave, lane);
  else
    stage128<0x11>(A1, B1, K1, 0, m0, n0, smem, 0, wave, lane);

  for (int it = 0; it < nIter; ++it) {
    if (it + 1 < nIter) {
      int nx = it + 1;
      if (HAS0 && nx < n0i)
        stage128<0>(A0, B0, K0, nx * 64, m0, n0, smem, nx & 1, wave, lane);
      else
        stage128<0x11>(A1, B1, K1, (nx - n0i) * 64, m0, n0, smem, nx & 1, wave, lane);
      __builtin_amdgcn_s_waitcnt(0xF78);  // vmcnt(8): prev stage landed
    } else {
      __builtin_amdgcn_s_waitcnt(0xF70);  // vmcnt(0)
    }
    __builtin_amdgcn_s_barrier();
    asm volatile("" ::: "memory");
    compute128(acc, smem, it & 1, wm, wn, l16, quad);
    asm volatile("" ::: "memory");
    __builtin_amdgcn_s_barrier();  // all waves done reading buf before overwrite
  }
}

// ============ phase-B 128x64 double-buffered GEMM (persistent kernel) ============
// buf b at smem + b*24576; As (128 rows) 16KB then Bs (64 rows) 8KB. BK=64.
__device__ __forceinline__ void stage_pb(const u16* A, const u16* B, int k0,
                                         int m0, int n0, char* smem, int buf,
                                         int wave, int lane) {
  u16* As = (u16*)(smem + buf * 24576);
  u16* Bs = (u16*)(smem + buf * 24576 + 16384);
#pragma unroll
  for (int i = 0; i < 4; ++i) {
    int c = (wave * 4 + i) * 64 + lane;               // 1024 chunks = 128 rows
    int row = c >> 3, lc = (c & 7) ^ (row & 7);
    load16_lds<0x11>(A + (size_t)(m0 + row) * 1024 + k0 + (lc << 3), As + c * 8);
  }
#pragma unroll
  for (int i = 0; i < 2; ++i) {
    int c = (wave * 2 + i) * 64 + lane;               // 512 chunks = 64 rows
    int row = c >> 3, lc = (c & 7) ^ (row & 7);
    load16_lds<0>(B + (size_t)(n0 + row) * 1024 + k0 + (lc << 3), Bs + c * 8);
  }
}

__device__ __forceinline__ void compute_pb(f32x4 acc[4][2], char* smem, int buf,
                                           int wm, int wn, int l16, int quad) {
  const bf16x8* Av = (const bf16x8*)(smem + buf * 24576);
  const bf16x8* Bv = (const bf16x8*)(smem + buf * 24576 + 16384);
  const int sw = l16 & 7;
#pragma unroll
  for (int kk = 0; kk < 2; ++kk) {
    const int pc = (kk * 4 + quad) ^ sw;
    bf16x8 a[4], b[2];
#pragma unroll
    for (int mt = 0; mt < 4; ++mt)
      a[mt] = Av[(wm * 64 + mt * 16 + l16) * 8 + pc];
#pragma unroll
    for (int nt = 0; nt < 2; ++nt)
      b[nt] = Bv[(wn * 32 + nt * 16 + l16) * 8 + pc];
#pragma unroll
    for (int mt = 0; mt < 4; ++mt)
#pragma unroll
      for (int nt = 0; nt < 2; ++nt)
        acc[mt][nt] = __builtin_amdgcn_mfma_f32_16x16x32_bf16(
            a[mt], b[nt], acc[mt][nt], 0, 0, 0);
  }
}

// ================= persistent whole-sequence kernel =================
__global__ __launch_bounds__(256, 1) void lstm_persistent(
    const u16* __restrict__ Xbf, const u16* __restrict__ W1a,
    const u16* __restrict__ Whh1b, const float* __restrict__ b1s,
    float* __restrict__ C1f, u16* __restrict__ C1b,
    const u16* __restrict__ Whh2b, const float* __restrict__ b2s,
    u16* __restrict__ U2, const u16* __restrict__ Wcombb,
    float* __restrict__ C2f, u16* __restrict__ C2seq,
    u16* __restrict__ H1x, u16* __restrict__ H1y,
    u16* __restrict__ H2x, u16* __restrict__ H2y,
    unsigned* __restrict__ bar)
{
  __shared__ __align__(16) char smem[65536];
  const int tid = threadIdx.x;
  const int lane = tid & 63, wave = tid >> 6;
  const int quad = lane >> 4, l16 = lane & 15;
  const int wm = wave >> 1, wn = wave & 1;
  const int b = blockIdx.x;
  const int grp = b & 7;

  for (int t = 0; t < TSTEPS; ++t) {
    const int p = t & 1;
    const u16* H1in = p ? H1y : H1x;  u16* H1o = p ? H1x : H1y;
    const u16* H2in = p ? H2y : H2x;  u16* H2o = p ? H2x : H2y;
    const u16* Xt = Xbf + (size_t)t * BSZ * 128;

    // ---------------- phase A ----------------
    if (b < 128) {
      f32x4 acc[4][4];
      const int m0 = (b >> 5) * 128, n0 = (b & 31) * 128;
      gemm128<true>(acc, Xt, W1a, 128, H1in, Whh1b, 1024, m0, n0, smem);

      float* gl = (float*)smem;  // [64][132]
      const int jbase = (b & 31) * 32;
#pragma unroll
      for (int h = 0; h < 2; ++h) {
        __syncthreads();
        if (wm == h) {
#pragma unroll
          for (int nt = 0; nt < 4; ++nt) {
            int col = wn * 64 + nt * 16 + l16;
#pragma unroll
            for (int mt = 0; mt < 4; ++mt) {
              int rowb = mt * 16 + quad * 4;
#pragma unroll
              for (int r = 0; r < 4; ++r)
                gl[(rowb + r) * 132 + col] = acc[mt][nt][r];
            }
          }
        }
        __syncthreads();
        // cell update, 2 cols/thread -> u32 coherent stores
#pragma unroll
        for (int itr = 0; itr < 4; ++itr) {
          int idx = itr * 256 + tid;
          int mr = idx >> 4, jp = idx & 15;
          const float* gp = gl + mr * 132 + jp * 8;
          f32x4 ga = *(const f32x4*)gp;
          f32x4 gb = *(const f32x4*)(gp + 4);
          const float* bp = b1s + jbase * 4 + jp * 8;
          ga += *(const f32x4*)bp;
          gb += *(const f32x4*)(bp + 4);
          size_t off = (size_t)(m0 + h * 64 + mr) * HDIM + jbase + jp * 2;
          f32x2 cp = *(const f32x2*)(C1f + off);      // private, cached
          float c0 = sigm(ga[1]) * cp[0] + sigm(ga[0]) * tanh_(ga[2]);
          float c1 = sigm(gb[1]) * cp[1] + sigm(gb[0]) * tanh_(gb[2]);
          float h0 = sigm(ga[3]) * tanh_(c0);
          float h1 = sigm(gb[3]) * tanh_(c1);
          f32x2 cn = {c0, c1};
          *(f32x2*)(C1f + off) = cn;
          st32(H1o + off, (unsigned)f2bf(h0) | ((unsigned)f2bf(h1) << 16));
          st32(C1b + off, (unsigned)f2bf(c0) | ((unsigned)f2bf(c1) << 16));
        }
      }
    } else {
      f32x4 acc[4][4];
      const int bb = b - 128;
      const int m0 = (bb >> 5) * 128, n0 = (bb & 31) * 128;
      gemm128<false>(acc, nullptr, nullptr, 0, H2in, Whh2b, 1024, m0, n0, smem);
      // U2 = acc + bias; lane-pair pack -> u32 coherent stores (even lanes)
#pragma unroll
      for (int nt = 0; nt < 4; ++nt) {
        int col = n0 + wn * 64 + nt * 16 + l16;
        float bias = b2s[col];
#pragma unroll
        for (int mt = 0; mt < 4; ++mt) {
          int row = m0 + wm * 64 + mt * 16 + quad * 4;
#pragma unroll
          for (int r = 0; r < 4; ++r) {
            float v = acc[mt][nt][r] + bias;
            float w = __shfl_xor(v, 1);
            if (!(lane & 1))
              st32(U2 + (size_t)(row + r) * 4096 + col,
                   (unsigned)f2bf(v) | ((unsigned)f2bf(w) << 16));
          }
        }
      }
    }
    grid_sync(bar, grp);

    // ---------------- phase B: gates2 = c1@Wcomb^T + U2, 128x64 tiles ----------------
    {
      f32x4 acc[4][2];
#pragma unroll
      for (int mt = 0; mt < 4; ++mt)
#pragma unroll
        for (int nt = 0; nt < 2; ++nt) {
          f32x4 z = {0.f, 0.f, 0.f, 0.f};
          acc[mt][nt] = z;
        }
      const int m0 = (b >> 6) * 128;        // 4 m-tiles
      const int n0 = (b & 63) * 64;         // 64 n-tiles
      const int jbase = (b & 63) * 16;

      stage_pb(C1b, Wcombb, 0, m0, n0, smem, 0, wave, lane);
      for (int it = 0; it < 16; ++it) {
        if (it + 1 < 16) {
          stage_pb(C1b, Wcombb, (it + 1) * 64, m0, n0, smem, (it + 1) & 1, wave, lane);
          __builtin_amdgcn_s_waitcnt(0xF76);  // vmcnt(6): prev stage landed
        } else {
          __builtin_amdgcn_s_waitcnt(0xF70);  // vmcnt(0)
        }
        __builtin_amdgcn_s_barrier();
        asm volatile("" ::: "memory");
        compute_pb(acc, smem, it & 1, wm, wn, l16, quad);
        asm volatile("" ::: "memory");
        __builtin_amdgcn_s_barrier();
      }

      float* gl = (float*)smem;  // [128][68]
      __syncthreads();
#pragma unroll
      for (int nt = 0; nt < 2; ++nt) {
        int col = wn * 32 + nt * 16 + l16;
#pragma unroll
        for (int mt = 0; mt < 4; ++mt) {
          int rowb = wm * 64 + mt * 16 + quad * 4;
#pragma unroll
          for (int r = 0; r < 4; ++r)
            gl[(rowb + r) * 68 + col] = acc[mt][nt][r];
        }
      }
      __syncthreads();
      u16* C2dst = C2seq + (size_t)t * BSZ * HDIM;
      // cell update, 2 cols/thread -> coherent 64/32-bit accesses
#pragma unroll
      for (int itr = 0; itr < 4; ++itr) {
        int idx = itr * 256 + tid;
        int mr = idx >> 3, jp = idx & 7;
        int grow = m0 + mr;
        const float* gp = gl + mr * 68 + jp * 8;
        f32x4 ga = *(const f32x4*)gp;
        f32x4 gb = *(const f32x4*)(gp + 4);
        const u16* u2p = U2 + (size_t)grow * 4096 + (jbase + jp * 2) * 4;
        u64 ua = ld64(u2p);
        u64 ub = ld64(u2p + 4);
        ga[0] += bf2f((unsigned)ua);        ga[1] += bf2f((unsigned)(ua >> 16));
        ga[2] += bf2f((unsigned)(ua >> 32)); ga[3] += bf2f((unsigned)(ua >> 48));
        gb[0] += bf2f((unsigned)ub);        gb[1] += bf2f((unsigned)(ub >> 16));
        gb[2] += bf2f((unsigned)(ub >> 32)); gb[3] += bf2f((unsigned)(ub >> 48));
        size_t off = (size_t)grow * HDIM + jbase + jp * 2;
        union { u64 u; float f[2]; } cv;
        cv.u = ld64(C2f + off);
        float c0 = sigm(ga[1]) * cv.f[0] + sigm(ga[0]) * tanh_(ga[2]);
        float c1 = sigm(gb[1]) * cv.f[1] + sigm(gb[0]) * tanh_(gb[2]);
        float h0 = sigm(ga[3]) * tanh_(c0);
        float h1 = sigm(gb[3]) * tanh_(c1);
        cv.f[0] = c0; cv.f[1] = c1;
        st64(C2f + off, cv.u);
        st32(H2o + off, (unsigned)f2bf(h0) | ((unsigned)f2bf(h1) << 16));
        st32(C2dst + off, (unsigned)f2bf(c0) | ((unsigned)f2bf(c1) << 16));
      }
    }
    grid_sync(bar, grp);
  }
}

// ============ fallback per-step kernels (old path) ============
__global__ __launch_bounds__(256, 1) void k1_fused(
    const u16* __restrict__ Xt, const u16* __restrict__ W1a,
    const u16* __restrict__ H1in, const u16* __restrict__ Whh1,
    const float* __restrict__ b1s, float* __restrict__ c1State,
    u16* __restrict__ H1out, u16* __restrict__ C1out,
    const u16* __restrict__ H2in, const u16* __restrict__ Whh2,
    const float* __restrict__ b2s, u16* __restrict__ U2)
{
  __shared__ __align__(16) char smem[65536];
  const int tid = threadIdx.x;
  const int lane = tid & 63, wave = tid >> 6;
  const int quad = lane >> 4, l16 = lane & 15;
  const int wm = wave >> 1, wn = wave & 1;
  const int b = blockIdx.x;
  f32x4 acc[4][4];

  if (b < 128) {
    const int m0 = (b >> 5) * 128, n0 = (b & 31) * 128;
    gemm128<true>(acc, Xt, W1a, 128, H1in, Whh1, 1024, m0, n0, smem);

    float* gl = (float*)smem;  // [64][132]
    const int jbase = (b & 31) * 32;
#pragma unroll
    for (int h = 0; h < 2; ++h) {
      __syncthreads();
      if (wm == h) {
#pragma unroll
        for (int nt = 0; nt < 4; ++nt) {
          int col = wn * 64 + nt * 16 + l16;
#pragma unroll
          for (int mt = 0; mt < 4; ++mt) {
            int rowb = mt * 16 + quad * 4;
#pragma unroll
            for (int r = 0; r < 4; ++r)
              gl[(rowb + r) * 132 + col] = acc[mt][nt][r];
          }
        }
      }
      __syncthreads();
#pragma unroll
      for (int itr = 0; itr < 8; ++itr) {
        int idx = itr * 256 + tid;
        int mr = idx >> 5, jl = idx & 31;
        f32x4 g4 = *(const f32x4*)(gl + mr * 132 + jl * 4);
        f32x4 b4 = *(const f32x4*)(b1s + jbase * 4 + jl * 4);
        g4 += b4;
        float ii = sigm(g4[0]), ff = sigm(g4[1]);
        float gg = tanh_(g4[2]), oo = sigm(g4[3]);
        size_t off = (size_t)(m0 + h * 64 + mr) * HDIM + jbase + jl;
        float cp = c1State[off];
        float cn = ff * cp + ii * gg;
        float hh = oo * tanh_(cn);
        c1State[off] = cn;
        H1out[off] = f2bf(hh);
        C1out[off] = f2bf(cn);
      }
    }
  } else {
    const int bb = b - 128;
    const int m0 = (bb >> 5) * 128, n0 = (bb & 31) * 128;
    gemm128<false>(acc, nullptr, nullptr, 0, H2in, Whh2, 1024, m0, n0, smem);
#pragma unroll
    for (int nt = 0; nt < 4; ++nt) {
      int col = n0 + wn * 64 + nt * 16 + l16;
      float bias = b2s[col];
#pragma unroll
      for (int mt = 0; mt < 4; ++mt) {
        int row = m0 + wm * 64 + mt * 16 + quad * 4;
#pragma unroll
        for (int r = 0; r < 4; ++r)
          U2[(size_t)(row + r) * 4096 + col] = f2bf(acc[mt][nt][r] + bias);
      }
    }
  }
}

__global__ __launch_bounds__(256, 1) void k2_cell2(
    const u16* __restrict__ C1b, const u16* __restrict__ Wcomb,
    const u16* __restrict__ U2, float* __restrict__ c2State,
    u16* __restrict__ H2out, u16* __restrict__ C2out)
{
  __shared__ __align__(16) char smem[65536];
  const int tid = threadIdx.x;
  const int lane = tid & 63, wave = tid >> 6;
  const int quad = lane >> 4, l16 = lane & 15;
  const int wm = wave >> 1, wn = wave & 1;
  const int b = blockIdx.x;
  const int m0 = (b >> 5) * 128, n0 = (b & 31) * 128;
  f32x4 acc[4][4];
  gemm128<false>(acc, nullptr, nullptr, 0, C1b, Wcomb, 1024, m0, n0, smem);

  float* gl = (float*)smem;
  const int jbase = (b & 31) * 32;
#pragma unroll
  for (int h = 0; h < 2; ++h) {
    __syncthreads();
    if (wm == h) {
#pragma unroll
      for (int nt = 0; nt < 4; ++nt) {
        int col = wn * 64 + nt * 16 + l16;
#pragma unroll
        for (int mt = 0; mt < 4; ++mt) {
          int rowb = mt * 16 + quad * 4;
#pragma unroll
          for (int r = 0; r < 4; ++r)
            gl[(rowb + r) * 132 + col] = acc[mt][nt][r];
        }
      }
    }
    __syncthreads();
#pragma unroll
    for (int itr = 0; itr < 8; ++itr) {
      int idx = itr * 256 + tid;
      int mr = idx >> 5, jl = idx & 31;
      int grow = m0 + h * 64 + mr;
      f32x4 g4 = *(const f32x4*)(gl + mr * 132 + jl * 4);
      const u16* u2p = U2 + (size_t)grow * 4096 + jbase * 4 + jl * 4;
      g4[0] += bf2f(u2p[0]); g4[1] += bf2f(u2p[1]);
      g4[2] += bf2f(u2p[2]); g4[3] += bf2f(u2p[3]);
      float ii = sigm(g4[0]), ff = sigm(g4[1]);
      float gg = tanh_(g4[2]), oo = sigm(g4[3]);
      size_t off = (size_t)grow * HDIM + jbase + jl;
      float cp = c2State[off];
      float cn = ff * cp + ii * gg;
      float hh = oo * tanh_(cn);
      c2State[off] = cn;
      H2out[off] = f2bf(hh);
      C2out[off] = f2bf(cn);
    }
  }
}

// ================= 64x128 single-buffered GEMM (wcomb / final) =================
__device__ __forceinline__ void gemm_tile_64x128(
    f32x4 acc[2][4],
    const u16* A0, const u16* B0, int K0,
    const u16* A1, const u16* B1, int K1,
    int m0, int n0, u16* As, u16* Bs)
{
  const int tid  = threadIdx.x;
  const int lane = tid & 63;
  const int wave = tid >> 6;
  const int quad = lane >> 4;
  const int l16  = lane & 15;
  const int wm   = wave >> 1;
  const int wn   = wave & 1;
  const int sw   = l16 & 7;

#pragma unroll
  for (int mt = 0; mt < 2; ++mt)
#pragma unroll
    for (int nt = 0; nt < 4; ++nt) {
      f32x4 z = {0.f, 0.f, 0.f, 0.f};
      acc[mt][nt] = z;
    }

  for (int s = 0; s < 2; ++s) {
    const u16* A = s ? A1 : A0;
    const u16* B = s ? B1 : B0;
    const int  K = s ? K1 : K0;
    for (int k0 = 0; k0 < K; k0 += 64) {
      __syncthreads();
#pragma unroll
      for (int i = 0; i < 2; ++i) {
        int c = (wave * 2 + i) * 64 + lane;
        int row = c >> 3, lc = (c & 7) ^ (row & 7);
        const u16* g = A + (size_t)(m0 + row) * K + k0 + (lc << 3);
        load16_lds<0>(g, As + c * 8);
      }
#pragma unroll
      for (int i = 0; i < 4; ++i) {
        int c = (wave * 4 + i) * 64 + lane;
        int row = c >> 3, lc = (c & 7) ^ (row & 7);
        const u16* g = B + (size_t)(n0 + row) * K + k0 + (lc << 3);
        load16_lds<0>(g, Bs + c * 8);
      }
      __syncthreads();
      const bf16x8* Av = (const bf16x8*)As;
      const bf16x8* Bv = (const bf16x8*)Bs;
#pragma unroll
      for (int kk = 0; kk < 2; ++kk) {
        const int pc = (kk * 4 + quad) ^ sw;
        bf16x8 a[2], b[4];
#pragma unroll
        for (int mt = 0; mt < 2; ++mt)
          a[mt] = Av[(wm * 32 + mt * 16 + l16) * 8 + pc];
#pragma unroll
        for (int nt = 0; nt < 4; ++nt)
          b[nt] = Bv[(wn * 64 + nt * 16 + l16) * 8 + pc];
#pragma unroll
        for (int mt = 0; mt < 2; ++mt)
#pragma unroll
          for (int nt = 0; nt < 4; ++nt)
            acc[mt][nt] = __builtin_amdgcn_mfma_f32_16x16x32_bf16(
                a[mt], b[nt], acc[mt][nt], 0, 0, 0);
      }
    }
  }
  __syncthreads();
}

__global__ __launch_bounds__(256, 2) void wcomb_gemm(
    const u16* __restrict__ A, const u16* __restrict__ Bt, u16* __restrict__ outp)
{
  __shared__ __align__(16) char smem[24576];
  u16* As = (u16*)smem;
  u16* Bs = (u16*)(smem + 8192);
  const int m0 = blockIdx.y * 64;
  const int n0 = blockIdx.x * 128;
  f32x4 acc[2][4];
  gemm_tile_64x128(acc, A, Bt, 1024, nullptr, nullptr, 0, m0, n0, As, Bs);
  const int lane = threadIdx.x & 63;
  const int wave = threadIdx.x >> 6;
  const int quad = lane >> 4, l16 = lane & 15;
  const int wm = wave >> 1, wn = wave & 1;
#pragma unroll
  for (int mt = 0; mt < 2; ++mt)
#pragma unroll
    for (int nt = 0; nt < 4; ++nt)
#pragma unroll
      for (int r = 0; r < 4; ++r) {
        int mr = m0 + wm * 32 + mt * 16 + quad * 4 + r;
        int c  = n0 + wn * 64 + nt * 16 + l16;
        outp[(size_t)permrow(mr) * 1024 + c] = f2bf(acc[mt][nt][r]);
      }
}

__global__ __launch_bounds__(256, 2) void final_logsoftmax(
    const u16* __restrict__ C2, const u16* __restrict__ Wf,
    const float* __restrict__ bfin, float* __restrict__ out)
{
  __shared__ __align__(16) char smem[64 * 132 * 4 + 256];
  u16* As = (u16*)smem;
  u16* Bs = (u16*)(smem + 8192);
  float* gl  = (float*)smem;
  float* lse = (float*)(smem + 64 * 132 * 4);

  const int m0 = blockIdx.y * 64;
  f32x4 acc[2][4];
  gemm_tile_64x128(acc, C2, Wf, 1024, nullptr, nullptr, 0, m0, 0, As, Bs);

  const int tid = threadIdx.x;
  const int lane = tid & 63;
  const int wave = tid >> 6;
  const int quad = lane >> 4, l16 = lane & 15;
  const int wm = wave >> 1, wn = wave & 1;
#pragma unroll
  for (int nt = 0; nt < 4; ++nt) {
    int coll = wn * 64 + nt * 16 + l16;
    float bias = (coll < VOUT) ? bfin[coll] : 0.f;
#pragma unroll
    for (int mt = 0; mt < 2; ++mt) {
      int rowb = wm * 32 + mt * 16 + quad * 4;
#pragma unroll
      for (int r = 0; r < 4; ++r)
        gl[(rowb + r) * 132 + coll] = acc[mt][nt][r] + bias;
    }
  }
  __syncthreads();
  if (tid < 64) {
    const float* row = gl + tid * 132;
    float mx = -1e30f;
    for (int c = 0; c < VOUT; ++c) mx = fmaxf(mx, row[c]);
    float s = 0.f;
    for (int c = 0; c < VOUT; ++c) s += __expf(row[c] - mx);
    lse[tid] = mx + __logf(s);
  }
  __syncthreads();
  for (int idx = tid; idx < 64 * VOUT; idx += 256) {
    int m = idx / VOUT, c = idx - m * VOUT;
    out[(size_t)(m0 + m) * VOUT + c] = gl[m * 132 + c] - lse[m];
  }
}

// ---------------- setup kernels ----------------
__global__ void k_build_w1a(const float* __restrict__ w, u16* __restrict__ d) {
  int idx = blockIdx.x * 256 + threadIdx.x;
  int n = idx >> 7, k = idx & 127;
  float v = (k < IIN) ? w[n * IIN + k] : 0.f;
  d[permrow(n) * 128 + k] = f2bf(v);
}
__global__ void k_conv_perm1024(const float* __restrict__ w, u16* __restrict__ d) {
  int idx = blockIdx.x * 256 + threadIdx.x;
  int n = idx >> 10, k = idx & 1023;
  d[(size_t)permrow(n) * 1024 + k] = f2bf(w[idx]);
}
__global__ void k_conv(const float* __restrict__ s, u16* __restrict__ d) {
  int idx = blockIdx.x * 256 + threadIdx.x;
  d[idx] = f2bf(s[idx]);
}
__global__ void k_transpose1024(const float* __restrict__ s, u16* __restrict__ d) {
  int idx = blockIdx.x * 256 + threadIdx.x;
  int r = idx >> 10, c = idx & 1023;
  d[c * 1024 + r] = f2bf(s[idx]);
}
__global__ void k_build_wfin(const float* __restrict__ w, u16* __restrict__ d) {
  int idx = blockIdx.x * 256 + threadIdx.x;
  int r = idx >> 10, c = idx & 1023;
  d[idx] = (r < VOUT) ? f2bf(w[r * 1024 + c]) : (u16)0;
}
__global__ void k_build_xpad(const float* __restrict__ x, u16* __restrict__ d) {
  int idx = blockIdx.x * 256 + threadIdx.x;
  int row = idx >> 7, k = idx & 127;
  d[idx] = (k < IIN) ? f2bf(x[row * IIN + k]) : (u16)0;
}
__global__ void k_b1sum(const float* __restrict__ a, const float* __restrict__ b,
                        float* __restrict__ d) {
  int n = blockIdx.x * 256 + threadIdx.x;
  d[permrow(n)] = a[n] + b[n];
}
__global__ void k_b2sum(const float* __restrict__ Wih2, const float* __restrict__ bmid,
                        const float* __restrict__ bih2, const float* __restrict__ bhh2,
                        float* __restrict__ d) {
  int row = blockIdx.x * 4 + (threadIdx.x >> 6);
  int lane = threadIdx.x & 63;
  const float* wr = Wih2 + (size_t)row * 1024;
  float s = 0.f;
  for (int k = lane; k < 1024; k += 64) s += wr[k] * bmid[k];
#pragma unroll
  for (int o = 32; o > 0; o >>= 1) s += __shfl_down(s, o);
  if (lane == 0) d[permrow(row)] = s + bih2[row] + bhh2[row];
}

extern "C" void kernel_launch(void* const* d_in, const int* in_sizes, int n_in,
                              void* d_out, int out_size, void* d_ws, size_t ws_size,
                              hipStream_t stream) {
  const float* x    = (const float*)d_in[0];
  const float* Wih1 = (const float*)d_in[1];
  const float* Whh1 = (const float*)d_in[2];
  const float* bih1 = (const float*)d_in[3];
  const float* bhh1 = (const float*)d_in[4];
  const float* Wmid = (const float*)d_in[5];
  const float* bmid = (const float*)d_in[6];
  const float* Wih2 = (const float*)d_in[7];
  const float* Whh2 = (const float*)d_in[8];
  const float* bih2 = (const float*)d_in[9];
  const float* bhh2 = (const float*)d_in[10];
  const float* Wfin = (const float*)d_in[11];
  const float* bfin = (const float*)d_in[12];

  const size_t SZ_XBF = (size_t)TSTEPS * BSZ * 128 * 2;
  const size_t SZ_W1A = (size_t)4096 * 128 * 2;
  const size_t SZ_W1K = (size_t)4096 * 1024 * 2;
  const size_t SZ_WMT = (size_t)1024 * 1024 * 2;
  const size_t SZ_WFB = (size_t)128 * 1024 * 2;
  const size_t SZ_BSM = (size_t)4096 * 4;
  const size_t SZ_HB  = (size_t)BSZ * HDIM * 2;
  const size_t SZ_CF  = (size_t)BSZ * HDIM * 4;
  const size_t SZ_U2  = (size_t)BSZ * 4096 * 2;
  const size_t SZ_C2S = (size_t)TSTEPS * BSZ * HDIM * 2;

  char* base = (char*)d_ws;
  size_t off = 0;
  auto alloc = [&](size_t b) { char* p = base + off; off += (b + 255) & ~(size_t)255; return p; };

  u16*   Xbf    = (u16*)alloc(SZ_XBF);
  u16*   W1a    = (u16*)alloc(SZ_W1A);
  u16*   Whh1b  = (u16*)alloc(SZ_W1K);
  u16*   Wcombb = (u16*)alloc(SZ_W1K);
  u16*   Whh2b  = (u16*)alloc(SZ_W1K);
  u16*   Wih2b  = (u16*)alloc(SZ_W1K);
  u16*   WmidT  = (u16*)alloc(SZ_WMT);
  u16*   Wfinb  = (u16*)alloc(SZ_WFB);
  float* b1s    = (float*)alloc(SZ_BSM);
  float* b2s    = (float*)alloc(SZ_BSM);
  u16*   H1p[2]; H1p[0] = (u16*)alloc(SZ_HB); H1p[1] = (u16*)alloc(SZ_HB);
  u16*   H2p[2]; H2p[0] = (u16*)alloc(SZ_HB); H2p[1] = (u16*)alloc(SZ_HB);
  float* C1f    = (float*)alloc(SZ_CF);
  float* C2f    = (float*)alloc(SZ_CF);
  u16*   C1b    = (u16*)alloc(SZ_HB);
  u16*   C2b    = (u16*)alloc(SZ_HB);
  u16*   U2     = (u16*)alloc(SZ_U2);
  unsigned* barp = (unsigned*)alloc(2048);
  u16*   C2seq  = (u16*)(base + off);
  bool batched  = (off + SZ_C2S) <= ws_size;

  // zero states: H1p0,H1p1,H2p0,H2p1,C1f,C2f contiguous (256-aligned sizes)
  size_t zbytes = 4 * SZ_HB + 2 * SZ_CF;
  hipMemsetAsync((void*)H1p[0], 0, zbytes, stream);
  hipMemsetAsync((void*)barp, 0, 2048, stream);

  k_build_w1a<<<2048, 256, 0, stream>>>(Wih1, W1a);
  k_conv_perm1024<<<16384, 256, 0, stream>>>(Whh1, Whh1b);
  k_conv_perm1024<<<16384, 256, 0, stream>>>(Whh2, Whh2b);
  k_conv<<<16384, 256, 0, stream>>>(Wih2, Wih2b);
  k_transpose1024<<<4096, 256, 0, stream>>>(Wmid, WmidT);
  k_build_wfin<<<512, 256, 0, stream>>>(Wfin, Wfinb);
  k_build_xpad<<<46080, 256, 0, stream>>>(x, Xbf);
  k_b1sum<<<16, 256, 0, stream>>>(bih1, bhh1, b1s);
  k_b2sum<<<1024, 256, 0, stream>>>(Wih2, bmid, bih2, bhh2, b2s);
  wcomb_gemm<<<dim3(8, 64), 256, 0, stream>>>(Wih2b, WmidT, Wcombb);

  bool usedPersistent = false;
  if (batched) {
    u16* H1x = H1p[0]; u16* H1y = H1p[1];
    u16* H2x = H2p[0]; u16* H2y = H2p[1];
    void* kargs[] = {
        (void*)&Xbf, (void*)&W1a, (void*)&Whh1b, (void*)&b1s,
        (void*)&C1f, (void*)&C1b, (void*)&Whh2b, (void*)&b2s,
        (void*)&U2, (void*)&Wcombb, (void*)&C2f, (void*)&C2seq,
        (void*)&H1x, (void*)&H1y, (void*)&H2x, (void*)&H2y,
        (void*)&barp};
    hipError_t ce = hipLaunchCooperativeKernel(
        (const void*)lstm_persistent, dim3(NBLK), dim3(256), kargs, 0, stream);
    usedPersistent = (ce == hipSuccess);
    if (!usedPersistent) (void)hipGetLastError();  // clear sticky error for fallback
  }

  if (usedPersistent) {
    final_logsoftmax<<<dim3(1, (TSTEPS * BSZ) / 64), 256, 0, stream>>>(
        C2seq, Wfinb, bfin, (float*)d_out);
  } else {
    for (int t = 0; t < TSTEPS; ++t) {
      int p = t & 1;
      k1_fused<<<256, 256, 0, stream>>>(
          Xbf + (size_t)t * BSZ * 128, W1a, H1p[p], Whh1b, b1s, C1f,
          H1p[p ^ 1], C1b, H2p[p], Whh2b, b2s, U2);
      u16* c2dst = batched ? (C2seq + (size_t)t * BSZ * HDIM) : C2b;
      k2_cell2<<<128, 256, 0, stream>>>(C1b, Wcombb, U2, C2f, H2p[p ^ 1], c2dst);
      if (!batched)
        final_logsoftmax<<<dim3(1, 8), 256, 0, stream>>>(
            C2b, Wfinb, bfin, (float*)d_out + (size_t)t * BSZ * VOUT);
    }
    if (batched)
      final_logsoftmax<<<dim3(1, (TSTEPS * BSZ) / 64), 256, 0, stream>>>(
          C2seq, Wfinb, bfin, (float*)d_out);
  }
}

// Round 8
// 6854.362 us; speedup vs baseline: 2.6230x; 1.0838x over previous
//
#include <hip/hip_runtime.h>
#include <stdint.h>

// LSTM_34359738368754: 2-layer LSTM, T=180 B=512 H=1024 I=V=108.
// R7: R6 (fence-free barrier + coherent paths) + 4-deep GEMM pipeline.
//  - R6 measured 7.43ms: MfmaUtil 13.5% -> ~5.6us MFMA/step vs 41.5us step.
//    ~20us/step = K-loop latency stall: coherent (sc1) A-operand loads pay
//    LLC latency (~600-900cy) but double-buffering gives only ~1 iter
//    (~150-200ns) of slack; 1 block/CU -> no TLP to hide it.
//  - R7: 4 LDS buffers, 3-deep prefetch, counted vmcnt (cp.async-style):
//    phase A steady-state vmcnt(24)=3x8 loads, tail 16/8/0;
//    phase B vmcnt(18)=3x6, tail 12/6/0. LDS 128KB (4x32KB) phase A,
//    4x24KB phase B. Occupancy unchanged (1 block/CU).
//  - stage(it+3) writes buf (it-1)&3: safe, readers passed it-1 end-barrier.

typedef unsigned short u16;
typedef __attribute__((ext_vector_type(2))) float f32x2;
typedef __attribute__((ext_vector_type(4))) float f32x4;
typedef __attribute__((ext_vector_type(8))) short bf16x8;
typedef unsigned long long u64;

#define HDIM 1024
#define BSZ  512
#define TSTEPS 180
#define IIN  108
#define VOUT 108
#define NBLK 256

#define AGENT __HIP_MEMORY_SCOPE_AGENT
#define RLX   __ATOMIC_RELAXED

__device__ __forceinline__ u16 f2bf(float x) {
  union { float f; unsigned u; } v; v.f = x;
  unsigned r = (v.u + 0x7fffu + ((v.u >> 16) & 1u)) >> 16;  // RNE
  return (u16)r;
}
__device__ __forceinline__ float bf2f(unsigned b) {
  union { unsigned u; float f; } v; v.u = (b & 0xffffu) << 16; return v.f;
}
__device__ __forceinline__ float sigm(float x) { return 1.f / (1.f + __expf(-x)); }
__device__ __forceinline__ float tanh_(float x) {
  float a = fabsf(x), t = __expf(-2.f * a);
  float r = (1.f - t) / (1.f + t);
  return x < 0.f ? -r : r;
}
__device__ __forceinline__ int permrow(int n) { return ((n & 1023) << 2) | (n >> 10); }

// aux = CPol: 0 = cached; 0x11 = SC0|SC1 (agent-coherent: bypass L1+L2, hit LLC)
template <int AUX>
__device__ __forceinline__ void load16_lds(const void* g, void* l) {
  __builtin_amdgcn_global_load_lds(
      (const __attribute__((address_space(1))) unsigned int*)g,
      (__attribute__((address_space(3))) unsigned int*)l, 16, 0, AUX);
}

__device__ __forceinline__ void st32(void* p, unsigned v) {
  __hip_atomic_store((unsigned*)p, v, RLX, AGENT);
}
__device__ __forceinline__ void st64(void* p, u64 v) {
  __hip_atomic_store((u64*)p, v, RLX, AGENT);
}
__device__ __forceinline__ u64 ld64(const void* p) {
  return __hip_atomic_load((u64*)p, RLX, AGENT);
}

// ---------------- fence-free grid barrier ----------------
// bar[0]=gen; bar[32]=root; bar[64+g*32]=group-g arrival (128B-separated).
__device__ __forceinline__ void grid_sync(unsigned* bar, int grp) {
  __syncthreads();
  if (threadIdx.x == 0) {
    unsigned* gen  = bar;
    unsigned* root = bar + 32;
    unsigned* gcnt = bar + 64 + grp * 32;
    unsigned g = __hip_atomic_load(gen, RLX, AGENT);
    asm volatile("s_waitcnt vmcnt(0)" ::: "memory");
    unsigned a = __hip_atomic_fetch_add(gcnt, 1u, RLX, AGENT);
    if (a == 31u) {                       // last of this group of 32
      __hip_atomic_store(gcnt, 0u, RLX, AGENT);
      asm volatile("s_waitcnt vmcnt(0)" ::: "memory");
      unsigned c = __hip_atomic_fetch_add(root, 1u, RLX, AGENT);
      if (c == 7u) {                      // last group: release the grid
        __hip_atomic_store(root, 0u, RLX, AGENT);
        asm volatile("s_waitcnt vmcnt(0)" ::: "memory");
        __hip_atomic_store(gen, g + 1u, RLX, AGENT);
      }
    }
    while (__hip_atomic_load(gen, RLX, AGENT) == g)
      __builtin_amdgcn_s_sleep(2);
  }
  __syncthreads();
}

// ================= 128x128 4-buffer GEMM =================
// smem: buf b at smem + b*32768 (b=0..3); As 16KB then Bs 16KB. BK=64.
// LDS chunk swizzle: physical chunk pc holds logical chunk pc^(row&7).
template <int AUXA>
__device__ __forceinline__ void stage128(const u16* A, const u16* B, int K,
                                         int k0, int m0, int n0,
                                         char* smem, int buf, int wave, int lane) {
  u16* As = (u16*)(smem + buf * 32768);
  u16* Bs = (u16*)(smem + buf * 32768 + 16384);
#pragma unroll
  for (int i = 0; i < 4; ++i) {
    int c = (wave * 4 + i) * 64 + lane;
    int row = c >> 3, lc = (c & 7) ^ (row & 7);     // swizzled source chunk
    const u16* g = A + (size_t)(m0 + row) * K + k0 + (lc << 3);
    load16_lds<AUXA>(g, As + c * 8);
  }
#pragma unroll
  for (int i = 0; i < 4; ++i) {
    int c = (wave * 4 + i) * 64 + lane;
    int row = c >> 3, lc = (c & 7) ^ (row & 7);
    const u16* g = B + (size_t)(n0 + row) * K + k0 + (lc << 3);
    load16_lds<0>(g, Bs + c * 8);
  }
}

__device__ __forceinline__ void compute128(f32x4 acc[4][4], char* smem, int buf,
                                           int wm, int wn, int l16, int quad) {
  const bf16x8* Av = (const bf16x8*)(smem + buf * 32768);
  const bf16x8* Bv = (const bf16x8*)(smem + buf * 32768 + 16384);
  const int sw = l16 & 7;
#pragma unroll
  for (int kk = 0; kk < 2; ++kk) {
    const int pc = (kk * 4 + quad) ^ sw;            // swizzled chunk
    bf16x8 a[4], b[4];
#pragma unroll
    for (int mt = 0; mt < 4; ++mt)
      a[mt] = Av[(wm * 64 + mt * 16 + l16) * 8 + pc];
#pragma unroll
    for (int nt = 0; nt < 4; ++nt)
      b[nt] = Bv[(wn * 64 + nt * 16 + l16) * 8 + pc];
#pragma unroll
    for (int mt = 0; mt < 4; ++mt)
#pragma unroll
      for (int nt = 0; nt < 4; ++nt)
        acc[mt][nt] = __builtin_amdgcn_mfma_f32_16x16x32_bf16(
            a[mt], b[nt], acc[mt][nt], 0, 0, 0);
  }
}

// acc(128x128) at (m0,n0) = A0@B0^T (K0, optional, cached A) + A1@B1^T (K1,
// coherent A). B operands always cached (weights). 4-buffer, 3-deep prefetch.
template <bool HAS0>
__device__ __forceinline__ void gemm128(f32x4 acc[4][4],
    const u16* A0, const u16* B0, int K0,
    const u16* A1, const u16* B1, int K1,
    int m0, int n0, char* smem) {
  const int tid = threadIdx.x;
  const int lane = tid & 63, wave = tid >> 6;
  const int quad = lane >> 4, l16 = lane & 15;
  const int wm = wave >> 1, wn = wave & 1;

#pragma unroll
  for (int mt = 0; mt < 4; ++mt)
#pragma unroll
    for (int nt = 0; nt < 4; ++nt) {
      f32x4 z = {0.f, 0.f, 0.f, 0.f};
      acc[mt][nt] = z;
    }

  const int n0i = HAS0 ? (K0 >> 6) : 0;
  const int nIter = n0i + (K1 >> 6);

  auto do_stage = [&](int ix) {
    if (HAS0 && ix < n0i)
      stage128<0>(A0, B0, K0, ix * 64, m0, n0, smem, ix & 3, wave, lane);
    else
      stage128<0x11>(A1, B1, K1, (ix - n0i) * 64, m0, n0, smem, ix & 3, wave, lane);
  };

  do_stage(0);
  if (nIter > 1) do_stage(1);
  if (nIter > 2) do_stage(2);

  for (int it = 0; it < nIter; ++it) {
    if (it + 3 < nIter) do_stage(it + 3);
    const int rem = nIter - 1 - it;     // stages still outstanding beyond it
    if (rem >= 3)      asm volatile("s_waitcnt vmcnt(24)" ::: "memory");
    else if (rem == 2) asm volatile("s_waitcnt vmcnt(16)" ::: "memory");
    else if (rem == 1) asm volatile("s_waitcnt vmcnt(8)"  ::: "memory");
    else               asm volatile("s_waitcnt vmcnt(0)"  ::: "memory");
    __builtin_amdgcn_s_barrier();
    asm volatile("" ::: "memory");
    compute128(acc, smem, it & 3, wm, wn, l16, quad);
    asm volatile("" ::: "memory");
    __builtin_amdgcn_s_barrier();  // all waves done reading buf before overwrite
  }
}

// ============ phase-B 128x64 4-buffer GEMM (persistent kernel) ============
// buf b at smem + b*24576 (b=0..3); As (128 rows) 16KB then Bs (64 rows) 8KB.
__device__ __forceinline__ void stage_pb(const u16* A, const u16* B, int k0,
                                         int m0, int n0, char* smem, int buf,
                                         int wave, int lane) {
  u16* As = (u16*)(smem + buf * 24576);
  u16* Bs = (u16*)(smem + buf * 24576 + 16384);
#pragma unroll
  for (int i = 0; i < 4; ++i) {
    int c = (wave * 4 + i) * 64 + lane;               // 1024 chunks = 128 rows
    int row = c >> 3, lc = (c & 7) ^ (row & 7);
    load16_lds<0x11>(A + (size_t)(m0 + row) * 1024 + k0 + (lc << 3), As + c * 8);
  }
#pragma unroll
  for (int i = 0; i < 2; ++i) {
    int c = (wave * 2 + i) * 64 + lane;               // 512 chunks = 64 rows
    int row = c >> 3, lc = (c & 7) ^ (row & 7);
    load16_lds<0>(B + (size_t)(n0 + row) * 1024 + k0 + (lc << 3), Bs + c * 8);
  }
}

__device__ __forceinline__ void compute_pb(f32x4 acc[4][2], char* smem, int buf,
                                           int wm, int wn, int l16, int quad) {
  const bf16x8* Av = (const bf16x8*)(smem + buf * 24576);
  const bf16x8* Bv = (const bf16x8*)(smem + buf * 24576 + 16384);
  const int sw = l16 & 7;
#pragma unroll
  for (int kk = 0; kk < 2; ++kk) {
    const int pc = (kk * 4 + quad) ^ sw;
    bf16x8 a[4], b[2];
#pragma unroll
    for (int mt = 0; mt < 4; ++mt)
      a[mt] = Av[(wm * 64 + mt * 16 + l16) * 8 + pc];
#pragma unroll
    for (int nt = 0; nt < 2; ++nt)
      b[nt] = Bv[(wn * 32 + nt * 16 + l16) * 8 + pc];
#pragma unroll
    for (int mt = 0; mt < 4; ++mt)
#pragma unroll
      for (int nt = 0; nt < 2; ++nt)
        acc[mt][nt] = __builtin_amdgcn_mfma_f32_16x16x32_bf16(
            a[mt], b[nt], acc[mt][nt], 0, 0, 0);
  }
}

// ================= persistent whole-sequence kernel =================
__global__ __launch_bounds__(256, 1) void lstm_persistent(
    const u16* __restrict__ Xbf, const u16* __restrict__ W1a,
    const u16* __restrict__ Whh1b, const float* __restrict__ b1s,
    float* __restrict__ C1f, u16* __restrict__ C1b,
    const u16* __restrict__ Whh2b, const float* __restrict__ b2s,
    u16* __restrict__ U2, const u16* __restrict__ Wcombb,
    float* __restrict__ C2f, u16* __restrict__ C2seq,
    u16* __restrict__ H1x, u16* __restrict__ H1y,
    u16* __restrict__ H2x, u16* __restrict__ H2y,
    unsigned* __restrict__ bar)
{
  __shared__ __align__(16) char smem[131072];
  const int tid = threadIdx.x;
  const int lane = tid & 63, wave = tid >> 6;
  const int quad = lane >> 4, l16 = lane & 15;
  const int wm = wave >> 1, wn = wave & 1;
  const int b = blockIdx.x;
  const int grp = b & 7;

  for (int t = 0; t < TSTEPS; ++t) {
    const int p = t & 1;
    const u16* H1in = p ? H1y : H1x;  u16* H1o = p ? H1x : H1y;
    const u16* H2in = p ? H2y : H2x;  u16* H2o = p ? H2x : H2y;
    const u16* Xt = Xbf + (size_t)t * BSZ * 128;

    // ---------------- phase A ----------------
    if (b < 128) {
      f32x4 acc[4][4];
      const int m0 = (b >> 5) * 128, n0 = (b & 31) * 128;
      gemm128<true>(acc, Xt, W1a, 128, H1in, Whh1b, 1024, m0, n0, smem);

      float* gl = (float*)smem;  // [64][132]
      const int jbase = (b & 31) * 32;
#pragma unroll
      for (int h = 0; h < 2; ++h) {
        __syncthreads();
        if (wm == h) {
#pragma unroll
          for (int nt = 0; nt < 4; ++nt) {
            int col = wn * 64 + nt * 16 + l16;
#pragma unroll
            for (int mt = 0; mt < 4; ++mt) {
              int rowb = mt * 16 + quad * 4;
#pragma unroll
              for (int r = 0; r < 4; ++r)
                gl[(rowb + r) * 132 + col] = acc[mt][nt][r];
            }
          }
        }
        __syncthreads();
        // cell update, 2 cols/thread -> u32 coherent stores
#pragma unroll
        for (int itr = 0; itr < 4; ++itr) {
          int idx = itr * 256 + tid;
          int mr = idx >> 4, jp = idx & 15;
          const float* gp = gl + mr * 132 + jp * 8;
          f32x4 ga = *(const f32x4*)gp;
          f32x4 gb = *(const f32x4*)(gp + 4);
          const float* bp = b1s + jbase * 4 + jp * 8;
          ga += *(const f32x4*)bp;
          gb += *(const f32x4*)(bp + 4);
          size_t off = (size_t)(m0 + h * 64 + mr) * HDIM + jbase + jp * 2;
          f32x2 cp = *(const f32x2*)(C1f + off);      // private, cached
          float c0 = sigm(ga[1]) * cp[0] + sigm(ga[0]) * tanh_(ga[2]);
          float c1 = sigm(gb[1]) * cp[1] + sigm(gb[0]) * tanh_(gb[2]);
          float h0 = sigm(ga[3]) * tanh_(c0);
          float h1 = sigm(gb[3]) * tanh_(c1);
          f32x2 cn = {c0, c1};
          *(f32x2*)(C1f + off) = cn;
          st32(H1o + off, (unsigned)f2bf(h0) | ((unsigned)f2bf(h1) << 16));
          st32(C1b + off, (unsigned)f2bf(c0) | ((unsigned)f2bf(c1) << 16));
        }
      }
    } else {
      f32x4 acc[4][4];
      const int bb = b - 128;
      const int m0 = (bb >> 5) * 128, n0 = (bb & 31) * 128;
      gemm128<false>(acc, nullptr, nullptr, 0, H2in, Whh2b, 1024, m0, n0, smem);
      // U2 = acc + bias; lane-pair pack -> u32 coherent stores (even lanes)
#pragma unroll
      for (int nt = 0; nt < 4; ++nt) {
        int col = n0 + wn * 64 + nt * 16 + l16;
        float bias = b2s[col];
#pragma unroll
        for (int mt = 0; mt < 4; ++mt) {
          int row = m0 + wm * 64 + mt * 16 + quad * 4;
#pragma unroll
          for (int r = 0; r < 4; ++r) {
            float v = acc[mt][nt][r] + bias;
            float w = __shfl_xor(v, 1);
            if (!(lane & 1))
              st32(U2 + (size_t)(row + r) * 4096 + col,
                   (unsigned)f2bf(v) | ((unsigned)f2bf(w) << 16));
          }
        }
      }
    }
    grid_sync(bar, grp);

    // ---------------- phase B: gates2 = c1@Wcomb^T + U2, 128x64 tiles ----------------
    {
      f32x4 acc[4][2];
#pragma unroll
      for (int mt = 0; mt < 4; ++mt)
#pragma unroll
        for (int nt = 0; nt < 2; ++nt) {
          f32x4 z = {0.f, 0.f, 0.f, 0.f};
          acc[mt][nt] = z;
        }
      const int m0 = (b >> 6) * 128;        // 4 m-tiles
      const int n0 = (b & 63) * 64;         // 64 n-tiles
      const int jbase = (b & 63) * 16;

      stage_pb(C1b, Wcombb, 0,   m0, n0, smem, 0, wave, lane);
      stage_pb(C1b, Wcombb, 64,  m0, n0, smem, 1, wave, lane);
      stage_pb(C1b, Wcombb, 128, m0, n0, smem, 2, wave, lane);
      for (int it = 0; it < 16; ++it) {
        if (it + 3 < 16)
          stage_pb(C1b, Wcombb, (it + 3) * 64, m0, n0, smem, (it + 3) & 3, wave, lane);
        const int rem = 15 - it;
        if (rem >= 3)      asm volatile("s_waitcnt vmcnt(18)" ::: "memory");
        else if (rem == 2) asm volatile("s_waitcnt vmcnt(12)" ::: "memory");
        else if (rem == 1) asm volatile("s_waitcnt vmcnt(6)"  ::: "memory");
        else               asm volatile("s_waitcnt vmcnt(0)"  ::: "memory");
        __builtin_amdgcn_s_barrier();
        asm volatile("" ::: "memory");
        compute_pb(acc, smem, it & 3, wm, wn, l16, quad);
        asm volatile("" ::: "memory");
        __builtin_amdgcn_s_barrier();
      }

      float* gl = (float*)smem;  // [128][68]
      __syncthreads();
#pragma unroll
      for (int nt = 0; nt < 2; ++nt) {
        int col = wn * 32 + nt * 16 + l16;
#pragma unroll
        for (int mt = 0; mt < 4; ++mt) {
          int rowb = wm * 64 + mt * 16 + quad * 4;
#pragma unroll
          for (int r = 0; r < 4; ++r)
            gl[(rowb + r) * 68 + col] = acc[mt][nt][r];
        }
      }
      __syncthreads();
      u16* C2dst = C2seq + (size_t)t * BSZ * HDIM;
      // cell update, 2 cols/thread -> coherent 64/32-bit accesses
#pragma unroll
      for (int itr = 0; itr < 4; ++itr) {
        int idx = itr * 256 + tid;
        int mr = idx >> 3, jp = idx & 7;
        int grow = m0 + mr;
        const float* gp = gl + mr * 68 + jp * 8;
        f32x4 ga = *(const f32x4*)gp;
        f32x4 gb = *(const f32x4*)(gp + 4);
        const u16* u2p = U2 + (size_t)grow * 4096 + (jbase + jp * 2) * 4;
        u64 ua = ld64(u2p);
        u64 ub = ld64(u2p + 4);
        ga[0] += bf2f((unsigned)ua);        ga[1] += bf2f((unsigned)(ua >> 16));
        ga[2] += bf2f((unsigned)(ua >> 32)); ga[3] += bf2f((unsigned)(ua >> 48));
        gb[0] += bf2f((unsigned)ub);        gb[1] += bf2f((unsigned)(ub >> 16));
        gb[2] += bf2f((unsigned)(ub >> 32)); gb[3] += bf2f((unsigned)(ub >> 48));
        size_t off = (size_t)grow * HDIM + jbase + jp * 2;
        union { u64 u; float f[2]; } cv;
        cv.u = ld64(C2f + off);
        float c0 = sigm(ga[1]) * cv.f[0] + sigm(ga[0]) * tanh_(ga[2]);
        float c1 = sigm(gb[1]) * cv.f[1] + sigm(gb[0]) * tanh_(gb[2]);
        float h0 = sigm(ga[3]) * tanh_(c0);
        float h1 = sigm(gb[3]) * tanh_(c1);
        cv.f[0] = c0; cv.f[1] = c1;
        st64(C2f + off, cv.u);
        st32(H2o + off, (unsigned)f2bf(h0) | ((unsigned)f2bf(h1) << 16));
        st32(C2dst + off, (unsigned)f2bf(c0) | ((unsigned)f2bf(c1) << 16));
      }
    }
    grid_sync(bar, grp);
  }
}

// ============ fallback per-step kernels (old path) ============
__global__ __launch_bounds__(256, 1) void k1_fused(
    const u16* __restrict__ Xt, const u16* __restrict__ W1a,
    const u16* __restrict__ H1in, const u16* __restrict__ Whh1,
    const float* __restrict__ b1s, float* __restrict__ c1State,
    u16* __restrict__ H1out, u16* __restrict__ C1out,
    const u16* __restrict__ H2in, const u16* __restrict__ Whh2,
    const float* __restrict__ b2s, u16* __restrict__ U2)
{
  __shared__ __align__(16) char smem[131072];
  const int tid = threadIdx.x;
  const int lane = tid & 63, wave = tid >> 6;
  const int quad = lane >> 4, l16 = lane & 15;
  const int wm = wave >> 1, wn = wave & 1;
  const int b = blockIdx.x;
  f32x4 acc[4][4];

  if (b < 128) {
    const int m0 = (b >> 5) * 128, n0 = (b & 31) * 128;
    gemm128<true>(acc, Xt, W1a, 128, H1in, Whh1, 1024, m0, n0, smem);

    float* gl = (float*)smem;  // [64][132]
    const int jbase = (b & 31) * 32;
#pragma unroll
    for (int h = 0; h < 2; ++h) {
      __syncthreads();
      if (wm == h) {
#pragma unroll
        for (int nt = 0; nt < 4; ++nt) {
          int col = wn * 64 + nt * 16 + l16;
#pragma unroll
          for (int mt = 0; mt < 4; ++mt) {
            int rowb = mt * 16 + quad * 4;
#pragma unroll
            for (int r = 0; r < 4; ++r)
              gl[(rowb + r) * 132 + col] = acc[mt][nt][r];
          }
        }
      }
      __syncthreads();
#pragma unroll
      for (int itr = 0; itr < 8; ++itr) {
        int idx = itr * 256 + tid;
        int mr = idx >> 5, jl = idx & 31;
        f32x4 g4 = *(const f32x4*)(gl + mr * 132 + jl * 4);
        f32x4 b4 = *(const f32x4*)(b1s + jbase * 4 + jl * 4);
        g4 += b4;
        float ii = sigm(g4[0]), ff = sigm(g4[1]);
        float gg = tanh_(g4[2]), oo = sigm(g4[3]);
        size_t off = (size_t)(m0 + h * 64 + mr) * HDIM + jbase + jl;
        float cp = c1State[off];
        float cn = ff * cp + ii * gg;
        float hh = oo * tanh_(cn);
        c1State[off] = cn;
        H1out[off] = f2bf(hh);
        C1out[off] = f2bf(cn);
      }
    }
  } else {
    const int bb = b - 128;
    const int m0 = (bb >> 5) * 128, n0 = (bb & 31) * 128;
    gemm128<false>(acc, nullptr, nullptr, 0, H2in, Whh2, 1024, m0, n0, smem);
#pragma unroll
    for (int nt = 0; nt < 4; ++nt) {
      int col = n0 + wn * 64 + nt * 16 + l16;
      float bias = b2s[col];
#pragma unroll
      for (int mt = 0; mt < 4; ++mt) {
        int row = m0 + wm * 64 + mt * 16 + quad * 4;
#pragma unroll
        for (int r = 0; r < 4; ++r)
          U2[(size_t)(row + r) * 4096 + col] = f2bf(acc[mt][nt][r] + bias);
      }
    }
  }
}

__global__ __launch_bounds__(256, 1) void k2_cell2(
    const u16* __restrict__ C1b, const u16* __restrict__ Wcomb,
    const u16* __restrict__ U2, float* __restrict__ c2State,
    u16* __restrict__ H2out, u16* __restrict__ C2out)
{
  __shared__ __align__(16) char smem[131072];
  const int tid = threadIdx.x;
  const int lane = tid & 63, wave = tid >> 6;
  const int quad = lane >> 4, l16 = lane & 15;
  const int wm = wave >> 1, wn = wave & 1;
  const int b = blockIdx.x;
  const int m0 = (b >> 5) * 128, n0 = (b & 31) * 128;
  f32x4 acc[4][4];
  gemm128<false>(acc, nullptr, nullptr, 0, C1b, Wcomb, 1024, m0, n0, smem);

  float* gl = (float*)smem;
  const int jbase = (b & 31) * 32;
#pragma unroll
  for (int h = 0; h < 2; ++h) {
    __syncthreads();
    if (wm == h) {
#pragma unroll
      for (int nt = 0; nt < 4; ++nt) {
        int col = wn * 64 + nt * 16 + l16;
#pragma unroll
        for (int mt = 0; mt < 4; ++mt) {
          int rowb = mt * 16 + quad * 4;
#pragma unroll
          for (int r = 0; r < 4; ++r)
            gl[(rowb + r) * 132 + col] = acc[mt][nt][r];
        }
      }
    }
    __syncthreads();
#pragma unroll
    for (int itr = 0; itr < 8; ++itr) {
      int idx = itr * 256 + tid;
      int mr = idx >> 5, jl = idx & 31;
      int grow = m0 + h * 64 + mr;
      f32x4 g4 = *(const f32x4*)(gl + mr * 132 + jl * 4);
      const u16* u2p = U2 + (size_t)grow * 4096 + jbase * 4 + jl * 4;
      g4[0] += bf2f(u2p[0]); g4[1] += bf2f(u2p[1]);
      g4[2] += bf2f(u2p[2]); g4[3] += bf2f(u2p[3]);
      float ii = sigm(g4[0]), ff = sigm(g4[1]);
      float gg = tanh_(g4[2]), oo = sigm(g4[3]);
      size_t off = (size_t)grow * HDIM + jbase + jl;
      float cp = c2State[off];
      float cn = ff * cp + ii * gg;
      float hh = oo * tanh_(cn);
      c2State[off] = cn;
      H2out[off] = f2bf(hh);
      C2out[off] = f2bf(cn);
    }
  }
}

// ================= 64x128 single-buffered GEMM (wcomb / final) =================
__device__ __forceinline__ void gemm_tile_64x128(
    f32x4 acc[2][4],
    const u16* A0, const u16* B0, int K0,
    const u16* A1, const u16* B1, int K1,
    int m0, int n0, u16* As, u16* Bs)
{
  const int tid  = threadIdx.x;
  const int lane = tid & 63;
  const int wave = tid >> 6;
  const int quad = lane >> 4;
  const int l16  = lane & 15;
  const int wm   = wave >> 1;
  const int wn   = wave & 1;
  const int sw   = l16 & 7;

#pragma unroll
  for (int mt = 0; mt < 2; ++mt)
#pragma unroll
    for (int nt = 0; nt < 4; ++nt) {
      f32x4 z = {0.f, 0.f, 0.f, 0.f};
      acc[mt][nt] = z;
    }

  for (int s = 0; s < 2; ++s) {
    const u16* A = s ? A1 : A0;
    const u16* B = s ? B1 : B0;
    const int  K = s ? K1 : K0;
    for (int k0 = 0; k0 < K; k0 += 64) {
      __syncthreads();
#pragma unroll
      for (int i = 0; i < 2; ++i) {
        int c = (wave * 2 + i) * 64 + lane;
        int row = c >> 3, lc = (c & 7) ^ (row & 7);
        const u16* g = A + (size_t)(m0 + row) * K + k0 + (lc << 3);
        load16_lds<0>(g, As + c * 8);
      }
#pragma unroll
      for (int i = 0; i < 4; ++i) {
        int c = (wave * 4 + i) * 64 + lane;
        int row = c >> 3, lc = (c & 7) ^ (row & 7);
        const u16* g = B + (size_t)(n0 + row) * K + k0 + (lc << 3);
        load16_lds<0>(g, Bs + c * 8);
      }
      __syncthreads();
      const bf16x8* Av = (const bf16x8*)As;
      const bf16x8* Bv = (const bf16x8*)Bs;
#pragma unroll
      for (int kk = 0; kk < 2; ++kk) {
        const int pc = (kk * 4 + quad) ^ sw;
        bf16x8 a[2], b[4];
#pragma unroll
        for (int mt = 0; mt < 2; ++mt)
          a[mt] = Av[(wm * 32 + mt * 16 + l16) * 8 + pc];
#pragma unroll
        for (int nt = 0; nt < 4; ++nt)
          b[nt] = Bv[(wn * 64 + nt * 16 + l16) * 8 + pc];
#pragma unroll
        for (int mt = 0; mt < 2; ++mt)
#pragma unroll
          for (int nt = 0; nt < 4; ++nt)
            acc[mt][nt] = __builtin_amdgcn_mfma_f32_16x16x32_bf16(
                a[mt], b[nt], acc[mt][nt], 0, 0, 0);
      }
    }
  }
  __syncthreads();
}

__global__ __launch_bounds__(256, 2) void wcomb_gemm(
    const u16* __restrict__ A, const u16* __restrict__ Bt, u16* __restrict__ outp)
{
  __shared__ __align__(16) char smem[24576];
  u16* As = (u16*)smem;
  u16* Bs = (u16*)(smem + 8192);
  const int m0 = blockIdx.y * 64;
  const int n0 = blockIdx.x * 128;
  f32x4 acc[2][4];
  gemm_tile_64x128(acc, A, Bt, 1024, nullptr, nullptr, 0, m0, n0, As, Bs);
  const int lane = threadIdx.x & 63;
  const int wave = threadIdx.x >> 6;
  const int quad = lane >> 4, l16 = lane & 15;
  const int wm = wave >> 1, wn = wave & 1;
#pragma unroll
  for (int mt = 0; mt < 2; ++mt)
#pragma unroll
    for (int nt = 0; nt < 4; ++nt)
#pragma unroll
      for (int r = 0; r < 4; ++r) {
        int mr = m0 + wm * 32 + mt * 16 + quad * 4 + r;
        int c  = n0 + wn * 64 + nt * 16 + l16;
        outp[(size_t)permrow(mr) * 1024 + c] = f2bf(acc[mt][nt][r]);
      }
}

__global__ __launch_bounds__(256, 2) void final_logsoftmax(
    const u16* __restrict__ C2, const u16* __restrict__ Wf,
    const float* __restrict__ bfin, float* __restrict__ out)
{
  __shared__ __align__(16) char smem[64 * 132 * 4 + 256];
  u16* As = (u16*)smem;
  u16* Bs = (u16*)(smem + 8192);
  float* gl  = (float*)smem;
  float* lse = (float*)(smem + 64 * 132 * 4);

  const int m0 = blockIdx.y * 64;
  f32x4 acc[2][4];
  gemm_tile_64x128(acc, C2, Wf, 1024, nullptr, nullptr, 0, m0, 0, As, Bs);

  const int tid = threadIdx.x;
  const int lane = tid & 63;
  const int wave = tid >> 6;
  const int quad = lane >> 4, l16 = lane & 15;
  const int wm = wave >> 1, wn = wave & 1;
#pragma unroll
  for (int nt = 0; nt < 4; ++nt) {
    int coll = wn * 64 + nt * 16 + l16;
    float bias = (coll < VOUT) ? bfin[coll] : 0.f;
#pragma unroll
    for (int mt = 0; mt < 2; ++mt) {
      int rowb = wm * 32 + mt * 16 + quad * 4;
#pragma unroll
      for (int r = 0; r < 4; ++r)
        gl[(rowb + r) * 132 + coll] = acc[mt][nt][r] + bias;
    }
  }
  __syncthreads();
  if (tid < 64) {
    const float* row = gl + tid * 132;
    float mx = -1e30f;
    for (int c = 0; c < VOUT; ++c) mx = fmaxf(mx, row[c]);
    float s = 0.f;
    for (int c = 0; c < VOUT; ++c) s += __expf(row[c] - mx);
    lse[tid] = mx + __logf(s);
  }
  __syncthreads();
  for (int idx = tid; idx < 64 * VOUT; idx += 256) {
    int m = idx / VOUT, c = idx - m * VOUT;
    out[(size_t)(m0 + m) * VOUT + c] = gl[m * 132 + c] - lse[m];
  }
}

// ---------------- setup kernels ----------------
__global__ void k_build_w1a(const float* __restrict__ w, u16* __restrict__ d) {
  int idx = blockIdx.x * 256 + threadIdx.x;
  int n = idx >> 7, k = idx & 127;
  float v = (k < IIN) ? w[n * IIN + k] : 0.f;
  d[permrow(n) * 128 + k] = f2bf(v);
}
__global__ void k_conv_perm1024(const float* __restrict__ w, u16* __restrict__ d) {
  int idx = blockIdx.x * 256 + threadIdx.x;
  int n = idx >> 10, k = idx & 1023;
  d[(size_t)permrow(n) * 1024 + k] = f2bf(w[idx]);
}
__global__ void k_conv(const float* __restrict__ s, u16* __restrict__ d) {
  int idx = blockIdx.x * 256 + threadIdx.x;
  d[idx] = f2bf(s[idx]);
}
__global__ void k_transpose1024(const float* __restrict__ s, u16* __restrict__ d) {
  int idx = blockIdx.x * 256 + threadIdx.x;
  int r = idx >> 10, c = idx & 1023;
  d[c * 1024 + r] = f2bf(s[idx]);
}
__global__ void k_build_wfin(const float* __restrict__ w, u16* __restrict__ d) {
  int idx = blockIdx.x * 256 + threadIdx.x;
  int r = idx >> 10, c = idx & 1023;
  d[idx] = (r < VOUT) ? f2bf(w[r * 1024 + c]) : (u16)0;
}
__global__ void k_build_xpad(const float* __restrict__ x, u16* __restrict__ d) {
  int idx = blockIdx.x * 256 + threadIdx.x;
  int row = idx >> 7, k = idx & 127;
  d[idx] = (k < IIN) ? f2bf(x[row * IIN + k]) : (u16)0;
}
__global__ void k_b1sum(const float* __restrict__ a, const float* __restrict__ b,
                        float* __restrict__ d) {
  int n = blockIdx.x * 256 + threadIdx.x;
  d[permrow(n)] = a[n] + b[n];
}
__global__ void k_b2sum(const float* __restrict__ Wih2, const float* __restrict__ bmid,
                        const float* __restrict__ bih2, const float* __restrict__ bhh2,
                        float* __restrict__ d) {
  int row = blockIdx.x * 4 + (threadIdx.x >> 6);
  int lane = threadIdx.x & 63;
  const float* wr = Wih2 + (size_t)row * 1024;
  float s = 0.f;
  for (int k = lane; k < 1024; k += 64) s += wr[k] * bmid[k];
#pragma unroll
  for (int o = 32; o > 0; o >>= 1) s += __shfl_down(s, o);
  if (lane == 0) d[permrow(row)] = s + bih2[row] + bhh2[row];
}

extern "C" void kernel_launch(void* const* d_in, const int* in_sizes, int n_in,
                              void* d_out, int out_size, void* d_ws, size_t ws_size,
                              hipStream_t stream) {
  const float* x    = (const float*)d_in[0];
  const float* Wih1 = (const float*)d_in[1];
  const float* Whh1 = (const float*)d_in[2];
  const float* bih1 = (const float*)d_in[3];
  const float* bhh1 = (const float*)d_in[4];
  const float* Wmid = (const float*)d_in[5];
  const float* bmid = (const float*)d_in[6];
  const float* Wih2 = (const float*)d_in[7];
  const float* Whh2 = (const float*)d_in[8];
  const float* bih2 = (const float*)d_in[9];
  const float* bhh2 = (const float*)d_in[10];
  const float* Wfin = (const float*)d_in[11];
  const float* bfin = (const float*)d_in[12];

  const size_t SZ_XBF = (size_t)TSTEPS * BSZ * 128 * 2;
  const size_t SZ_W1A = (size_t)4096 * 128 * 2;
  const size_t SZ_W1K = (size_t)4096 * 1024 * 2;
  const size_t SZ_WMT = (size_t)1024 * 1024 * 2;
  const size_t SZ_WFB = (size_t)128 * 1024 * 2;
  const size_t SZ_BSM = (size_t)4096 * 4;
  const size_t SZ_HB  = (size_t)BSZ * HDIM * 2;
  const size_t SZ_CF  = (size_t)BSZ * HDIM * 4;
  const size_t SZ_U2  = (size_t)BSZ * 4096 * 2;
  const size_t SZ_C2S = (size_t)TSTEPS * BSZ * HDIM * 2;

  char* base = (char*)d_ws;
  size_t off = 0;
  auto alloc = [&](size_t b) { char* p = base + off; off += (b + 255) & ~(size_t)255; return p; };

  u16*   Xbf    = (u16*)alloc(SZ_XBF);
  u16*   W1a    = (u16*)alloc(SZ_W1A);
  u16*   Whh1b  = (u16*)alloc(SZ_W1K);
  u16*   Wcombb = (u16*)alloc(SZ_W1K);
  u16*   Whh2b  = (u16*)alloc(SZ_W1K);
  u16*   Wih2b  = (u16*)alloc(SZ_W1K);
  u16*   WmidT  = (u16*)alloc(SZ_WMT);
  u16*   Wfinb  = (u16*)alloc(SZ_WFB);
  float* b1s    = (float*)alloc(SZ_BSM);
  float* b2s    = (float*)alloc(SZ_BSM);
  u16*   H1p[2]; H1p[0] = (u16*)alloc(SZ_HB); H1p[1] = (u16*)alloc(SZ_HB);
  u16*   H2p[2]; H2p[0] = (u16*)alloc(SZ_HB); H2p[1] = (u16*)alloc(SZ_HB);
  float* C1f    = (float*)alloc(SZ_CF);
  float* C2f    = (float*)alloc(SZ_CF);
  u16*   C1b    = (u16*)alloc(SZ_HB);
  u16*   C2b    = (u16*)alloc(SZ_HB);
  u16*   U2     = (u16*)alloc(SZ_U2);
  unsigned* barp = (unsigned*)alloc(2048);
  u16*   C2seq  = (u16*)(base + off);
  bool batched  = (off + SZ_C2S) <= ws_size;

  // zero states: H1p0,H1p1,H2p0,H2p1,C1f,C2f contiguous (256-aligned sizes)
  size_t zbytes = 4 * SZ_HB + 2 * SZ_CF;
  hipMemsetAsync((void*)H1p[0], 0, zbytes, stream);
  hipMemsetAsync((void*)barp, 0, 2048, stream);

  k_build_w1a<<<2048, 256, 0, stream>>>(Wih1, W1a);
  k_conv_perm1024<<<16384, 256, 0, stream>>>(Whh1, Whh1b);
  k_conv_perm1024<<<16384, 256, 0, stream>>>(Whh2, Whh2b);
  k_conv<<<16384, 256, 0, stream>>>(Wih2, Wih2b);
  k_transpose1024<<<4096, 256, 0, stream>>>(Wmid, WmidT);
  k_build_wfin<<<512, 256, 0, stream>>>(Wfin, Wfinb);
  k_build_xpad<<<46080, 256, 0, stream>>>(x, Xbf);
  k_b1sum<<<16, 256, 0, stream>>>(bih1, bhh1, b1s);
  k_b2sum<<<1024, 256, 0, stream>>>(Wih2, bmid, bih2, bhh2, b2s);
  wcomb_gemm<<<dim3(8, 64), 256, 0, stream>>>(Wih2b, WmidT, Wcombb);

  bool usedPersistent = false;
  if (batched) {
    u16* H1x = H1p[0]; u16* H1y = H1p[1];
    u16* H2x = H2p[0]; u16* H2y = H2p[1];
    void* kargs[] = {
        (void*)&Xbf, (void*)&W1a, (void*)&Whh1b, (void*)&b1s,
        (void*)&C1f, (void*)&C1b, (void*)&Whh2b, (void*)&b2s,
        (void*)&U2, (void*)&Wcombb, (void*)&C2f, (void*)&C2seq,
        (void*)&H1x, (void*)&H1y, (void*)&H2x, (void*)&H2y,
        (void*)&barp};
    hipError_t ce = hipLaunchCooperativeKernel(
        (const void*)lstm_persistent, dim3(NBLK), dim3(256), kargs, 0, stream);
    usedPersistent = (ce == hipSuccess);
    if (!usedPersistent) (void)hipGetLastError();  // clear sticky error for fallback
  }

  if (usedPersistent) {
    final_logsoftmax<<<dim3(1, (TSTEPS * BSZ) / 64), 256, 0, stream>>>(
        C2seq, Wfinb, bfin, (float*)d_out);
  } else {
    for (int t = 0; t < TSTEPS; ++t) {
      int p = t & 1;
      k1_fused<<<256, 256, 0, stream>>>(
          Xbf + (size_t)t * BSZ * 128, W1a, H1p[p], Whh1b, b1s, C1f,
          H1p[p ^ 1], C1b, H2p[p], Whh2b, b2s, U2);
      u16* c2dst = batched ? (C2seq + (size_t)t * BSZ * HDIM) : C2b;
      k2_cell2<<<128, 256, 0, stream>>>(C1b, Wcombb, U2, C2f, H2p[p ^ 1], c2dst);
      if (!batched)
        final_logsoftmax<<<dim3(1, 8), 256, 0, stream>>>(
            C2b, Wfinb, bfin, (float*)d_out + (size_t)t * BSZ * VOUT);
    }
    if (batched)
      final_logsoftmax<<<dim3(1, (TSTEPS * BSZ) / 64), 256, 0, stream>>>(
          C2seq, Wfinb, bfin, (float*)d_out);
  }
}

// Round 10
// 5665.133 us; speedup vs baseline: 3.1737x; 1.2099x over previous
//
#include <hip/hip_runtime.h>
#include <stdint.h>

// LSTM_34359738368754: 2-layer LSTM, T=180 B=512 H=1024 I=V=108.
// R8: R7 + 512-thread blocks (8 waves = 2 waves/SIMD) in the persistent kernel.
//  - R7 measured 6.85ms: 4-deep prefetch nearly null -> K-loop cost is NOT
//    raw load latency. At 1 wave/SIMD (Occupancy 12.4%) the per-iter
//    critical path {vmcnt, s_barrier, 16x ds_read_b128, dependent MFMA,
//    s_barrier} has no second wave to hide behind.
//  - R8: same 256-block grid/tiles/barriers; 512 threads -> 2 waves/SIMD.
//    Phase A: 8-wave 2x4 layout, acc[4][2], 4 loads/stage, vmcnt 12/8/4/0.
//    Phase B: acc[4], 3 loads/stage, vmcnt 9/6/3/0. Epilogues re-indexed.
//  - Fallback per-step kernels keep the 256-thread code (proven).

typedef unsigned short u16;
typedef __attribute__((ext_vector_type(2))) float f32x2;
typedef __attribute__((ext_vector_type(4))) float f32x4;
typedef __attribute__((ext_vector_type(8))) short bf16x8;
typedef unsigned long long u64;

#define HDIM 1024
#define BSZ  512
#define TSTEPS 180
#define IIN  108
#define VOUT 108
#define NBLK 256

#define AGENT __HIP_MEMORY_SCOPE_AGENT
#define RLX   __ATOMIC_RELAXED

__device__ __forceinline__ u16 f2bf(float x) {
  union { float f; unsigned u; } v; v.f = x;
  unsigned r = (v.u + 0x7fffu + ((v.u >> 16) & 1u)) >> 16;  // RNE
  return (u16)r;
}
__device__ __forceinline__ float bf2f(unsigned b) {
  union { unsigned u; float f; } v; v.u = (b & 0xffffu) << 16; return v.f;
}
__device__ __forceinline__ float sigm(float x) { return 1.f / (1.f + __expf(-x)); }
__device__ __forceinline__ float tanh_(float x) {
  float a = fabsf(x), t = __expf(-2.f * a);
  float r = (1.f - t) / (1.f + t);
  return x < 0.f ? -r : r;
}
__device__ __forceinline__ int permrow(int n) { return ((n & 1023) << 2) | (n >> 10); }

// aux = CPol: 0 = cached; 0x11 = SC0|SC1 (agent-coherent: bypass L1+L2, hit LLC)
template <int AUX>
__device__ __forceinline__ void load16_lds(const void* g, void* l) {
  __builtin_amdgcn_global_load_lds(
      (const __attribute__((address_space(1))) unsigned int*)g,
      (__attribute__((address_space(3))) unsigned int*)l, 16, 0, AUX);
}

__device__ __forceinline__ void st32(void* p, unsigned v) {
  __hip_atomic_store((unsigned*)p, v, RLX, AGENT);
}
__device__ __forceinline__ void st64(void* p, u64 v) {
  __hip_atomic_store((u64*)p, v, RLX, AGENT);
}
__device__ __forceinline__ u64 ld64(const void* p) {
  return __hip_atomic_load((u64*)p, RLX, AGENT);
}

// ---------------- fence-free grid barrier ----------------
// bar[0]=gen; bar[32]=root; bar[64+g*32]=group-g arrival (128B-separated).
__device__ __forceinline__ void grid_sync(unsigned* bar, int grp) {
  __syncthreads();
  if (threadIdx.x == 0) {
    unsigned* gen  = bar;
    unsigned* root = bar + 32;
    unsigned* gcnt = bar + 64 + grp * 32;
    unsigned g = __hip_atomic_load(gen, RLX, AGENT);
    asm volatile("s_waitcnt vmcnt(0)" ::: "memory");
    unsigned a = __hip_atomic_fetch_add(gcnt, 1u, RLX, AGENT);
    if (a == 31u) {                       // last of this group of 32
      __hip_atomic_store(gcnt, 0u, RLX, AGENT);
      asm volatile("s_waitcnt vmcnt(0)" ::: "memory");
      unsigned c = __hip_atomic_fetch_add(root, 1u, RLX, AGENT);
      if (c == 7u) {                      // last group: release the grid
        __hip_atomic_store(root, 0u, RLX, AGENT);
        asm volatile("s_waitcnt vmcnt(0)" ::: "memory");
        __hip_atomic_store(gen, g + 1u, RLX, AGENT);
      }
    }
    while (__hip_atomic_load(gen, RLX, AGENT) == g)
      __builtin_amdgcn_s_sleep(2);
  }
  __syncthreads();
}

// ======== 8-wave (512-thread) 128x128 4-buffer GEMM — persistent kernel ========
// Wave layout 2x4: wm = wave>>2 (64 rows), wn = wave&3 (32 cols). acc[4][2].
template <int AUXA>
__device__ __forceinline__ void stage128_8w(const u16* A, const u16* B, int K,
                                            int k0, int m0, int n0,
                                            char* smem, int buf, int wave, int lane) {
  u16* As = (u16*)(smem + buf * 32768);
  u16* Bs = (u16*)(smem + buf * 32768 + 16384);
#pragma unroll
  for (int i = 0; i < 2; ++i) {
    int c = (wave * 2 + i) * 64 + lane;             // 1024 chunks = 128 rows
    int row = c >> 3, lc = (c & 7) ^ (row & 7);
    load16_lds<AUXA>(A + (size_t)(m0 + row) * K + k0 + (lc << 3), As + c * 8);
  }
#pragma unroll
  for (int i = 0; i < 2; ++i) {
    int c = (wave * 2 + i) * 64 + lane;
    int row = c >> 3, lc = (c & 7) ^ (row & 7);
    load16_lds<0>(B + (size_t)(n0 + row) * K + k0 + (lc << 3), Bs + c * 8);
  }
}

__device__ __forceinline__ void compute128_8w(f32x4 acc[4][2], char* smem, int buf,
                                              int wm, int wn, int l16, int quad) {
  const bf16x8* Av = (const bf16x8*)(smem + buf * 32768);
  const bf16x8* Bv = (const bf16x8*)(smem + buf * 32768 + 16384);
  const int sw = l16 & 7;
#pragma unroll
  for (int kk = 0; kk < 2; ++kk) {
    const int pc = (kk * 4 + quad) ^ sw;
    bf16x8 a[4], b[2];
#pragma unroll
    for (int mt = 0; mt < 4; ++mt)
      a[mt] = Av[(wm * 64 + mt * 16 + l16) * 8 + pc];
#pragma unroll
    for (int nt = 0; nt < 2; ++nt)
      b[nt] = Bv[(wn * 32 + nt * 16 + l16) * 8 + pc];
#pragma unroll
    for (int mt = 0; mt < 4; ++mt)
#pragma unroll
      for (int nt = 0; nt < 2; ++nt)
        acc[mt][nt] = __builtin_amdgcn_mfma_f32_16x16x32_bf16(
            a[mt], b[nt], acc[mt][nt], 0, 0, 0);
  }
}

template <bool HAS0>
__device__ __forceinline__ void gemm128_8w(f32x4 acc[4][2],
    const u16* A0, const u16* B0, int K0,
    const u16* A1, const u16* B1, int K1,
    int m0, int n0, char* smem) {
  const int tid = threadIdx.x;
  const int lane = tid & 63, wave = tid >> 6;
  const int quad = lane >> 4, l16 = lane & 15;
  const int wm = wave >> 2, wn = wave & 3;

#pragma unroll
  for (int mt = 0; mt < 4; ++mt)
#pragma unroll
    for (int nt = 0; nt < 2; ++nt) {
      f32x4 z = {0.f, 0.f, 0.f, 0.f};
      acc[mt][nt] = z;
    }

  const int n0i = HAS0 ? (K0 >> 6) : 0;
  const int nIter = n0i + (K1 >> 6);

  auto do_stage = [&](int ix) {
    if (HAS0 && ix < n0i)
      stage128_8w<0>(A0, B0, K0, ix * 64, m0, n0, smem, ix & 3, wave, lane);
    else
      stage128_8w<0x11>(A1, B1, K1, (ix - n0i) * 64, m0, n0, smem, ix & 3, wave, lane);
  };

  do_stage(0);
  if (nIter > 1) do_stage(1);
  if (nIter > 2) do_stage(2);

  for (int it = 0; it < nIter; ++it) {
    if (it + 3 < nIter) do_stage(it + 3);
    const int rem = nIter - 1 - it;     // stages still outstanding beyond it
    if (rem >= 3)      asm volatile("s_waitcnt vmcnt(12)" ::: "memory");
    else if (rem == 2) asm volatile("s_waitcnt vmcnt(8)"  ::: "memory");
    else if (rem == 1) asm volatile("s_waitcnt vmcnt(4)"  ::: "memory");
    else               asm volatile("s_waitcnt vmcnt(0)"  ::: "memory");
    __builtin_amdgcn_s_barrier();
    asm volatile("" ::: "memory");
    compute128_8w(acc, smem, it & 3, wm, wn, l16, quad);
    asm volatile("" ::: "memory");
    __builtin_amdgcn_s_barrier();  // all waves done reading buf before overwrite
  }
}

// ======== 8-wave phase-B 128x64 4-buffer GEMM ========
// Per wave: 64 rows (wm), 16 cols (wn*16). acc[4].
__device__ __forceinline__ void stage_pb_8w(const u16* A, const u16* B, int k0,
                                            int m0, int n0, char* smem, int buf,
                                            int wave, int lane) {
  u16* As = (u16*)(smem + buf * 24576);
  u16* Bs = (u16*)(smem + buf * 24576 + 16384);
#pragma unroll
  for (int i = 0; i < 2; ++i) {
    int c = (wave * 2 + i) * 64 + lane;               // 1024 chunks = 128 rows
    int row = c >> 3, lc = (c & 7) ^ (row & 7);
    load16_lds<0x11>(A + (size_t)(m0 + row) * 1024 + k0 + (lc << 3), As + c * 8);
  }
  {
    int c = wave * 64 + lane;                         // 512 chunks = 64 rows
    int row = c >> 3, lc = (c & 7) ^ (row & 7);
    load16_lds<0>(B + (size_t)(n0 + row) * 1024 + k0 + (lc << 3), Bs + c * 8);
  }
}

__device__ __forceinline__ void compute_pb_8w(f32x4 acc[4], char* smem, int buf,
                                              int wm, int wn, int l16, int quad) {
  const bf16x8* Av = (const bf16x8*)(smem + buf * 24576);
  const bf16x8* Bv = (const bf16x8*)(smem + buf * 24576 + 16384);
  const int sw = l16 & 7;
#pragma unroll
  for (int kk = 0; kk < 2; ++kk) {
    const int pc = (kk * 4 + quad) ^ sw;
    bf16x8 a[4], b;
#pragma unroll
    for (int mt = 0; mt < 4; ++mt)
      a[mt] = Av[(wm * 64 + mt * 16 + l16) * 8 + pc];
    b = Bv[(wn * 16 + l16) * 8 + pc];
#pragma unroll
    for (int mt = 0; mt < 4; ++mt)
      acc[mt] = __builtin_amdgcn_mfma_f32_16x16x32_bf16(a[mt], b, acc[mt], 0, 0, 0);
  }
}

// ================= persistent whole-sequence kernel (512 threads) =================
__global__ __launch_bounds__(512, 1) void lstm_persistent(
    const u16* __restrict__ Xbf, const u16* __restrict__ W1a,
    const u16* __restrict__ Whh1b, const float* __restrict__ b1s,
    float* __restrict__ C1f, u16* __restrict__ C1b,
    const u16* __restrict__ Whh2b, const float* __restrict__ b2s,
    u16* __restrict__ U2, const u16* __restrict__ Wcombb,
    float* __restrict__ C2f, u16* __restrict__ C2seq,
    u16* __restrict__ H1x, u16* __restrict__ H1y,
    u16* __restrict__ H2x, u16* __restrict__ H2y,
    unsigned* __restrict__ bar)
{
  __shared__ __align__(16) char smem[131072];
  const int tid = threadIdx.x;
  const int lane = tid & 63, wave = tid >> 6;
  const int quad = lane >> 4, l16 = lane & 15;
  const int wm = wave >> 2, wn = wave & 3;
  const int b = blockIdx.x;
  const int grp = b & 7;

  for (int t = 0; t < TSTEPS; ++t) {
    const int p = t & 1;
    const u16* H1in = p ? H1y : H1x;  u16* H1o = p ? H1x : H1y;
    const u16* H2in = p ? H2y : H2x;  u16* H2o = p ? H2x : H2y;
    const u16* Xt = Xbf + (size_t)t * BSZ * 128;

    // ---------------- phase A ----------------
    if (b < 128) {
      f32x4 acc[4][2];
      const int m0 = (b >> 5) * 128, n0 = (b & 31) * 128;
      gemm128_8w<true>(acc, Xt, W1a, 128, H1in, Whh1b, 1024, m0, n0, smem);

      float* gl = (float*)smem;  // [64][132]
      const int jbase = (b & 31) * 32;
#pragma unroll
      for (int h = 0; h < 2; ++h) {
        __syncthreads();
        if (wm == h) {
#pragma unroll
          for (int nt = 0; nt < 2; ++nt) {
            int col = wn * 32 + nt * 16 + l16;
#pragma unroll
            for (int mt = 0; mt < 4; ++mt) {
              int rowb = mt * 16 + quad * 4;
#pragma unroll
              for (int r = 0; r < 4; ++r)
                gl[(rowb + r) * 132 + col] = acc[mt][nt][r];
            }
          }
        }
        __syncthreads();
        // cell update, 2 cols/thread -> u32 coherent stores (64 rows x 16 pairs)
#pragma unroll
        for (int itr = 0; itr < 2; ++itr) {
          int idx = itr * 512 + tid;
          int mr = idx >> 4, jp = idx & 15;
          const float* gp = gl + mr * 132 + jp * 8;
          f32x4 ga = *(const f32x4*)gp;
          f32x4 gb = *(const f32x4*)(gp + 4);
          const float* bp = b1s + jbase * 4 + jp * 8;
          ga += *(const f32x4*)bp;
          gb += *(const f32x4*)(bp + 4);
          size_t off = (size_t)(m0 + h * 64 + mr) * HDIM + jbase + jp * 2;
          f32x2 cp = *(const f32x2*)(C1f + off);      // private, cached
          float c0 = sigm(ga[1]) * cp[0] + sigm(ga[0]) * tanh_(ga[2]);
          float c1 = sigm(gb[1]) * cp[1] + sigm(gb[0]) * tanh_(gb[2]);
          float h0 = sigm(ga[3]) * tanh_(c0);
          float h1 = sigm(gb[3]) * tanh_(c1);
          f32x2 cn = {c0, c1};
          *(f32x2*)(C1f + off) = cn;
          st32(H1o + off, (unsigned)f2bf(h0) | ((unsigned)f2bf(h1) << 16));
          st32(C1b + off, (unsigned)f2bf(c0) | ((unsigned)f2bf(c1) << 16));
        }
      }
    } else {
      f32x4 acc[4][2];
      const int bb = b - 128;
      const int m0 = (bb >> 5) * 128, n0 = (bb & 31) * 128;
      gemm128_8w<false>(acc, nullptr, nullptr, 0, H2in, Whh2b, 1024, m0, n0, smem);
      // U2 = acc + bias; lane-pair pack -> u32 coherent stores (even lanes)
#pragma unroll
      for (int nt = 0; nt < 2; ++nt) {
        int col = n0 + wn * 32 + nt * 16 + l16;
        float bias = b2s[col];
#pragma unroll
        for (int mt = 0; mt < 4; ++mt) {
          int row = m0 + wm * 64 + mt * 16 + quad * 4;
#pragma unroll
          for (int r = 0; r < 4; ++r) {
            float v = acc[mt][nt][r] + bias;
            float w = __shfl_xor(v, 1);
            if (!(lane & 1))
              st32(U2 + (size_t)(row + r) * 4096 + col,
                   (unsigned)f2bf(v) | ((unsigned)f2bf(w) << 16));
          }
        }
      }
    }
    grid_sync(bar, grp);

    // ---------------- phase B: gates2 = c1@Wcomb^T + U2, 128x64 tiles ----------------
    {
      f32x4 acc[4];
#pragma unroll
      for (int mt = 0; mt < 4; ++mt) {
        f32x4 z = {0.f, 0.f, 0.f, 0.f};
        acc[mt] = z;
      }
      const int m0 = (b >> 6) * 128;        // 4 m-tiles
      const int n0 = (b & 63) * 64;         // 64 n-tiles
      const int jbase = (b & 63) * 16;

      stage_pb_8w(C1b, Wcombb, 0,   m0, n0, smem, 0, wave, lane);
      stage_pb_8w(C1b, Wcombb, 64,  m0, n0, smem, 1, wave, lane);
      stage_pb_8w(C1b, Wcombb, 128, m0, n0, smem, 2, wave, lane);
      for (int it = 0; it < 16; ++it) {
        if (it + 3 < 16)
          stage_pb_8w(C1b, Wcombb, (it + 3) * 64, m0, n0, smem, (it + 3) & 3, wave, lane);
        const int rem = 15 - it;
        if (rem >= 3)      asm volatile("s_waitcnt vmcnt(9)" ::: "memory");
        else if (rem == 2) asm volatile("s_waitcnt vmcnt(6)" ::: "memory");
        else if (rem == 1) asm volatile("s_waitcnt vmcnt(3)" ::: "memory");
        else               asm volatile("s_waitcnt vmcnt(0)" ::: "memory");
        __builtin_amdgcn_s_barrier();
        asm volatile("" ::: "memory");
        compute_pb_8w(acc, smem, it & 3, wm, wn, l16, quad);
        asm volatile("" ::: "memory");
        __builtin_amdgcn_s_barrier();
      }

      float* gl = (float*)smem;  // [128][68]
      __syncthreads();
      {
        int col = wn * 16 + l16;
#pragma unroll
        for (int mt = 0; mt < 4; ++mt) {
          int rowb = wm * 64 + mt * 16 + quad * 4;
#pragma unroll
          for (int r = 0; r < 4; ++r)
            gl[(rowb + r) * 68 + col] = acc[mt][r];
        }
      }
      __syncthreads();
      u16* C2dst = C2seq + (size_t)t * BSZ * HDIM;
      // cell update, 2 cols/thread (128 rows x 8 pairs)
#pragma unroll
      for (int itr = 0; itr < 2; ++itr) {
        int idx = itr * 512 + tid;
        int mr = idx >> 3, jp = idx & 7;
        int grow = m0 + mr;
        const float* gp = gl + mr * 68 + jp * 8;
        f32x4 ga = *(const f32x4*)gp;
        f32x4 gb = *(const f32x4*)(gp + 4);
        const u16* u2p = U2 + (size_t)grow * 4096 + (jbase + jp * 2) * 4;
        u64 ua = ld64(u2p);
        u64 ub = ld64(u2p + 4);
        ga[0] += bf2f((unsigned)ua);        ga[1] += bf2f((unsigned)(ua >> 16));
        ga[2] += bf2f((unsigned)(ua >> 32)); ga[3] += bf2f((unsigned)(ua >> 48));
        gb[0] += bf2f((unsigned)ub);        gb[1] += bf2f((unsigned)(ub >> 16));
        gb[2] += bf2f((unsigned)(ub >> 32)); gb[3] += bf2f((unsigned)(ub >> 48));
        size_t off = (size_t)grow * HDIM + jbase + jp * 2;
        union { u64 u; float f[2]; } cv;
        cv.u = ld64(C2f + off);
        float c0 = sigm(ga[1]) * cv.f[0] + sigm(ga[0]) * tanh_(ga[2]);
        float c1 = sigm(gb[1]) * cv.f[1] + sigm(gb[0]) * tanh_(gb[2]);
        float h0 = sigm(ga[3]) * tanh_(c0);
        float h1 = sigm(gb[3]) * tanh_(c1);
        cv.f[0] = c0; cv.f[1] = c1;
        st64(C2f + off, cv.u);
        st32(H2o + off, (unsigned)f2bf(h0) | ((unsigned)f2bf(h1) << 16));
        st32(C2dst + off, (unsigned)f2bf(c0) | ((unsigned)f2bf(c1) << 16));
      }
    }
    grid_sync(bar, grp);
  }
}

// ============ 256-thread 4-buffer GEMM (fallback kernels) ============
template <int AUXA>
__device__ __forceinline__ void stage128(const u16* A, const u16* B, int K,
                                         int k0, int m0, int n0,
                                         char* smem, int buf, int wave, int lane) {
  u16* As = (u16*)(smem + buf * 32768);
  u16* Bs = (u16*)(smem + buf * 32768 + 16384);
#pragma unroll
  for (int i = 0; i < 4; ++i) {
    int c = (wave * 4 + i) * 64 + lane;
    int row = c >> 3, lc = (c & 7) ^ (row & 7);
    load16_lds<AUXA>(A + (size_t)(m0 + row) * K + k0 + (lc << 3), As + c * 8);
  }
#pragma unroll
  for (int i = 0; i < 4; ++i) {
    int c = (wave * 4 + i) * 64 + lane;
    int row = c >> 3, lc = (c & 7) ^ (row & 7);
    load16_lds<0>(B + (size_t)(n0 + row) * K + k0 + (lc << 3), Bs + c * 8);
  }
}

__device__ __forceinline__ void compute128(f32x4 acc[4][4], char* smem, int buf,
                                           int wm, int wn, int l16, int quad) {
  const bf16x8* Av = (const bf16x8*)(smem + buf * 32768);
  const bf16x8* Bv = (const bf16x8*)(smem + buf * 32768 + 16384);
  const int sw = l16 & 7;
#pragma unroll
  for (int kk = 0; kk < 2; ++kk) {
    const int pc = (kk * 4 + quad) ^ sw;
    bf16x8 a[4], b[4];
#pragma unroll
    for (int mt = 0; mt < 4; ++mt)
      a[mt] = Av[(wm * 64 + mt * 16 + l16) * 8 + pc];
#pragma unroll
    for (int nt = 0; nt < 4; ++nt)
      b[nt] = Bv[(wn * 64 + nt * 16 + l16) * 8 + pc];
#pragma unroll
    for (int mt = 0; mt < 4; ++mt)
#pragma unroll
      for (int nt = 0; nt < 4; ++nt)
        acc[mt][nt] = __builtin_amdgcn_mfma_f32_16x16x32_bf16(
            a[mt], b[nt], acc[mt][nt], 0, 0, 0);
  }
}

template <bool HAS0>
__device__ __forceinline__ void gemm128(f32x4 acc[4][4],
    const u16* A0, const u16* B0, int K0,
    const u16* A1, const u16* B1, int K1,
    int m0, int n0, char* smem) {
  const int tid = threadIdx.x;
  const int lane = tid & 63, wave = tid >> 6;
  const int quad = lane >> 4, l16 = lane & 15;
  const int wm = wave >> 1, wn = wave & 1;

#pragma unroll
  for (int mt = 0; mt < 4; ++mt)
#pragma unroll
    for (int nt = 0; nt < 4; ++nt) {
      f32x4 z = {0.f, 0.f, 0.f, 0.f};
      acc[mt][nt] = z;
    }

  const int n0i = HAS0 ? (K0 >> 6) : 0;
  const int nIter = n0i + (K1 >> 6);

  auto do_stage = [&](int ix) {
    if (HAS0 && ix < n0i)
      stage128<0>(A0, B0, K0, ix * 64, m0, n0, smem, ix & 3, wave, lane);
    else
      stage128<0x11>(A1, B1, K1, (ix - n0i) * 64, m0, n0, smem, ix & 3, wave, lane);
  };

  do_stage(0);
  if (nIter > 1) do_stage(1);
  if (nIter > 2) do_stage(2);

  for (int it = 0; it < nIter; ++it) {
    if (it + 3 < nIter) do_stage(it + 3);
    const int rem = nIter - 1 - it;
    if (rem >= 3)      asm volatile("s_waitcnt vmcnt(24)" ::: "memory");
    else if (rem == 2) asm volatile("s_waitcnt vmcnt(16)" ::: "memory");
    else if (rem == 1) asm volatile("s_waitcnt vmcnt(8)"  ::: "memory");
    else               asm volatile("s_waitcnt vmcnt(0)"  ::: "memory");
    __builtin_amdgcn_s_barrier();
    asm volatile("" ::: "memory");
    compute128(acc, smem, it & 3, wm, wn, l16, quad);
    asm volatile("" ::: "memory");
    __builtin_amdgcn_s_barrier();
  }
}

__global__ __launch_bounds__(256, 1) void k1_fused(
    const u16* __restrict__ Xt, const u16* __restrict__ W1a,
    const u16* __restrict__ H1in, const u16* __restrict__ Whh1,
    const float* __restrict__ b1s, float* __restrict__ c1State,
    u16* __restrict__ H1out, u16* __restrict__ C1out,
    const u16* __restrict__ H2in, const u16* __restrict__ Whh2,
    const float* __restrict__ b2s, u16* __restrict__ U2)
{
  __shared__ __align__(16) char smem[131072];
  const int tid = threadIdx.x;
  const int lane = tid & 63, wave = tid >> 6;
  const int quad = lane >> 4, l16 = lane & 15;
  const int wm = wave >> 1, wn = wave & 1;
  const int b = blockIdx.x;
  f32x4 acc[4][4];

  if (b < 128) {
    const int m0 = (b >> 5) * 128, n0 = (b & 31) * 128;
    gemm128<true>(acc, Xt, W1a, 128, H1in, Whh1, 1024, m0, n0, smem);

    float* gl = (float*)smem;  // [64][132]
    const int jbase = (b & 31) * 32;
#pragma unroll
    for (int h = 0; h < 2; ++h) {
      __syncthreads();
      if (wm == h) {
#pragma unroll
        for (int nt = 0; nt < 4; ++nt) {
          int col = wn * 64 + nt * 16 + l16;
#pragma unroll
          for (int mt = 0; mt < 4; ++mt) {
            int rowb = mt * 16 + quad * 4;
#pragma unroll
            for (int r = 0; r < 4; ++r)
              gl[(rowb + r) * 132 + col] = acc[mt][nt][r];
          }
        }
      }
      __syncthreads();
#pragma unroll
      for (int itr = 0; itr < 8; ++itr) {
        int idx = itr * 256 + tid;
        int mr = idx >> 5, jl = idx & 31;
        f32x4 g4 = *(const f32x4*)(gl + mr * 132 + jl * 4);
        f32x4 b4 = *(const f32x4*)(b1s + jbase * 4 + jl * 4);
        g4 += b4;
        float ii = sigm(g4[0]), ff = sigm(g4[1]);
        float gg = tanh_(g4[2]), oo = sigm(g4[3]);
        size_t off = (size_t)(m0 + h * 64 + mr) * HDIM + jbase + jl;
        float cp = c1State[off];
        float cn = ff * cp + ii * gg;
        float hh = oo * tanh_(cn);
        c1State[off] = cn;
        H1out[off] = f2bf(hh);
        C1out[off] = f2bf(cn);
      }
    }
  } else {
    const int bb = b - 128;
    const int m0 = (bb >> 5) * 128, n0 = (bb & 31) * 128;
    gemm128<false>(acc, nullptr, nullptr, 0, H2in, Whh2, 1024, m0, n0, smem);
#pragma unroll
    for (int nt = 0; nt < 4; ++nt) {
      int col = n0 + wn * 64 + nt * 16 + l16;
      float bias = b2s[col];
#pragma unroll
      for (int mt = 0; mt < 4; ++mt) {
        int row = m0 + wm * 64 + mt * 16 + quad * 4;
#pragma unroll
        for (int r = 0; r < 4; ++r)
          U2[(size_t)(row + r) * 4096 + col] = f2bf(acc[mt][nt][r] + bias);
      }
    }
  }
}

__global__ __launch_bounds__(256, 1) void k2_cell2(
    const u16* __restrict__ C1b, const u16* __restrict__ Wcomb,
    const u16* __restrict__ U2, float* __restrict__ c2State,
    u16* __restrict__ H2out, u16* __restrict__ C2out)
{
  __shared__ __align__(16) char smem[131072];
  const int tid = threadIdx.x;
  const int lane = tid & 63, wave = tid >> 6;
  const int quad = lane >> 4, l16 = lane & 15;
  const int wm = wave >> 1, wn = wave & 1;
  const int b = blockIdx.x;
  const int m0 = (b >> 5) * 128, n0 = (b & 31) * 128;
  f32x4 acc[4][4];
  gemm128<false>(acc, nullptr, nullptr, 0, C1b, Wcomb, 1024, m0, n0, smem);

  float* gl = (float*)smem;
  const int jbase = (b & 31) * 32;
#pragma unroll
  for (int h = 0; h < 2; ++h) {
    __syncthreads();
    if (wm == h) {
#pragma unroll
      for (int nt = 0; nt < 4; ++nt) {
        int col = wn * 64 + nt * 16 + l16;
#pragma unroll
        for (int mt = 0; mt < 4; ++mt) {
          int rowb = mt * 16 + quad * 4;
#pragma unroll
          for (int r = 0; r < 4; ++r)
            gl[(rowb + r) * 132 + col] = acc[mt][nt][r];
        }
      }
    }
    __syncthreads();
#pragma unroll
    for (int itr = 0; itr < 8; ++itr) {
      int idx = itr * 256 + tid;
      int mr = idx >> 5, jl = idx & 31;
      int grow = m0 + h * 64 + mr;
      f32x4 g4 = *(const f32x4*)(gl + mr * 132 + jl * 4);
      const u16* u2p = U2 + (size_t)grow * 4096 + jbase * 4 + jl * 4;
      g4[0] += bf2f(u2p[0]); g4[1] += bf2f(u2p[1]);
      g4[2] += bf2f(u2p[2]); g4[3] += bf2f(u2p[3]);
      float ii = sigm(g4[0]), ff = sigm(g4[1]);
      float gg = tanh_(g4[2]), oo = sigm(g4[3]);
      size_t off = (size_t)grow * HDIM + jbase + jl;
      float cp = c2State[off];
      float cn = ff * cp + ii * gg;
      float hh = oo * tanh_(cn);
      c2State[off] = cn;
      H2out[off] = f2bf(hh);
      C2out[off] = f2bf(cn);
    }
  }
}

// ================= 64x128 single-buffered GEMM (wcomb / final) =================
__device__ __forceinline__ void gemm_tile_64x128(
    f32x4 acc[2][4],
    const u16* A0, const u16* B0, int K0,
    const u16* A1, const u16* B1, int K1,
    int m0, int n0, u16* As, u16* Bs)
{
  const int tid  = threadIdx.x;
  const int lane = tid & 63;
  const int wave = tid >> 6;
  const int quad = lane >> 4;
  const int l16  = lane & 15;
  const int wm   = wave >> 1;
  const int wn   = wave & 1;
  const int sw   = l16 & 7;

#pragma unroll
  for (int mt = 0; mt < 2; ++mt)
#pragma unroll
    for (int nt = 0; nt < 4; ++nt) {
      f32x4 z = {0.f, 0.f, 0.f, 0.f};
      acc[mt][nt] = z;
    }

  for (int s = 0; s < 2; ++s) {
    const u16* A = s ? A1 : A0;
    const u16* B = s ? B1 : B0;
    const int  K = s ? K1 : K0;
    for (int k0 = 0; k0 < K; k0 += 64) {
      __syncthreads();
#pragma unroll
      for (int i = 0; i < 2; ++i) {
        int c = (wave * 2 + i) * 64 + lane;
        int row = c >> 3, lc = (c & 7) ^ (row & 7);
        const u16* g = A + (size_t)(m0 + row) * K + k0 + (lc << 3);
        load16_lds<0>(g, As + c * 8);
      }
#pragma unroll
      for (int i = 0; i < 4; ++i) {
        int c = (wave * 4 + i) * 64 + lane;
        int row = c >> 3, lc = (c & 7) ^ (row & 7);
        const u16* g = B + (size_t)(n0 + row) * K + k0 + (lc << 3);
        load16_lds<0>(g, Bs + c * 8);
      }
      __syncthreads();
      const bf16x8* Av = (const bf16x8*)As;
      const bf16x8* Bv = (const bf16x8*)Bs;
#pragma unroll
      for (int kk = 0; kk < 2; ++kk) {
        const int pc = (kk * 4 + quad) ^ sw;
        bf16x8 a[2], b[4];
#pragma unroll
        for (int mt = 0; mt < 2; ++mt)
          a[mt] = Av[(wm * 32 + mt * 16 + l16) * 8 + pc];
#pragma unroll
        for (int nt = 0; nt < 4; ++nt)
          b[nt] = Bv[(wn * 64 + nt * 16 + l16) * 8 + pc];
#pragma unroll
        for (int mt = 0; mt < 2; ++mt)
#pragma unroll
          for (int nt = 0; nt < 4; ++nt)
            acc[mt][nt] = __builtin_amdgcn_mfma_f32_16x16x32_bf16(
                a[mt], b[nt], acc[mt][nt], 0, 0, 0);
      }
    }
  }
  __syncthreads();
}

__global__ __launch_bounds__(256, 2) void wcomb_gemm(
    const u16* __restrict__ A, const u16* __restrict__ Bt, u16* __restrict__ outp)
{
  __shared__ __align__(16) char smem[24576];
  u16* As = (u16*)smem;
  u16* Bs = (u16*)(smem + 8192);
  const int m0 = blockIdx.y * 64;
  const int n0 = blockIdx.x * 128;
  f32x4 acc[2][4];
  gemm_tile_64x128(acc, A, Bt, 1024, nullptr, nullptr, 0, m0, n0, As, Bs);
  const int lane = threadIdx.x & 63;
  const int wave = threadIdx.x >> 6;
  const int quad = lane >> 4, l16 = lane & 15;
  const int wm = wave >> 1, wn = wave & 1;
#pragma unroll
  for (int mt = 0; mt < 2; ++mt)
#pragma unroll
    for (int nt = 0; nt < 4; ++nt)
#pragma unroll
      for (int r = 0; r < 4; ++r) {
        int mr = m0 + wm * 32 + mt * 16 + quad * 4 + r;
        int c  = n0 + wn * 64 + nt * 16 + l16;
        outp[(size_t)permrow(mr) * 1024 + c] = f2bf(acc[mt][nt][r]);
      }
}

__global__ __launch_bounds__(256, 2) void final_logsoftmax(
    const u16* __restrict__ C2, const u16* __restrict__ Wf,
    const float* __restrict__ bfin, float* __restrict__ out)
{
  __shared__ __align__(16) char smem[64 * 132 * 4 + 256];
  u16* As = (u16*)smem;
  u16* Bs = (u16*)(smem + 8192);
  float* gl  = (float*)smem;
  float* lse = (float*)(smem + 64 * 132 * 4);

  const int m0 = blockIdx.y * 64;
  f32x4 acc[2][4];
  gemm_tile_64x128(acc, C2, Wf, 1024, nullptr, nullptr, 0, m0, 0, As, Bs);

  const int tid = threadIdx.x;
  const int lane = tid & 63;
  const int wave = tid >> 6;
  const int quad = lane >> 4, l16 = lane & 15;
  const int wm = wave >> 1, wn = wave & 1;
#pragma unroll
  for (int nt = 0; nt < 4; ++nt) {
    int coll = wn * 64 + nt * 16 + l16;
    float bias = (coll < VOUT) ? bfin[coll] : 0.f;
#pragma unroll
    for (int mt = 0; mt < 2; ++mt) {
      int rowb = wm * 32 + mt * 16 + quad * 4;
#pragma unroll
      for (int r = 0; r < 4; ++r)
        gl[(rowb + r) * 132 + coll] = acc[mt][nt][r] + bias;
    }
  }
  __syncthreads();
  if (tid < 64) {
    const float* row = gl + tid * 132;
    float mx = -1e30f;
    for (int c = 0; c < VOUT; ++c) mx = fmaxf(mx, row[c]);
    float s = 0.f;
    for (int c = 0; c < VOUT; ++c) s += __expf(row[c] - mx);
    lse[tid] = mx + __logf(s);
  }
  __syncthreads();
  for (int idx = tid; idx < 64 * VOUT; idx += 256) {
    int m = idx / VOUT, c = idx - m * VOUT;
    out[(size_t)(m0 + m) * VOUT + c] = gl[m * 132 + c] - lse[m];
  }
}

// ---------------- setup kernels ----------------
__global__ void k_build_w1a(const float* __restrict__ w, u16* __restrict__ d) {
  int idx = blockIdx.x * 256 + threadIdx.x;
  int n = idx >> 7, k = idx & 127;
  float v = (k < IIN) ? w[n * IIN + k] : 0.f;
  d[permrow(n) * 128 + k] = f2bf(v);
}
__global__ void k_conv_perm1024(const float* __restrict__ w, u16* __restrict__ d) {
  int idx = blockIdx.x * 256 + threadIdx.x;
  int n = idx >> 10, k = idx & 1023;
  d[(size_t)permrow(n) * 1024 + k] = f2bf(w[idx]);
}
__global__ void k_conv(const float* __restrict__ s, u16* __restrict__ d) {
  int idx = blockIdx.x * 256 + threadIdx.x;
  d[idx] = f2bf(s[idx]);
}
__global__ void k_transpose1024(const float* __restrict__ s, u16* __restrict__ d) {
  int idx = blockIdx.x * 256 + threadIdx.x;
  int r = idx >> 10, c = idx & 1023;
  d[c * 1024 + r] = f2bf(s[idx]);
}
__global__ void k_build_wfin(const float* __restrict__ w, u16* __restrict__ d) {
  int idx = blockIdx.x * 256 + threadIdx.x;
  int r = idx >> 10, c = idx & 1023;
  d[idx] = (r < VOUT) ? f2bf(w[r * 1024 + c]) : (u16)0;
}
__global__ void k_build_xpad(const float* __restrict__ x, u16* __restrict__ d) {
  int idx = blockIdx.x * 256 + threadIdx.x;
  int row = idx >> 7, k = idx & 127;
  d[idx] = (k < IIN) ? f2bf(x[row * IIN + k]) : (u16)0;
}
__global__ void k_b1sum(const float* __restrict__ a, const float* __restrict__ b,
                        float* __restrict__ d) {
  int n = blockIdx.x * 256 + threadIdx.x;
  d[permrow(n)] = a[n] + b[n];
}
__global__ void k_b2sum(const float* __restrict__ Wih2, const float* __restrict__ bmid,
                        const float* __restrict__ bih2, const float* __restrict__ bhh2,
                        float* __restrict__ d) {
  int row = blockIdx.x * 4 + (threadIdx.x >> 6);
  int lane = threadIdx.x & 63;
  const float* wr = Wih2 + (size_t)row * 1024;
  float s = 0.f;
  for (int k = lane; k < 1024; k += 64) s += wr[k] * bmid[k];
#pragma unroll
  for (int o = 32; o > 0; o >>= 1) s += __shfl_down(s, o);
  if (lane == 0) d[permrow(row)] = s + bih2[row] + bhh2[row];
}

extern "C" void kernel_launch(void* const* d_in, const int* in_sizes, int n_in,
                              void* d_out, int out_size, void* d_ws, size_t ws_size,
                              hipStream_t stream) {
  const float* x    = (const float*)d_in[0];
  const float* Wih1 = (const float*)d_in[1];
  const float* Whh1 = (const float*)d_in[2];
  const float* bih1 = (const float*)d_in[3];
  const float* bhh1 = (const float*)d_in[4];
  const float* Wmid = (const float*)d_in[5];
  const float* bmid = (const float*)d_in[6];
  const float* Wih2 = (const float*)d_in[7];
  const float* Whh2 = (const float*)d_in[8];
  const float* bih2 = (const float*)d_in[9];
  const float* bhh2 = (const float*)d_in[10];
  const float* Wfin = (const float*)d_in[11];
  const float* bfin = (const float*)d_in[12];

  const size_t SZ_XBF = (size_t)TSTEPS * BSZ * 128 * 2;
  const size_t SZ_W1A = (size_t)4096 * 128 * 2;
  const size_t SZ_W1K = (size_t)4096 * 1024 * 2;
  const size_t SZ_WMT = (size_t)1024 * 1024 * 2;
  const size_t SZ_WFB = (size_t)128 * 1024 * 2;
  const size_t SZ_BSM = (size_t)4096 * 4;
  const size_t SZ_HB  = (size_t)BSZ * HDIM * 2;
  const size_t SZ_CF  = (size_t)BSZ * HDIM * 4;
  const size_t SZ_U2  = (size_t)BSZ * 4096 * 2;
  const size_t SZ_C2S = (size_t)TSTEPS * BSZ * HDIM * 2;

  char* base = (char*)d_ws;
  size_t off = 0;
  auto alloc = [&](size_t b) { char* p = base + off; off += (b + 255) & ~(size_t)255; return p; };

  u16*   Xbf    = (u16*)alloc(SZ_XBF);
  u16*   W1a    = (u16*)alloc(SZ_W1A);
  u16*   Whh1b  = (u16*)alloc(SZ_W1K);
  u16*   Wcombb = (u16*)alloc(SZ_W1K);
  u16*   Whh2b  = (u16*)alloc(SZ_W1K);
  u16*   Wih2b  = (u16*)alloc(SZ_W1K);
  u16*   WmidT  = (u16*)alloc(SZ_WMT);
  u16*   Wfinb  = (u16*)alloc(SZ_WFB);
  float* b1s    = (float*)alloc(SZ_BSM);
  float* b2s    = (float*)alloc(SZ_BSM);
  u16*   H1p[2]; H1p[0] = (u16*)alloc(SZ_HB); H1p[1] = (u16*)alloc(SZ_HB);
  u16*   H2p[2]; H2p[0] = (u16*)alloc(SZ_HB); H2p[1] = (u16*)alloc(SZ_HB);
  float* C1f    = (float*)alloc(SZ_CF);
  float* C2f    = (float*)alloc(SZ_CF);
  u16*   C1b    = (u16*)alloc(SZ_HB);
  u16*   C2b    = (u16*)alloc(SZ_HB);
  u16*   U2     = (u16*)alloc(SZ_U2);
  unsigned* barp = (unsigned*)alloc(2048);
  u16*   C2seq  = (u16*)(base + off);
  bool batched  = (off + SZ_C2S) <= ws_size;

  // zero states: H1p0,H1p1,H2p0,H2p1,C1f,C2f contiguous (256-aligned sizes)
  size_t zbytes = 4 * SZ_HB + 2 * SZ_CF;
  hipMemsetAsync((void*)H1p[0], 0, zbytes, stream);
  hipMemsetAsync((void*)barp, 0, 2048, stream);

  k_build_w1a<<<2048, 256, 0, stream>>>(Wih1, W1a);
  k_conv_perm1024<<<16384, 256, 0, stream>>>(Whh1, Whh1b);
  k_conv_perm1024<<<16384, 256, 0, stream>>>(Whh2, Whh2b);
  k_conv<<<16384, 256, 0, stream>>>(Wih2, Wih2b);
  k_transpose1024<<<4096, 256, 0, stream>>>(Wmid, WmidT);
  k_build_wfin<<<512, 256, 0, stream>>>(Wfin, Wfinb);
  k_build_xpad<<<46080, 256, 0, stream>>>(x, Xbf);
  k_b1sum<<<16, 256, 0, stream>>>(bih1, bhh1, b1s);
  k_b2sum<<<1024, 256, 0, stream>>>(Wih2, bmid, bih2, bhh2, b2s);
  wcomb_gemm<<<dim3(8, 64), 256, 0, stream>>>(Wih2b, WmidT, Wcombb);

  bool usedPersistent = false;
  if (batched) {
    u16* H1x = H1p[0]; u16* H1y = H1p[1];
    u16* H2x = H2p[0]; u16* H2y = H2p[1];
    void* kargs[] = {
        (void*)&Xbf, (void*)&W1a, (void*)&Whh1b, (void*)&b1s,
        (void*)&C1f, (void*)&C1b, (void*)&Whh2b, (void*)&b2s,
        (void*)&U2, (void*)&Wcombb, (void*)&C2f, (void*)&C2seq,
        (void*)&H1x, (void*)&H1y, (void*)&H2x, (void*)&H2y,
        (void*)&barp};
    hipError_t ce = hipLaunchCooperativeKernel(
        (const void*)lstm_persistent, dim3(NBLK), dim3(512), kargs, 0, stream);
    usedPersistent = (ce == hipSuccess);
    if (!usedPersistent) (void)hipGetLastError();  // clear sticky error for fallback
  }

  if (usedPersistent) {
    final_logsoftmax<<<dim3(1, (TSTEPS * BSZ) / 64), 256, 0, stream>>>(
        C2seq, Wfinb, bfin, (float*)d_out);
  } else {
    for (int t = 0; t < TSTEPS; ++t) {
      int p = t & 1;
      k1_fused<<<256, 256, 0, stream>>>(
          Xbf + (size_t)t * BSZ * 128, W1a, H1p[p], Whh1b, b1s, C1f,
          H1p[p ^ 1], C1b, H2p[p], Whh2b, b2s, U2);
      u16* c2dst = batched ? (C2seq + (size_t)t * BSZ * HDIM) : C2b;
      k2_cell2<<<128, 256, 0, stream>>>(C1b, Wcombb, U2, C2f, H2p[p ^ 1], c2dst);
      if (!batched)
        final_logsoftmax<<<dim3(1, 8), 256, 0, stream>>>(
            C2b, Wfinb, bfin, (float*)d_out + (size_t)t * BSZ * VOUT);
    }
    if (batched)
      final_logsoftmax<<<dim3(1, (TSTEPS * BSZ) / 64), 256, 0, stream>>>(
          C2seq, Wfinb, bfin, (float*)d_out);
  }
}